// Round 2
// baseline (711.353 us; speedup 1.0000x reference)
//
#include <hip/hip_runtime.h>

typedef __bf16 bf16;
typedef __bf16 bf16x8 __attribute__((ext_vector_type(8)));
typedef float f32x4 __attribute__((ext_vector_type(4)));

#define DEVI __device__ __forceinline__

typedef const __attribute__((address_space(1))) void* gas1;
typedef __attribute__((address_space(3))) void* las3;

// ---------------------------------------------------------------------------
// Stage a [rows x 64] bf16 tile (row bytes = 128) into LDS via global_load_lds.
// 256 threads = 4 waves; each wave DMA's 1KB chunks (lane*16 appended by HW).
// ---------------------------------------------------------------------------
DEVI void stage_tile(const bf16* g, int ld, char* lds, int bytes, int tid)
{
  const int wv = tid >> 6, lane = tid & 63;
  const char* gb = (const char*)g;
  const long rowb = (long)ld * 2;
  for (int off = wv * 1024; off < bytes; off += 4096) {
    const int o  = off + lane * 16;
    const int r  = o >> 7;      // 128B per tile row
    const int cb = o & 127;
    __builtin_amdgcn_global_load_lds((gas1)(gb + (long)r * rowb + cb),
                                     (las3)(lds + off), 16, 0, 0);
  }
}

// ---------------------------------------------------------------------------
// Epilogue functors
// ---------------------------------------------------------------------------
struct EpiQKV {
  const float* bias; float* C;
  DEVI void operator()(int z, int row, int col, float v) const {
    C[(long)row * 2304 + col] = v + bias[col];
  }
};

struct EpiAttn {
  const float* stats; const float* wn; const float* bn; float* outp;
  DEVI void operator()(int z, int row, int col, float v) const {
    const int b = z / 12, h = z - b * 12;
    const float mu = stats[2 * b], rs = stats[2 * b + 1];
    const long widx = ((long)h * 1024 + row) * 1024 + col;
    const float r = (v - mu) * rs * wn[widx] + bn[widx];
    outp[((long)z * 1024 + row) * 1024 + col] = r;
  }
};

struct EpiProj {
  const float* bias; const float* x; float* src;
  DEVI void operator()(int z, int row, int col, float v) const {
    const long i = (long)row * 768 + col;
    src[i] = v + bias[col] + x[i];
  }
};

struct EpiGelu {
  const float* bias; bf16* g;
  DEVI void operator()(int z, int row, int col, float v) const {
    const float t = v + bias[col];
    const float r = 0.5f * t * (1.0f + erff(t * 0.70710678118654752f));
    g[(long)row * 3072 + col] = (bf16)r;
  }
};

struct EpiOut {
  const float* bias; const float* lnf; float* outp;
  DEVI void operator()(int z, int row, int col, float v) const {
    const long i = (long)row * 768 + col;
    outp[i] = v + bias[col] + lnf[i];   // final residual uses POST-LN1 src
  }
};

// ---------------------------------------------------------------------------
// Generic split-bf16 GEMM: C[M,N] = sum_pass A_p @ B_p^T, B stored [N][K].
// NPASS==3: (Ah,Bh)+(Ah,Bl)+(Al,Bh).  NPASS==1: (Ah,Bh) only.
// 256 threads = 4 waves arranged 2 x WC; per-wave FM x FN 16x16 fragments.
// ---------------------------------------------------------------------------
template<int BM, int BN, int WC, int FM, int FN, int NPASS, class Epi>
__global__ __launch_bounds__(256, 2) void gemm_k(
    const bf16* __restrict__ Ah, const bf16* __restrict__ Al, long abatch,
    const bf16* __restrict__ Bh, const bf16* __restrict__ Bl, long bbatch,
    int lda, int ldb, int K, Epi epi)
{
  constexpr int BK = 64;
  constexpr int AB = BM * BK * 2, BB = BN * BK * 2;
  constexpr int NBUF = (NPASS > 1) ? 2 : 1;
  __shared__ char smem[NBUF * (AB + BB)];
  char* Ash = smem;
  char* Asl = smem + AB;
  char* Bsh = smem + NBUF * AB;
  char* Bsl = Bsh + BB;

  const int tid = threadIdx.x, lane = tid & 63, wv = tid >> 6;
  const int wr = wv / WC, wc = wv % WC;
  const int mt = blockIdx.y, nt = blockIdx.x, z = blockIdx.z;
  const long abase = (long)z * abatch + (long)mt * BM * lda;
  const long bbase = (long)z * bbatch + (long)nt * BN * ldb;

  f32x4 acc[FM][FN];
#pragma unroll
  for (int m = 0; m < FM; ++m)
#pragma unroll
    for (int n = 0; n < FN; ++n) acc[m][n] = f32x4{0.f, 0.f, 0.f, 0.f};

  const int arow = wr * FM * 16, bcol = wc * FN * 16;

  for (int kt = 0; kt < K; kt += BK) {
    __syncthreads();
    stage_tile(Ah + abase + kt, lda, Ash, AB, tid);
    if (NPASS > 1) stage_tile(Al + abase + kt, lda, Asl, AB, tid);
    stage_tile(Bh + bbase + kt, ldb, Bsh, BB, tid);
    if (NPASS > 1) stage_tile(Bl + bbase + kt, ldb, Bsl, BB, tid);
    __syncthreads();
#pragma unroll
    for (int p = 0; p < NPASS; ++p) {
      const char* As = (p == 2) ? Asl : Ash;
      const char* Bs = (p == 1) ? Bsl : Bsh;
#pragma unroll
      for (int ks = 0; ks < 2; ++ks) {
        const int ko = ks * 64 + (lane >> 4) * 16;
        bf16x8 av[FM], bv[FN];
#pragma unroll
        for (int m = 0; m < FM; ++m)
          av[m] = *(const bf16x8*)(As + (arow + m * 16 + (lane & 15)) * 128 + ko);
#pragma unroll
        for (int n = 0; n < FN; ++n)
          bv[n] = *(const bf16x8*)(Bs + (bcol + n * 16 + (lane & 15)) * 128 + ko);
#pragma unroll
        for (int m = 0; m < FM; ++m)
#pragma unroll
          for (int n = 0; n < FN; ++n)
            acc[m][n] = __builtin_amdgcn_mfma_f32_16x16x32_bf16(av[m], bv[n], acc[m][n], 0, 0, 0);
      }
    }
  }

#pragma unroll
  for (int m = 0; m < FM; ++m)
#pragma unroll
    for (int n = 0; n < FN; ++n)
#pragma unroll
      for (int r = 0; r < 4; ++r) {
        const int grow = mt * BM + arow + m * 16 + (lane >> 4) * 4 + r;
        const int gcol = nt * BN + bcol + n * 16 + (lane & 15);
        epi(z, grow, gcol, acc[m][n][r]);
      }
}

// ---------------------------------------------------------------------------
// PV GEMM: out[z](1024x64) = attn_ln[z](1024x1024, f32) @ vT[z](64x1024)^T
// A staged from f32 with in-register hi/lo split; 3-pass. BM=64, 4 waves.
// ---------------------------------------------------------------------------
__global__ __launch_bounds__(256, 2) void gemm_pv(
    const float* __restrict__ A, const bf16* __restrict__ Bh,
    const bf16* __restrict__ Bl, bf16* __restrict__ oh, bf16* __restrict__ ol)
{
  __shared__ char smem[32768];
  char* Ash = smem;
  char* Asl = smem + 8192;
  char* Bsh = smem + 16384;
  char* Bsl = smem + 24576;
  const int tid = threadIdx.x, lane = tid & 63, wv = tid >> 6;
  const int mt = blockIdx.x, z = blockIdx.y;
  const float* pA = A + (long)z * 1048576 + (long)mt * 64 * 1024;
  const bf16* pBh = Bh + (long)z * 65536;
  const bf16* pBl = Bl + (long)z * 65536;

  f32x4 acc[4];
#pragma unroll
  for (int n = 0; n < 4; ++n) acc[n] = f32x4{0.f, 0.f, 0.f, 0.f};

  const int ar = tid >> 2, ac0 = (tid & 3) * 16;

  for (int kt = 0; kt < 1024; kt += 64) {
    __syncthreads();
    {
      const float* srcp = pA + (long)ar * 1024 + kt + ac0;
      float v[16];
#pragma unroll
      for (int i = 0; i < 16; i += 4) {
        f32x4 t = *(const f32x4*)(srcp + i);
        v[i] = t[0]; v[i + 1] = t[1]; v[i + 2] = t[2]; v[i + 3] = t[3];
      }
      bf16x8 h0, h1, l0, l1;
#pragma unroll
      for (int i = 0; i < 8; ++i) {
        bf16 hi = (bf16)v[i]; h0[i] = hi; l0[i] = (bf16)(v[i] - (float)hi);
      }
#pragma unroll
      for (int i = 0; i < 8; ++i) {
        bf16 hi = (bf16)v[8 + i]; h1[i] = hi; l1[i] = (bf16)(v[8 + i] - (float)hi);
      }
      *(bf16x8*)(Ash + ar * 128 + ac0 * 2)      = h0;
      *(bf16x8*)(Ash + ar * 128 + ac0 * 2 + 16) = h1;
      *(bf16x8*)(Asl + ar * 128 + ac0 * 2)      = l0;
      *(bf16x8*)(Asl + ar * 128 + ac0 * 2 + 16) = l1;
    }
    stage_tile(pBh + kt, 1024, Bsh, 8192, tid);
    stage_tile(pBl + kt, 1024, Bsl, 8192, tid);
    __syncthreads();
#pragma unroll
    for (int p = 0; p < 3; ++p) {
      const char* As = (p == 2) ? Asl : Ash;
      const char* Bs = (p == 1) ? Bsl : Bsh;
#pragma unroll
      for (int ks = 0; ks < 2; ++ks) {
        const int ko = ks * 64 + (lane >> 4) * 16;
        bf16x8 av = *(const bf16x8*)(As + (wv * 16 + (lane & 15)) * 128 + ko);
#pragma unroll
        for (int n = 0; n < 4; ++n) {
          bf16x8 bv = *(const bf16x8*)(Bs + (n * 16 + (lane & 15)) * 128 + ko);
          acc[n] = __builtin_amdgcn_mfma_f32_16x16x32_bf16(av, bv, acc[n], 0, 0, 0);
        }
      }
    }
  }

  const int b = z / 12, h = z - b * 12;
#pragma unroll
  for (int n = 0; n < 4; ++n)
#pragma unroll
    for (int r = 0; r < 4; ++r) {
      const int row = mt * 64 + wv * 16 + (lane >> 4) * 4 + r;
      const int col = n * 16 + (lane & 15);
      const long addr = ((long)(b * 1024 + row)) * 768 + h * 64 + col;
      const float v = acc[n][r];
      const bf16 hi = (bf16)v;
      oh[addr] = hi;
      ol[addr] = (bf16)(v - (float)hi);
    }
}

// ---------------------------------------------------------------------------
// Elementwise helpers
// ---------------------------------------------------------------------------
__global__ void cast_split(const float* __restrict__ s, bf16* __restrict__ dh,
                           bf16* __restrict__ dl, int n)
{
  const int i = blockIdx.x * 256 + threadIdx.x;
  if (i < n) {
    const float x = s[i];
    const bf16 hi = (bf16)x;
    dh[i] = hi;
    if (dl) dl[i] = (bf16)(x - (float)hi);
  }
}

// LayerNorm over rows of 768; writes bf16 hi (+ optional lo, + optional f32).
__global__ __launch_bounds__(256) void ln_row(
    const float* __restrict__ in, const float* __restrict__ w,
    const float* __restrict__ b, bf16* __restrict__ outh,
    bf16* __restrict__ outl, float* __restrict__ outf)
{
  __shared__ float red[256];
  const int row = blockIdx.x, tid = threadIdx.x;
  const float* p = in + (long)row * 768;
  const float v0 = p[tid], v1 = p[tid + 256], v2 = p[tid + 512];
  red[tid] = v0 + v1 + v2;
  __syncthreads();
  for (int st = 128; st > 0; st >>= 1) { if (tid < st) red[tid] += red[tid + st]; __syncthreads(); }
  const float mu = red[0] * (1.0f / 768.0f);
  __syncthreads();
  const float d0 = v0 - mu, d1 = v1 - mu, d2 = v2 - mu;
  red[tid] = d0 * d0 + d1 * d1 + d2 * d2;
  __syncthreads();
  for (int st = 128; st > 0; st >>= 1) { if (tid < st) red[tid] += red[tid + st]; __syncthreads(); }
  const float rs = rsqrtf(red[0] * (1.0f / 768.0f) + 1e-5f);
  const float dv[3] = {d0, d1, d2};
#pragma unroll
  for (int k = 0; k < 3; ++k) {
    const int c = tid + k * 256;
    const float h = dv[k] * rs * w[c] + b[c];
    const bf16 hi = (bf16)h;
    outh[(long)row * 768 + c] = hi;
    if (outl) outl[(long)row * 768 + c] = (bf16)(h - (float)hi);
    if (outf) outf[(long)row * 768 + c] = h;
  }
}

// Per (b,n): normalize q,k head-vectors -> (q/||q||)^2 split bf16 (B,H,N,D);
// v -> f32 (B,H,N,D).
__global__ __launch_bounds__(256) void qkv_post(
    const float* __restrict__ qkv, bf16* __restrict__ q2h, bf16* __restrict__ q2l,
    bf16* __restrict__ k2h, bf16* __restrict__ k2l, float* __restrict__ vf)
{
  const int row = blockIdx.x;           // b*1024+n
  const int b = row >> 10, n = row & 1023;
  const int wv = threadIdx.x >> 6, lane = threadIdx.x & 63;
  for (int t = wv; t < 36; t += 4) {
    const int s = t / 12, h = t - s * 12;
    const float val = qkv[(long)row * 2304 + s * 768 + h * 64 + lane];
    const long addr = (((long)(b * 12 + h)) * 1024 + n) * 64 + lane;
    if (s == 2) {
      vf[addr] = val;
    } else {
      const float sq = val * val;
      float tot = sq;
#pragma unroll
      for (int d = 1; d < 64; d <<= 1) tot += __shfl_xor(tot, d);
      const float q2 = sq / tot;
      const bf16 hi = (bf16)q2;
      const bf16 lo = (bf16)(q2 - (float)hi);
      if (s == 0) { q2h[addr] = hi; q2l[addr] = lo; }
      else        { k2h[addr] = hi; k2l[addr] = lo; }
    }
  }
}

// v (B,H,N,D) f32 -> vT (B,H,D,N) split bf16, 64x64 tiles.
__global__ __launch_bounds__(256) void transpose_v(
    const float* __restrict__ vf, bf16* __restrict__ vth, bf16* __restrict__ vtl)
{
  __shared__ float t[64][65];
  const int z = blockIdx.y, n0 = blockIdx.x * 64, tid = threadIdx.x;
  const float* srcp = vf + ((long)z * 1024 + n0) * 64;
  for (int e = tid; e < 4096; e += 256) t[e >> 6][e & 63] = srcp[e];
  __syncthreads();
  for (int e = tid; e < 4096; e += 256) {
    const int d = e >> 6, c = e & 63;
    const float v = t[c][d];
    const bf16 hi = (bf16)v;
    const long a = ((long)z * 64 + d) * 1024 + n0 + c;
    vth[a] = hi;
    vtl[a] = (bf16)(v - (float)hi);
  }
}

// Gram partials: Gq += q2^T q2 (64x64), Gk likewise; Sq/Sk column sums.
__global__ __launch_bounds__(256) void stats_accum(
    const bf16* __restrict__ q2h, const bf16* __restrict__ q2l,
    const bf16* __restrict__ k2h, const bf16* __restrict__ k2l,
    float* __restrict__ Gq, float* __restrict__ Gk,
    float* __restrict__ Sq, float* __restrict__ Sk)
{
  __shared__ float rowbuf[128];
  const int tid = threadIdx.x;
  const int z = blockIdx.y;
  const long base = ((long)z * 1024 + (long)blockIdx.x * 128) * 64;
  const int tx = tid & 15, ty = tid >> 4;
  float gq[4][4] = {}, gk[4][4] = {};
  float sq = 0.f, sk = 0.f;
  for (int r = 0; r < 128; ++r) {
    if (tid < 64)
      rowbuf[tid] = (float)q2h[base + r * 64 + tid] + (float)q2l[base + r * 64 + tid];
    else if (tid < 128)
      rowbuf[tid] = (float)k2h[base + r * 64 + tid - 64] + (float)k2l[base + r * 64 + tid - 64];
    __syncthreads();
    float qa[4], qe[4], ka[4], ke[4];
#pragma unroll
    for (int i = 0; i < 4; ++i) {
      qa[i] = rowbuf[ty * 4 + i]; qe[i] = rowbuf[tx * 4 + i];
      ka[i] = rowbuf[64 + ty * 4 + i]; ke[i] = rowbuf[64 + tx * 4 + i];
    }
#pragma unroll
    for (int i = 0; i < 4; ++i)
#pragma unroll
      for (int j = 0; j < 4; ++j) {
        gq[i][j] += qa[i] * qe[j];
        gk[i][j] += ka[i] * ke[j];
      }
    if (tid < 64) sq += rowbuf[tid];
    else if (tid < 128) sk += rowbuf[tid];
    __syncthreads();
  }
#pragma unroll
  for (int i = 0; i < 4; ++i)
#pragma unroll
    for (int j = 0; j < 4; ++j) {
      atomicAdd(&Gq[(long)z * 4096 + (ty * 4 + i) * 64 + tx * 4 + j], gq[i][j]);
      atomicAdd(&Gk[(long)z * 4096 + (ty * 4 + i) * 64 + tx * 4 + j], gk[i][j]);
    }
  if (tid < 64) atomicAdd(&Sq[z * 64 + tid], sq);
  else if (tid < 128) atomicAdd(&Sk[z * 64 + tid - 64], sk);
}

// Per-batch mean / rstd of the attn tensor from Gram partials.
__global__ __launch_bounds__(256) void stats_final(
    const float* __restrict__ Gq, const float* __restrict__ Gk,
    const float* __restrict__ Sq, const float* __restrict__ Sk,
    float* __restrict__ stats)
{
  __shared__ double red[256];
  const int b = blockIdx.x, tid = threadIdx.x;
  double s2 = 0.0, s1 = 0.0;
  for (int h = 0; h < 12; ++h) {
    const float* gq = Gq + ((long)(b * 12 + h)) * 4096;
    const float* gk = Gk + ((long)(b * 12 + h)) * 4096;
    for (int i = tid; i < 4096; i += 256) s2 += (double)gq[i] * (double)gk[i];
    const float* sqp = Sq + (b * 12 + h) * 64;
    const float* skp = Sk + (b * 12 + h) * 64;
    for (int i = tid; i < 64; i += 256) s1 += (double)sqp[i] * (double)skp[i];
  }
  red[tid] = s2; __syncthreads();
  for (int st = 128; st > 0; st >>= 1) { if (tid < st) red[tid] += red[tid + st]; __syncthreads(); }
  const double S2 = red[0]; __syncthreads();
  red[tid] = s1; __syncthreads();
  for (int st = 128; st > 0; st >>= 1) { if (tid < st) red[tid] += red[tid + st]; __syncthreads(); }
  if (tid == 0) {
    const double S1 = red[0];
    const double cnt = 12.0 * 1024.0 * 1024.0;
    const double mean = S1 / cnt;
    const double var = S2 / cnt - mean * mean;
    stats[2 * b] = (float)mean;
    stats[2 * b + 1] = (float)(1.0 / sqrt(var + 1e-5));
  }
}

// ---------------------------------------------------------------------------
extern "C" void kernel_launch(void* const* d_in, const int* in_sizes, int n_in,
                              void* d_out, int out_size, void* d_ws, size_t ws_size,
                              hipStream_t stream)
{
  const float* x      = (const float*)d_in[0];
  const float* ln0_w  = (const float*)d_in[1];
  const float* ln0_b  = (const float*)d_in[2];
  const float* qkv_w  = (const float*)d_in[3];
  const float* qkv_b  = (const float*)d_in[4];
  const float* proj_w = (const float*)d_in[5];
  const float* proj_b = (const float*)d_in[6];
  const float* attn_w = (const float*)d_in[7];
  const float* attn_b = (const float*)d_in[8];
  const float* ln1_w  = (const float*)d_in[9];
  const float* ln1_b  = (const float*)d_in[10];
  const float* fc1_w  = (const float*)d_in[11];
  const float* fc1_b  = (const float*)d_in[12];
  const float* fc2_w  = (const float*)d_in[13];
  const float* fc2_b  = (const float*)d_in[14];

  float* out_src  = (float*)d_out;
  float* out_attn = out_src + 4L * 1024 * 768;       // 3145728

  char* p = (char*)d_ws;
  auto take = [&](long bytes) -> char* {
    char* r = p;
    p += (bytes + 255) & ~255L;
    return r;
  };
  bf16* qkvw_h = (bf16*)take(3538944);
  bf16* qkvw_l = (bf16*)take(3538944);
  bf16* projw_h = (bf16*)take(1179648);
  bf16* projw_l = (bf16*)take(1179648);
  bf16* fc1w_h = (bf16*)take(4718592);
  bf16* fc2w_h = (bf16*)take(4718592);
  char* regB = take(12582912);                 // hh+hl, later src_f32
  bf16* hh = (bf16*)regB;
  bf16* hl = (bf16*)(regB + 6291456);
  float* src = (float*)regB;
  char* regC = take(37748736);                 // qkv f32, later gelu acts + ln1f
  float* qkvf = (float*)regC;
  bf16* gact = (bf16*)regC;                    // [0, 25165824) bf16 4096x3072
  float* ln1f = (float*)(regC + 25165824);     // [25165824, 37748736) f32 4096x768
  bf16* q2h = (bf16*)take(6291456);
  bf16* q2l = (bf16*)take(6291456);
  bf16* k2h = (bf16*)take(6291456);
  bf16* k2l = (bf16*)take(6291456);
  bf16* vth = (bf16*)take(6291456);
  bf16* vtl = (bf16*)take(6291456);
  char* regF = take(12582912);                 // v f32, later oh+ol
  float* vf = (float*)regF;
  bf16* oh = (bf16*)regF;
  bf16* ol = (bf16*)(regF + 6291456);
  bf16* h1v = (bf16*)take(6291456);
  float* Gq = (float*)take(786432);
  float* Gk = (float*)take(786432);
  float* Sq = (float*)take(12288);
  float* Sk = (float*)take(12288);
  float* stats = (float*)take(256);

  const dim3 blk(256);

  (void)hipMemsetAsync((void*)Gq, 0, 786432 * 2 + 12288 * 2 + 256, stream);

  cast_split<<<dim3((1769472 + 255) / 256), blk, 0, stream>>>(qkv_w, qkvw_h, qkvw_l, 1769472);
  cast_split<<<dim3((589824 + 255) / 256), blk, 0, stream>>>(proj_w, projw_h, projw_l, 589824);
  cast_split<<<dim3((2359296 + 255) / 256), blk, 0, stream>>>(fc1_w, fc1w_h, nullptr, 2359296);
  cast_split<<<dim3((2359296 + 255) / 256), blk, 0, stream>>>(fc2_w, fc2w_h, nullptr, 2359296);

  ln_row<<<dim3(4096), blk, 0, stream>>>(x, ln0_w, ln0_b, hh, hl, nullptr);

  gemm_k<128, 128, 2, 4, 4, 3, EpiQKV><<<dim3(18, 32, 1), blk, 0, stream>>>(
      hh, hl, 0, qkvw_h, qkvw_l, 0, 768, 768, 768, EpiQKV{qkv_b, qkvf});

  qkv_post<<<dim3(4096), blk, 0, stream>>>(qkvf, q2h, q2l, k2h, k2l, vf);
  transpose_v<<<dim3(16, 48), blk, 0, stream>>>(vf, vth, vtl);
  stats_accum<<<dim3(8, 48), blk, 0, stream>>>(q2h, q2l, k2h, k2l, Gq, Gk, Sq, Sk);
  stats_final<<<dim3(4), blk, 0, stream>>>(Gq, Gk, Sq, Sk, stats);

  gemm_k<128, 128, 2, 4, 4, 3, EpiAttn><<<dim3(8, 8, 48), blk, 0, stream>>>(
      q2h, q2l, 65536, k2h, k2l, 65536, 64, 64, 64, EpiAttn{stats, attn_w, attn_b, out_attn});

  gemm_pv<<<dim3(16, 48), blk, 0, stream>>>(out_attn, vth, vtl, oh, ol);

  gemm_k<128, 64, 2, 4, 2, 3, EpiProj><<<dim3(12, 32, 1), blk, 0, stream>>>(
      oh, ol, 0, projw_h, projw_l, 0, 768, 768, 768, EpiProj{proj_b, x, src});

  ln_row<<<dim3(4096), blk, 0, stream>>>(src, ln1_w, ln1_b, h1v, nullptr, ln1f);

  gemm_k<128, 128, 2, 4, 4, 1, EpiGelu><<<dim3(24, 32, 1), blk, 0, stream>>>(
      h1v, nullptr, 0, fc1w_h, nullptr, 0, 768, 768, 768, EpiGelu{fc1_b, gact});

  gemm_k<128, 64, 2, 4, 2, 1, EpiOut><<<dim3(12, 32, 1), blk, 0, stream>>>(
      gact, nullptr, 0, fc2w_h, nullptr, 0, 3072, 3072, 3072, EpiOut{fc2_b, ln1f, out_src});
}

// Round 3
// 609.908 us; speedup vs baseline: 1.1663x; 1.1663x over previous
//
#include <hip/hip_runtime.h>

typedef __bf16 bf16;
typedef __bf16 bf16x4 __attribute__((ext_vector_type(4)));
typedef __bf16 bf16x8 __attribute__((ext_vector_type(8)));
typedef float f32x4 __attribute__((ext_vector_type(4)));

#define DEVI __device__ __forceinline__

typedef const __attribute__((address_space(1))) void* gas1;
typedef __attribute__((address_space(3))) void* las3;

// ---------------------------------------------------------------------------
// Stage a [rows x 64] bf16 tile (row bytes = 128) into LDS via global_load_lds.
// 256 threads = 4 waves; each wave DMA's 1KB chunks (lane*16 appended by HW).
// ---------------------------------------------------------------------------
DEVI void stage_tile(const bf16* g, int ld, char* lds, int bytes, int tid)
{
  const int wv = tid >> 6, lane = tid & 63;
  const char* gb = (const char*)g;
  const long rowb = (long)ld * 2;
  for (int off = wv * 1024; off < bytes; off += 4096) {
    const int o  = off + lane * 16;
    const int r  = o >> 7;      // 128B per tile row
    const int cb = o & 127;
    __builtin_amdgcn_global_load_lds((gas1)(gb + (long)r * rowb + cb),
                                     (las3)(lds + off), 16, 0, 0);
  }
}

// ---------------------------------------------------------------------------
// Epilogue functors
// ---------------------------------------------------------------------------
struct EpiQKV {
  const float* bias; float* C;
  DEVI void operator()(int z, int row, int col, float v) const {
    C[(long)row * 2304 + col] = v + bias[col];
  }
};

struct EpiProj {
  const float* bias; const float* x; float* src;
  DEVI void operator()(int z, int row, int col, float v) const {
    const long i = (long)row * 768 + col;
    src[i] = v + bias[col] + x[i];
  }
};

struct EpiGelu {
  const float* bias; bf16* g;
  DEVI void operator()(int z, int row, int col, float v) const {
    const float t = v + bias[col];
    const float r = 0.5f * t * (1.0f + erff(t * 0.70710678118654752f));
    g[(long)row * 3072 + col] = (bf16)r;
  }
};

struct EpiOut {
  const float* bias; const float* lnf; float* outp;
  DEVI void operator()(int z, int row, int col, float v) const {
    const long i = (long)row * 768 + col;
    outp[i] = v + bias[col] + lnf[i];   // final residual uses POST-LN1 src
  }
};

// ---------------------------------------------------------------------------
// Generic split-bf16 GEMM: C[M,N] = sum_pass A_p @ B_p^T, B stored [N][K].
// NPASS==3: (Ah,Bh)+(Ah,Bl)+(Al,Bh).  NPASS==1: (Ah,Bh) only.
// 256 threads = 4 waves arranged 2 x WC; per-wave FM x FN 16x16 fragments.
// ---------------------------------------------------------------------------
template<int BM, int BN, int WC, int FM, int FN, int NPASS, class Epi>
__global__ __launch_bounds__(256, 2) void gemm_k(
    const bf16* __restrict__ Ah, const bf16* __restrict__ Al, long abatch,
    const bf16* __restrict__ Bh, const bf16* __restrict__ Bl, long bbatch,
    int lda, int ldb, int K, Epi epi)
{
  constexpr int BK = 64;
  constexpr int AB = BM * BK * 2, BB = BN * BK * 2;
  constexpr int NBUF = (NPASS > 1) ? 2 : 1;
  __shared__ char smem[NBUF * (AB + BB)];
  char* Ash = smem;
  char* Asl = smem + AB;
  char* Bsh = smem + NBUF * AB;
  char* Bsl = Bsh + BB;

  const int tid = threadIdx.x, lane = tid & 63, wv = tid >> 6;
  const int wr = wv / WC, wc = wv % WC;
  const int mt = blockIdx.y, nt = blockIdx.x, z = blockIdx.z;
  const long abase = (long)z * abatch + (long)mt * BM * lda;
  const long bbase = (long)z * bbatch + (long)nt * BN * ldb;

  f32x4 acc[FM][FN];
#pragma unroll
  for (int m = 0; m < FM; ++m)
#pragma unroll
    for (int n = 0; n < FN; ++n) acc[m][n] = f32x4{0.f, 0.f, 0.f, 0.f};

  const int arow = wr * FM * 16, bcol = wc * FN * 16;

  for (int kt = 0; kt < K; kt += BK) {
    __syncthreads();
    stage_tile(Ah + abase + kt, lda, Ash, AB, tid);
    if (NPASS > 1) stage_tile(Al + abase + kt, lda, Asl, AB, tid);
    stage_tile(Bh + bbase + kt, ldb, Bsh, BB, tid);
    if (NPASS > 1) stage_tile(Bl + bbase + kt, ldb, Bsl, BB, tid);
    __syncthreads();
#pragma unroll
    for (int p = 0; p < NPASS; ++p) {
      const char* As = (p == 2) ? Asl : Ash;
      const char* Bs = (p == 1) ? Bsl : Bsh;
#pragma unroll
      for (int ks = 0; ks < 2; ++ks) {
        const int ko = ks * 64 + (lane >> 4) * 16;
        bf16x8 av[FM], bv[FN];
#pragma unroll
        for (int m = 0; m < FM; ++m)
          av[m] = *(const bf16x8*)(As + (arow + m * 16 + (lane & 15)) * 128 + ko);
#pragma unroll
        for (int n = 0; n < FN; ++n)
          bv[n] = *(const bf16x8*)(Bs + (bcol + n * 16 + (lane & 15)) * 128 + ko);
#pragma unroll
        for (int m = 0; m < FM; ++m)
#pragma unroll
          for (int n = 0; n < FN; ++n)
            acc[m][n] = __builtin_amdgcn_mfma_f32_16x16x32_bf16(av[m], bv[n], acc[m][n], 0, 0, 0);
      }
    }
  }

#pragma unroll
  for (int m = 0; m < FM; ++m)
#pragma unroll
    for (int n = 0; n < FN; ++n)
#pragma unroll
      for (int r = 0; r < 4; ++r) {
        const int grow = mt * BM + arow + m * 16 + (lane >> 4) * 4 + r;
        const int gcol = nt * BN + bcol + n * 16 + (lane & 15);
        epi(z, grow, gcol, acc[m][n][r]);
      }
}

// ---------------------------------------------------------------------------
// Fused attention tail: per workgroup = (row-strip of 64, z=(b,h)).
//   loop over 16 col-tiles of 64:
//     QK^T (3-pass split bf16) -> raw scores to LDS ->
//     coalesced LN pass (f32x4 wn/bn loads, f32x4 attn store, bf16 h/l of P
//     back to LDS) -> PV MFMA accumulate (3-pass) in registers.
// Epilogue: write o (B,N,C layout) as split bf16 for the proj GEMM.
// LDS = 80KB -> 2 blocks/CU.
// ---------------------------------------------------------------------------
__global__ __launch_bounds__(256, 2) void attn_fused(
    const bf16* __restrict__ q2h, const bf16* __restrict__ q2l,
    const bf16* __restrict__ k2h, const bf16* __restrict__ k2l,
    const bf16* __restrict__ vth, const bf16* __restrict__ vtl,
    const float* __restrict__ stats, const float* __restrict__ wn,
    const float* __restrict__ bn, float* __restrict__ attn_out,
    bf16* __restrict__ oh, bf16* __restrict__ ol)
{
  __shared__ char smem[81920];
  char* Qh = smem;                    //  8KB  64x64 bf16
  char* Ql = smem + 8192;
  char* Kh = smem + 16384;
  char* Kl = smem + 24576;
  char* Vh = smem + 32768;
  char* Vl = smem + 40960;
  float* Pf = (float*)(smem + 49152); // 16KB  64x64 f32 raw scores
  char* Ph = smem + 65536;
  char* Pl = smem + 73728;

  const int tid = threadIdx.x, lane = tid & 63, wv = tid >> 6;
  const int wr = wv >> 1, wc = wv & 1;
  const int mt = blockIdx.x, z = blockIdx.y;
  const int b = z / 12, h = z - b * 12;
  const float mu = stats[2 * b], rs = stats[2 * b + 1];

  const long zoff = (long)z * 65536;
  stage_tile(q2h + zoff + (long)mt * 64 * 64, 64, Qh, 8192, tid);
  stage_tile(q2l + zoff + (long)mt * 64 * 64, 64, Ql, 8192, tid);

  f32x4 oacc[2][2];
#pragma unroll
  for (int m = 0; m < 2; ++m)
#pragma unroll
    for (int n = 0; n < 2; ++n) oacc[m][n] = f32x4{0.f, 0.f, 0.f, 0.f};

  for (int nt = 0; nt < 16; ++nt) {
    __syncthreads();   // previous PV done before overwriting K/V/P
    stage_tile(k2h + zoff + (long)nt * 64 * 64, 64, Kh, 8192, tid);
    stage_tile(k2l + zoff + (long)nt * 64 * 64, 64, Kl, 8192, tid);
    stage_tile(vth + zoff + nt * 64, 1024, Vh, 8192, tid);
    stage_tile(vtl + zoff + nt * 64, 1024, Vl, 8192, tid);
    __syncthreads();

    // ---- QK^T: scores[i (64), j (64)] = sum_d q2[i,d] k2[j,d], 3-pass ----
    f32x4 acc[2][2];
#pragma unroll
    for (int m = 0; m < 2; ++m)
#pragma unroll
      for (int n = 0; n < 2; ++n) acc[m][n] = f32x4{0.f, 0.f, 0.f, 0.f};
#pragma unroll
    for (int p = 0; p < 3; ++p) {
      const char* As = (p == 2) ? Ql : Qh;
      const char* Bs = (p == 1) ? Kl : Kh;
#pragma unroll
      for (int ks = 0; ks < 2; ++ks) {
        const int ko = ks * 64 + (lane >> 4) * 16;
        bf16x8 av[2], bv[2];
#pragma unroll
        for (int m = 0; m < 2; ++m)
          av[m] = *(const bf16x8*)(As + (wr * 32 + m * 16 + (lane & 15)) * 128 + ko);
#pragma unroll
        for (int n = 0; n < 2; ++n)
          bv[n] = *(const bf16x8*)(Bs + (wc * 32 + n * 16 + (lane & 15)) * 128 + ko);
#pragma unroll
        for (int m = 0; m < 2; ++m)
#pragma unroll
          for (int n = 0; n < 2; ++n)
            acc[m][n] = __builtin_amdgcn_mfma_f32_16x16x32_bf16(av[m], bv[n], acc[m][n], 0, 0, 0);
      }
    }
    // raw scores -> LDS
#pragma unroll
    for (int m = 0; m < 2; ++m)
#pragma unroll
      for (int n = 0; n < 2; ++n)
#pragma unroll
        for (int r = 0; r < 4; ++r) {
          const int i = wr * 32 + m * 16 + (lane >> 4) * 4 + r;
          const int j = wc * 32 + n * 16 + (lane & 15);
          Pf[i * 64 + j] = acc[m][n][r];
        }
    __syncthreads();

    // ---- LN pass: coalesced. thread t: row rr*16+(t>>4), cols (t&15)*4 ----
    {
      const int lr = tid >> 4, c0 = (tid & 15) * 4;
#pragma unroll
      for (int rr = 0; rr < 4; ++rr) {
        const int row = rr * 16 + lr;
        const long grow = (long)mt * 64 + row;
        const long gcol = (long)nt * 64 + c0;
        const f32x4 s = *(const f32x4*)&Pf[row * 64 + c0];
        const f32x4 w4 = *(const f32x4*)&wn[((long)h * 1024 + grow) * 1024 + gcol];
        const f32x4 b4 = *(const f32x4*)&bn[((long)h * 1024 + grow) * 1024 + gcol];
        f32x4 r4;
        bf16x4 h4, l4;
#pragma unroll
        for (int e = 0; e < 4; ++e) {
          const float r = (s[e] - mu) * rs * w4[e] + b4[e];
          r4[e] = r;
          const bf16 hi = (bf16)r;
          h4[e] = hi;
          l4[e] = (bf16)(r - (float)hi);
        }
        *(f32x4*)&attn_out[((long)z * 1024 + grow) * 1024 + gcol] = r4;
        *(bf16x4*)(Ph + row * 128 + c0 * 2) = h4;
        *(bf16x4*)(Pl + row * 128 + c0 * 2) = l4;
      }
    }
    __syncthreads();

    // ---- PV: out[i, d] += sum_j p[i,j] vT[d,j], 3-pass ----
#pragma unroll
    for (int p = 0; p < 3; ++p) {
      const char* As = (p == 2) ? Pl : Ph;
      const char* Bs = (p == 1) ? Vl : Vh;
#pragma unroll
      for (int ks = 0; ks < 2; ++ks) {
        const int ko = ks * 64 + (lane >> 4) * 16;
        bf16x8 av[2], bv[2];
#pragma unroll
        for (int m = 0; m < 2; ++m)
          av[m] = *(const bf16x8*)(As + (wr * 32 + m * 16 + (lane & 15)) * 128 + ko);
#pragma unroll
        for (int n = 0; n < 2; ++n)
          bv[n] = *(const bf16x8*)(Bs + (wc * 32 + n * 16 + (lane & 15)) * 128 + ko);
#pragma unroll
        for (int m = 0; m < 2; ++m)
#pragma unroll
          for (int n = 0; n < 2; ++n)
            oacc[m][n] = __builtin_amdgcn_mfma_f32_16x16x32_bf16(av[m], bv[n], oacc[m][n], 0, 0, 0);
      }
    }
  }

  // ---- epilogue: o -> (B,N,C) split bf16 ----
#pragma unroll
  for (int m = 0; m < 2; ++m)
#pragma unroll
    for (int n = 0; n < 2; ++n)
#pragma unroll
      for (int r = 0; r < 4; ++r) {
        const int row = mt * 64 + wr * 32 + m * 16 + (lane >> 4) * 4 + r;
        const int col = wc * 32 + n * 16 + (lane & 15);
        const long addr = ((long)(b * 1024 + row)) * 768 + h * 64 + col;
        const float v = oacc[m][n][r];
        const bf16 hi = (bf16)v;
        oh[addr] = hi;
        ol[addr] = (bf16)(v - (float)hi);
      }
}

// ---------------------------------------------------------------------------
// Elementwise helpers
// ---------------------------------------------------------------------------
__global__ void cast_split(const float* __restrict__ s, bf16* __restrict__ dh,
                           bf16* __restrict__ dl, int n)
{
  const int i = blockIdx.x * 256 + threadIdx.x;
  if (i < n) {
    const float x = s[i];
    const bf16 hi = (bf16)x;
    dh[i] = hi;
    if (dl) dl[i] = (bf16)(x - (float)hi);
  }
}

// LayerNorm over rows of 768; writes bf16 hi (+ optional lo, + optional f32).
__global__ __launch_bounds__(256) void ln_row(
    const float* __restrict__ in, const float* __restrict__ w,
    const float* __restrict__ b, bf16* __restrict__ outh,
    bf16* __restrict__ outl, float* __restrict__ outf)
{
  __shared__ float red[256];
  const int row = blockIdx.x, tid = threadIdx.x;
  const float* p = in + (long)row * 768;
  const float v0 = p[tid], v1 = p[tid + 256], v2 = p[tid + 512];
  red[tid] = v0 + v1 + v2;
  __syncthreads();
  for (int st = 128; st > 0; st >>= 1) { if (tid < st) red[tid] += red[tid + st]; __syncthreads(); }
  const float mu = red[0] * (1.0f / 768.0f);
  __syncthreads();
  const float d0 = v0 - mu, d1 = v1 - mu, d2 = v2 - mu;
  red[tid] = d0 * d0 + d1 * d1 + d2 * d2;
  __syncthreads();
  for (int st = 128; st > 0; st >>= 1) { if (tid < st) red[tid] += red[tid + st]; __syncthreads(); }
  const float rs = rsqrtf(red[0] * (1.0f / 768.0f) + 1e-5f);
  const float dv[3] = {d0, d1, d2};
#pragma unroll
  for (int k = 0; k < 3; ++k) {
    const int c = tid + k * 256;
    const float h = dv[k] * rs * w[c] + b[c];
    const bf16 hi = (bf16)h;
    outh[(long)row * 768 + c] = hi;
    if (outl) outl[(long)row * 768 + c] = (bf16)(h - (float)hi);
    if (outf) outf[(long)row * 768 + c] = h;
  }
}

// Per (b,n): normalize q,k head-vectors -> (q/||q||)^2 split bf16 (B,H,N,D);
// v -> f32 (B,H,N,D).
__global__ __launch_bounds__(256) void qkv_post(
    const float* __restrict__ qkv, bf16* __restrict__ q2h, bf16* __restrict__ q2l,
    bf16* __restrict__ k2h, bf16* __restrict__ k2l, float* __restrict__ vf)
{
  const int row = blockIdx.x;           // b*1024+n
  const int b = row >> 10, n = row & 1023;
  const int wv = threadIdx.x >> 6, lane = threadIdx.x & 63;
  for (int t = wv; t < 36; t += 4) {
    const int s = t / 12, h = t - s * 12;
    const float val = qkv[(long)row * 2304 + s * 768 + h * 64 + lane];
    const long addr = (((long)(b * 12 + h)) * 1024 + n) * 64 + lane;
    if (s == 2) {
      vf[addr] = val;
    } else {
      const float sq = val * val;
      float tot = sq;
#pragma unroll
      for (int d = 1; d < 64; d <<= 1) tot += __shfl_xor(tot, d);
      const float q2 = sq / tot;
      const bf16 hi = (bf16)q2;
      const bf16 lo = (bf16)(q2 - (float)hi);
      if (s == 0) { q2h[addr] = hi; q2l[addr] = lo; }
      else        { k2h[addr] = hi; k2l[addr] = lo; }
    }
  }
}

// v (B,H,N,D) f32 -> vT (B,H,D,N) split bf16, 64x64 tiles.
__global__ __launch_bounds__(256) void transpose_v(
    const float* __restrict__ vf, bf16* __restrict__ vth, bf16* __restrict__ vtl)
{
  __shared__ float t[64][65];
  const int z = blockIdx.y, n0 = blockIdx.x * 64, tid = threadIdx.x;
  const float* srcp = vf + ((long)z * 1024 + n0) * 64;
  for (int e = tid; e < 4096; e += 256) t[e >> 6][e & 63] = srcp[e];
  __syncthreads();
  for (int e = tid; e < 4096; e += 256) {
    const int d = e >> 6, c = e & 63;
    const float v = t[c][d];
    const bf16 hi = (bf16)v;
    const long a = ((long)z * 64 + d) * 1024 + n0 + c;
    vth[a] = hi;
    vtl[a] = (bf16)(v - (float)hi);
  }
}

// Gram partials: Gq += q2^T q2 (64x64), Gk likewise; Sq/Sk column sums.
__global__ __launch_bounds__(256) void stats_accum(
    const bf16* __restrict__ q2h, const bf16* __restrict__ q2l,
    const bf16* __restrict__ k2h, const bf16* __restrict__ k2l,
    float* __restrict__ Gq, float* __restrict__ Gk,
    float* __restrict__ Sq, float* __restrict__ Sk)
{
  __shared__ float rowbuf[128];
  const int tid = threadIdx.x;
  const int z = blockIdx.y;
  const long base = ((long)z * 1024 + (long)blockIdx.x * 128) * 64;
  const int tx = tid & 15, ty = tid >> 4;
  float gq[4][4] = {}, gk[4][4] = {};
  float sq = 0.f, sk = 0.f;
  for (int r = 0; r < 128; ++r) {
    if (tid < 64)
      rowbuf[tid] = (float)q2h[base + r * 64 + tid] + (float)q2l[base + r * 64 + tid];
    else if (tid < 128)
      rowbuf[tid] = (float)k2h[base + r * 64 + tid - 64] + (float)k2l[base + r * 64 + tid - 64];
    __syncthreads();
    float qa[4], qe[4], ka[4], ke[4];
#pragma unroll
    for (int i = 0; i < 4; ++i) {
      qa[i] = rowbuf[ty * 4 + i]; qe[i] = rowbuf[tx * 4 + i];
      ka[i] = rowbuf[64 + ty * 4 + i]; ke[i] = rowbuf[64 + tx * 4 + i];
    }
#pragma unroll
    for (int i = 0; i < 4; ++i)
#pragma unroll
      for (int j = 0; j < 4; ++j) {
        gq[i][j] += qa[i] * qe[j];
        gk[i][j] += ka[i] * ke[j];
      }
    if (tid < 64) sq += rowbuf[tid];
    else if (tid < 128) sk += rowbuf[tid];
    __syncthreads();
  }
#pragma unroll
  for (int i = 0; i < 4; ++i)
#pragma unroll
    for (int j = 0; j < 4; ++j) {
      atomicAdd(&Gq[(long)z * 4096 + (ty * 4 + i) * 64 + tx * 4 + j], gq[i][j]);
      atomicAdd(&Gk[(long)z * 4096 + (ty * 4 + i) * 64 + tx * 4 + j], gk[i][j]);
    }
  if (tid < 64) atomicAdd(&Sq[z * 64 + tid], sq);
  else if (tid < 128) atomicAdd(&Sk[z * 64 + tid - 64], sk);
}

// Per-batch mean / rstd of the attn tensor from Gram partials.
__global__ __launch_bounds__(256) void stats_final(
    const float* __restrict__ Gq, const float* __restrict__ Gk,
    const float* __restrict__ Sq, const float* __restrict__ Sk,
    float* __restrict__ stats)
{
  __shared__ double red[256];
  const int b = blockIdx.x, tid = threadIdx.x;
  double s2 = 0.0, s1 = 0.0;
  for (int h = 0; h < 12; ++h) {
    const float* gq = Gq + ((long)(b * 12 + h)) * 4096;
    const float* gk = Gk + ((long)(b * 12 + h)) * 4096;
    for (int i = tid; i < 4096; i += 256) s2 += (double)gq[i] * (double)gk[i];
    const float* sqp = Sq + (b * 12 + h) * 64;
    const float* skp = Sk + (b * 12 + h) * 64;
    for (int i = tid; i < 64; i += 256) s1 += (double)sqp[i] * (double)skp[i];
  }
  red[tid] = s2; __syncthreads();
  for (int st = 128; st > 0; st >>= 1) { if (tid < st) red[tid] += red[tid + st]; __syncthreads(); }
  const double S2 = red[0]; __syncthreads();
  red[tid] = s1; __syncthreads();
  for (int st = 128; st > 0; st >>= 1) { if (tid < st) red[tid] += red[tid + st]; __syncthreads(); }
  if (tid == 0) {
    const double S1 = red[0];
    const double cnt = 12.0 * 1024.0 * 1024.0;
    const double mean = S1 / cnt;
    const double var = S2 / cnt - mean * mean;
    stats[2 * b] = (float)mean;
    stats[2 * b + 1] = (float)(1.0 / sqrt(var + 1e-5));
  }
}

// ---------------------------------------------------------------------------
extern "C" void kernel_launch(void* const* d_in, const int* in_sizes, int n_in,
                              void* d_out, int out_size, void* d_ws, size_t ws_size,
                              hipStream_t stream)
{
  const float* x      = (const float*)d_in[0];
  const float* ln0_w  = (const float*)d_in[1];
  const float* ln0_b  = (const float*)d_in[2];
  const float* qkv_w  = (const float*)d_in[3];
  const float* qkv_b  = (const float*)d_in[4];
  const float* proj_w = (const float*)d_in[5];
  const float* proj_b = (const float*)d_in[6];
  const float* attn_w = (const float*)d_in[7];
  const float* attn_b = (const float*)d_in[8];
  const float* ln1_w  = (const float*)d_in[9];
  const float* ln1_b  = (const float*)d_in[10];
  const float* fc1_w  = (const float*)d_in[11];
  const float* fc1_b  = (const float*)d_in[12];
  const float* fc2_w  = (const float*)d_in[13];
  const float* fc2_b  = (const float*)d_in[14];

  float* out_src  = (float*)d_out;
  float* out_attn = out_src + 4L * 1024 * 768;       // 3145728

  char* p = (char*)d_ws;
  auto take = [&](long bytes) -> char* {
    char* r = p;
    p += (bytes + 255) & ~255L;
    return r;
  };
  bf16* qkvw_h = (bf16*)take(3538944);
  bf16* qkvw_l = (bf16*)take(3538944);
  bf16* projw_h = (bf16*)take(1179648);
  bf16* projw_l = (bf16*)take(1179648);
  bf16* fc1w_h = (bf16*)take(4718592);
  bf16* fc2w_h = (bf16*)take(4718592);
  char* regB = take(12582912);                 // hh+hl, later src_f32
  bf16* hh = (bf16*)regB;
  bf16* hl = (bf16*)(regB + 6291456);
  float* src = (float*)regB;
  char* regC = take(37748736);                 // qkv f32, later gelu acts + ln1f
  float* qkvf = (float*)regC;
  bf16* gact = (bf16*)regC;                    // [0, 25165824) bf16 4096x3072
  float* ln1f = (float*)(regC + 25165824);     // [25165824, 37748736) f32 4096x768
  bf16* q2h = (bf16*)take(6291456);
  bf16* q2l = (bf16*)take(6291456);
  bf16* k2h = (bf16*)take(6291456);
  bf16* k2l = (bf16*)take(6291456);
  bf16* vth = (bf16*)take(6291456);
  bf16* vtl = (bf16*)take(6291456);
  char* regF = take(12582912);                 // v f32, later oh+ol
  float* vf = (float*)regF;
  bf16* oh = (bf16*)regF;
  bf16* ol = (bf16*)(regF + 6291456);
  bf16* h1v = (bf16*)take(6291456);
  float* Gq = (float*)take(786432);
  float* Gk = (float*)take(786432);
  float* Sq = (float*)take(12288);
  float* Sk = (float*)take(12288);
  float* stats = (float*)take(256);

  const dim3 blk(256);

  (void)hipMemsetAsync((void*)Gq, 0, 786432 * 2 + 12288 * 2 + 256, stream);

  cast_split<<<dim3((1769472 + 255) / 256), blk, 0, stream>>>(qkv_w, qkvw_h, qkvw_l, 1769472);
  cast_split<<<dim3((589824 + 255) / 256), blk, 0, stream>>>(proj_w, projw_h, projw_l, 589824);
  cast_split<<<dim3((2359296 + 255) / 256), blk, 0, stream>>>(fc1_w, fc1w_h, nullptr, 2359296);
  cast_split<<<dim3((2359296 + 255) / 256), blk, 0, stream>>>(fc2_w, fc2w_h, nullptr, 2359296);

  ln_row<<<dim3(4096), blk, 0, stream>>>(x, ln0_w, ln0_b, hh, hl, nullptr);

  gemm_k<128, 128, 2, 4, 4, 3, EpiQKV><<<dim3(18, 32, 1), blk, 0, stream>>>(
      hh, hl, 0, qkvw_h, qkvw_l, 0, 768, 768, 768, EpiQKV{qkv_b, qkvf});

  qkv_post<<<dim3(4096), blk, 0, stream>>>(qkvf, q2h, q2l, k2h, k2l, vf);
  transpose_v<<<dim3(16, 48), blk, 0, stream>>>(vf, vth, vtl);
  stats_accum<<<dim3(8, 48), blk, 0, stream>>>(q2h, q2l, k2h, k2l, Gq, Gk, Sq, Sk);
  stats_final<<<dim3(4), blk, 0, stream>>>(Gq, Gk, Sq, Sk, stats);

  attn_fused<<<dim3(16, 48), blk, 0, stream>>>(
      q2h, q2l, k2h, k2l, vth, vtl, stats, attn_w, attn_b, out_attn, oh, ol);

  gemm_k<128, 64, 2, 4, 2, 3, EpiProj><<<dim3(12, 32, 1), blk, 0, stream>>>(
      oh, ol, 0, projw_h, projw_l, 0, 768, 768, 768, EpiProj{proj_b, x, src});

  ln_row<<<dim3(4096), blk, 0, stream>>>(src, ln1_w, ln1_b, h1v, nullptr, ln1f);

  gemm_k<128, 128, 2, 4, 4, 1, EpiGelu><<<dim3(24, 32, 1), blk, 0, stream>>>(
      h1v, nullptr, 0, fc1w_h, nullptr, 0, 768, 768, 768, EpiGelu{fc1_b, gact});

  gemm_k<128, 64, 2, 4, 2, 1, EpiOut><<<dim3(12, 32, 1), blk, 0, stream>>>(
      gact, nullptr, 0, fc2w_h, nullptr, 0, 3072, 3072, 3072, EpiOut{fc2_b, ln1f, out_src});
}

// Round 4
// 527.503 us; speedup vs baseline: 1.3485x; 1.1562x over previous
//
#include <hip/hip_runtime.h>

typedef __bf16 bf16;
typedef __bf16 bf16x4 __attribute__((ext_vector_type(4)));
typedef __bf16 bf16x8 __attribute__((ext_vector_type(8)));
typedef float f32x4 __attribute__((ext_vector_type(4)));

#define DEVI __device__ __forceinline__

typedef const __attribute__((address_space(1))) void* gas1;
typedef __attribute__((address_space(3))) void* las3;

// ---------------------------------------------------------------------------
// Stage a [rows x 64] bf16 tile (row bytes = 128) into LDS via global_load_lds,
// with st-style XOR swizzle: LDS[o] = data[o ^ ((row(o)&7)<<4)].
// Swizzle is an involution on byte bits 4-6 keyed by row bits (7-9), so the
// global SOURCE address is pre-swizzled (rule: linear dest + inv-swz source)
// and every ds_read applies the same XOR. 16-way bank conflict -> 2-way (free).
// ---------------------------------------------------------------------------
DEVI void stage_tile(const bf16* g, int ld, char* lds, int bytes, int tid)
{
  const int wv = tid >> 6, lane = tid & 63;
  const char* gb = (const char*)g;
  const long rowb = (long)ld * 2;
  for (int off = wv * 1024; off < bytes; off += 4096) {
    const int o  = off + lane * 16;                 // linear LDS dest
    const int s  = o ^ (((o >> 7) & 7) << 4);       // pre-swizzled source pos
    const int r  = s >> 7;                          // 128B per tile row
    const int cb = s & 127;
    __builtin_amdgcn_global_load_lds((gas1)(gb + (long)r * rowb + cb),
                                     (las3)(lds + off), 16, 0, 0);
  }
}

// ---------------------------------------------------------------------------
// Epilogue functors
// ---------------------------------------------------------------------------
struct EpiQKV {
  const float* bias; float* C;
  DEVI void operator()(int z, int row, int col, float v) const {
    C[(long)row * 2304 + col] = v + bias[col];
  }
};

struct EpiProj {
  const float* bias; const float* x; float* src;
  DEVI void operator()(int z, int row, int col, float v) const {
    const long i = (long)row * 768 + col;
    src[i] = v + bias[col] + x[i];
  }
};

struct EpiGelu {
  const float* bias; bf16* g;
  DEVI void operator()(int z, int row, int col, float v) const {
    const float t = v + bias[col];
    const float r = 0.5f * t * (1.0f + erff(t * 0.70710678118654752f));
    g[(long)row * 3072 + col] = (bf16)r;
  }
};

struct EpiOut {
  const float* bias; const float* lnf; float* outp;
  DEVI void operator()(int z, int row, int col, float v) const {
    const long i = (long)row * 768 + col;
    outp[i] = v + bias[col] + lnf[i];   // final residual uses POST-LN1 src
  }
};

// ---------------------------------------------------------------------------
// Generic split-bf16 GEMM: C[M,N] = sum_pass A_p @ B_p^T, B stored [N][K].
// NPASS==3: (Ah,Bh)+(Ah,Bl)+(Al,Bh).  NPASS==1: (Ah,Bh) only.
// 256 threads = 4 waves arranged 2 x WC; per-wave FM x FN 16x16 fragments.
// LDS tiles XOR-swizzled (see stage_tile).
// ---------------------------------------------------------------------------
template<int BM, int BN, int WC, int FM, int FN, int NPASS, int WPE, class Epi>
__global__ __launch_bounds__(256, WPE) void gemm_k(
    const bf16* __restrict__ Ah, const bf16* __restrict__ Al, long abatch,
    const bf16* __restrict__ Bh, const bf16* __restrict__ Bl, long bbatch,
    int lda, int ldb, int K, Epi epi)
{
  constexpr int BK = 64;
  constexpr int AB = BM * BK * 2, BB = BN * BK * 2;
  constexpr int NBUF = (NPASS > 1) ? 2 : 1;
  __shared__ char smem[NBUF * (AB + BB)];
  char* Ash = smem;
  char* Asl = smem + AB;
  char* Bsh = smem + NBUF * AB;
  char* Bsl = Bsh + BB;

  const int tid = threadIdx.x, lane = tid & 63, wv = tid >> 6;
  const int wr = wv / WC, wc = wv % WC;
  const int mt = blockIdx.y, nt = blockIdx.x, z = blockIdx.z;
  const long abase = (long)z * abatch + (long)mt * BM * lda;
  const long bbase = (long)z * bbatch + (long)nt * BN * ldb;
  const int l15 = lane & 15, l7 = lane & 7;
  const int sw = l7 << 4;                    // per-lane read swizzle

  f32x4 acc[FM][FN];
#pragma unroll
  for (int m = 0; m < FM; ++m)
#pragma unroll
    for (int n = 0; n < FN; ++n) acc[m][n] = f32x4{0.f, 0.f, 0.f, 0.f};

  const int arow = wr * FM * 16, bcol = wc * FN * 16;

  for (int kt = 0; kt < K; kt += BK) {
    __syncthreads();
    stage_tile(Ah + abase + kt, lda, Ash, AB, tid);
    if (NPASS > 1) stage_tile(Al + abase + kt, lda, Asl, AB, tid);
    stage_tile(Bh + bbase + kt, ldb, Bsh, BB, tid);
    if (NPASS > 1) stage_tile(Bl + bbase + kt, ldb, Bsl, BB, tid);
    __syncthreads();
#pragma unroll
    for (int p = 0; p < NPASS; ++p) {
      const char* As = (p == 2) ? Asl : Ash;
      const char* Bs = (p == 1) ? Bsl : Bsh;
#pragma unroll
      for (int ks = 0; ks < 2; ++ks) {
        const int ko = (ks * 64 + (lane >> 4) * 16) ^ sw;
        bf16x8 av[FM], bv[FN];
#pragma unroll
        for (int m = 0; m < FM; ++m)
          av[m] = *(const bf16x8*)(As + (arow + m * 16 + l15) * 128 + ko);
#pragma unroll
        for (int n = 0; n < FN; ++n)
          bv[n] = *(const bf16x8*)(Bs + (bcol + n * 16 + l15) * 128 + ko);
#pragma unroll
        for (int m = 0; m < FM; ++m)
#pragma unroll
          for (int n = 0; n < FN; ++n)
            acc[m][n] = __builtin_amdgcn_mfma_f32_16x16x32_bf16(av[m], bv[n], acc[m][n], 0, 0, 0);
      }
    }
  }

#pragma unroll
  for (int m = 0; m < FM; ++m)
#pragma unroll
    for (int n = 0; n < FN; ++n)
#pragma unroll
      for (int r = 0; r < 4; ++r) {
        const int grow = mt * BM + arow + m * 16 + (lane >> 4) * 4 + r;
        const int gcol = nt * BN + bcol + n * 16 + l15;
        epi(z, grow, gcol, acc[m][n][r]);
      }
}

// ---------------------------------------------------------------------------
// Fused attention tail: per workgroup = (row-strip of 64, z).
// z remapped: h = z>>2, b = z&3 so the 4 batches sharing wn[h]/bn[h] are
// dispatch-adjacent (L3 reuse of the 402MB wn/bn stream -> ~100MB fetch).
//   loop over 16 col-tiles of 64:
//     QK^T (3-pass split bf16, swizzled LDS) -> raw scores to swizzled Pf ->
//     coalesced LN pass (f32x4 wn/bn loads, f32x4 attn store, bf16 h/l of P
//     back to swizzled LDS) -> PV MFMA accumulate (3-pass) in registers.
// LDS = 80KB -> 2 blocks/CU.
// ---------------------------------------------------------------------------
__global__ __launch_bounds__(256, 2) void attn_fused(
    const bf16* __restrict__ q2h, const bf16* __restrict__ q2l,
    const bf16* __restrict__ k2h, const bf16* __restrict__ k2l,
    const bf16* __restrict__ vth, const bf16* __restrict__ vtl,
    const float* __restrict__ stats, const float* __restrict__ wn,
    const float* __restrict__ bn, float* __restrict__ attn_out,
    bf16* __restrict__ oh, bf16* __restrict__ ol)
{
  __shared__ char smem[81920];
  char* Qh = smem;                    //  8KB  64x64 bf16 (swizzled)
  char* Ql = smem + 8192;
  char* Kh = smem + 16384;
  char* Kl = smem + 24576;
  char* Vh = smem + 32768;
  char* Vl = smem + 40960;
  float* Pf = (float*)(smem + 49152); // 16KB  64x64 f32 raw scores (swizzled)
  char* Ph = smem + 65536;
  char* Pl = smem + 73728;

  const int tid = threadIdx.x, lane = tid & 63, wv = tid >> 6;
  const int wr = wv >> 1, wc = wv & 1;
  const int mt = blockIdx.x, z = blockIdx.y;
  const int h = z >> 2, b = z & 3;
  const int zq = b * 12 + h;
  const float mu = stats[2 * b], rs = stats[2 * b + 1];
  const int l15 = lane & 15, l7 = lane & 7;
  const int sw = l7 << 4;

  const long zoff = (long)zq * 65536;
  stage_tile(q2h + zoff + (long)mt * 64 * 64, 64, Qh, 8192, tid);
  stage_tile(q2l + zoff + (long)mt * 64 * 64, 64, Ql, 8192, tid);

  f32x4 oacc[2][2];
#pragma unroll
  for (int m = 0; m < 2; ++m)
#pragma unroll
    for (int n = 0; n < 2; ++n) oacc[m][n] = f32x4{0.f, 0.f, 0.f, 0.f};

  for (int nt = 0; nt < 16; ++nt) {
    __syncthreads();   // previous PV done before overwriting K/V/P
    stage_tile(k2h + zoff + (long)nt * 64 * 64, 64, Kh, 8192, tid);
    stage_tile(k2l + zoff + (long)nt * 64 * 64, 64, Kl, 8192, tid);
    stage_tile(vth + zoff + nt * 64, 1024, Vh, 8192, tid);
    stage_tile(vtl + zoff + nt * 64, 1024, Vl, 8192, tid);
    __syncthreads();

    // ---- QK^T: scores[i (64), j (64)] = sum_d q2[i,d] k2[j,d], 3-pass ----
    f32x4 acc[2][2];
#pragma unroll
    for (int m = 0; m < 2; ++m)
#pragma unroll
      for (int n = 0; n < 2; ++n) acc[m][n] = f32x4{0.f, 0.f, 0.f, 0.f};
#pragma unroll
    for (int p = 0; p < 3; ++p) {
      const char* As = (p == 2) ? Ql : Qh;
      const char* Bs = (p == 1) ? Kl : Kh;
#pragma unroll
      for (int ks = 0; ks < 2; ++ks) {
        const int ko = (ks * 64 + (lane >> 4) * 16) ^ sw;
        bf16x8 av[2], bv[2];
#pragma unroll
        for (int m = 0; m < 2; ++m)
          av[m] = *(const bf16x8*)(As + (wr * 32 + m * 16 + l15) * 128 + ko);
#pragma unroll
        for (int n = 0; n < 2; ++n)
          bv[n] = *(const bf16x8*)(Bs + (wc * 32 + n * 16 + l15) * 128 + ko);
#pragma unroll
        for (int m = 0; m < 2; ++m)
#pragma unroll
          for (int n = 0; n < 2; ++n)
            acc[m][n] = __builtin_amdgcn_mfma_f32_16x16x32_bf16(av[m], bv[n], acc[m][n], 0, 0, 0);
      }
    }
    // raw scores -> swizzled Pf: slot(i,j) = j ^ (((i^(i>>2))&7)<<2).
    // Write side varies i in steps of 4 ((i>>2) spreads); read side consecutive
    // rows ((i&2:0) spreads) -> both conflict-free.
#pragma unroll
    for (int m = 0; m < 2; ++m)
#pragma unroll
      for (int n = 0; n < 2; ++n)
#pragma unroll
        for (int r = 0; r < 4; ++r) {
          const int i = wr * 32 + m * 16 + (lane >> 4) * 4 + r;
          const int j = wc * 32 + n * 16 + l15;
          const int sp = ((i ^ (i >> 2)) & 7) << 2;
          Pf[i * 64 + (j ^ sp)] = acc[m][n][r];
        }
    __syncthreads();

    // ---- LN pass: coalesced. thread t: rows rr*16+(t>>4), cols (t&15)*4 ----
    {
      const int lr = tid >> 4, c0 = (tid & 15) * 4;
#pragma unroll
      for (int rr = 0; rr < 4; ++rr) {
        const int row = rr * 16 + lr;
        const int sp = ((row ^ (row >> 2)) & 7) << 2;
        const long grow = (long)mt * 64 + row;
        const long gcol = (long)nt * 64 + c0;
        const f32x4 s = *(const f32x4*)&Pf[row * 64 + (c0 ^ sp)];
        const f32x4 w4 = *(const f32x4*)&wn[((long)h * 1024 + grow) * 1024 + gcol];
        const f32x4 b4 = *(const f32x4*)&bn[((long)h * 1024 + grow) * 1024 + gcol];
        f32x4 r4;
        bf16x4 h4, l4;
#pragma unroll
        for (int e = 0; e < 4; ++e) {
          const float r = (s[e] - mu) * rs * w4[e] + b4[e];
          r4[e] = r;
          const bf16 hi = (bf16)r;
          h4[e] = hi;
          l4[e] = (bf16)(r - (float)hi);
        }
        *(f32x4*)&attn_out[((long)zq * 1024 + grow) * 1024 + gcol] = r4;
        const int pb = row * 128 + ((c0 * 2) ^ ((row & 7) << 4));
        *(bf16x4*)(Ph + pb) = h4;
        *(bf16x4*)(Pl + pb) = l4;
      }
    }
    __syncthreads();

    // ---- PV: out[i, d] += sum_j p[i,j] vT[d,j], 3-pass ----
#pragma unroll
    for (int p = 0; p < 3; ++p) {
      const char* As = (p == 2) ? Pl : Ph;
      const char* Bs = (p == 1) ? Vl : Vh;
#pragma unroll
      for (int ks = 0; ks < 2; ++ks) {
        const int ko = (ks * 64 + (lane >> 4) * 16) ^ sw;
        bf16x8 av[2], bv[2];
#pragma unroll
        for (int m = 0; m < 2; ++m)
          av[m] = *(const bf16x8*)(As + (wr * 32 + m * 16 + l15) * 128 + ko);
#pragma unroll
        for (int n = 0; n < 2; ++n)
          bv[n] = *(const bf16x8*)(Bs + (wc * 32 + n * 16 + l15) * 128 + ko);
#pragma unroll
        for (int m = 0; m < 2; ++m)
#pragma unroll
          for (int n = 0; n < 2; ++n)
            oacc[m][n] = __builtin_amdgcn_mfma_f32_16x16x32_bf16(av[m], bv[n], oacc[m][n], 0, 0, 0);
      }
    }
  }

  // ---- epilogue: o -> (B,N,C) split bf16 ----
#pragma unroll
  for (int m = 0; m < 2; ++m)
#pragma unroll
    for (int n = 0; n < 2; ++n)
#pragma unroll
      for (int r = 0; r < 4; ++r) {
        const int row = mt * 64 + wr * 32 + m * 16 + (lane >> 4) * 4 + r;
        const int col = wc * 32 + n * 16 + l15;
        const long addr = ((long)(b * 1024 + row)) * 768 + h * 64 + col;
        const float v = oacc[m][n][r];
        const bf16 hi = (bf16)v;
        oh[addr] = hi;
        ol[addr] = (bf16)(v - (float)hi);
      }
}

// ---------------------------------------------------------------------------
// Elementwise helpers
// ---------------------------------------------------------------------------
__global__ void cast_split(const float* __restrict__ s, bf16* __restrict__ dh,
                           bf16* __restrict__ dl, int n)
{
  const int i = blockIdx.x * 256 + threadIdx.x;
  if (i < n) {
    const float x = s[i];
    const bf16 hi = (bf16)x;
    dh[i] = hi;
    if (dl) dl[i] = (bf16)(x - (float)hi);
  }
}

// LayerNorm over rows of 768; writes bf16 hi (+ optional lo, + optional f32).
__global__ __launch_bounds__(256) void ln_row(
    const float* __restrict__ in, const float* __restrict__ w,
    const float* __restrict__ b, bf16* __restrict__ outh,
    bf16* __restrict__ outl, float* __restrict__ outf)
{
  __shared__ float red[256];
  const int row = blockIdx.x, tid = threadIdx.x;
  const float* p = in + (long)row * 768;
  const float v0 = p[tid], v1 = p[tid + 256], v2 = p[tid + 512];
  red[tid] = v0 + v1 + v2;
  __syncthreads();
  for (int st = 128; st > 0; st >>= 1) { if (tid < st) red[tid] += red[tid + st]; __syncthreads(); }
  const float mu = red[0] * (1.0f / 768.0f);
  __syncthreads();
  const float d0 = v0 - mu, d1 = v1 - mu, d2 = v2 - mu;
  red[tid] = d0 * d0 + d1 * d1 + d2 * d2;
  __syncthreads();
  for (int st = 128; st > 0; st >>= 1) { if (tid < st) red[tid] += red[tid + st]; __syncthreads(); }
  const float rs = rsqrtf(red[0] * (1.0f / 768.0f) + 1e-5f);
  const float dv[3] = {d0, d1, d2};
#pragma unroll
  for (int k = 0; k < 3; ++k) {
    const int c = tid + k * 256;
    const float h = dv[k] * rs * w[c] + b[c];
    const bf16 hi = (bf16)h;
    outh[(long)row * 768 + c] = hi;
    if (outl) outl[(long)row * 768 + c] = (bf16)(h - (float)hi);
    if (outf) outf[(long)row * 768 + c] = h;
  }
}

// Per (b,n): normalize q,k head-vectors -> (q/||q||)^2 split bf16 (B,H,N,D);
// v -> f32 (B,H,N,D).
__global__ __launch_bounds__(256) void qkv_post(
    const float* __restrict__ qkv, bf16* __restrict__ q2h, bf16* __restrict__ q2l,
    bf16* __restrict__ k2h, bf16* __restrict__ k2l, float* __restrict__ vf)
{
  const int row = blockIdx.x;           // b*1024+n
  const int b = row >> 10, n = row & 1023;
  const int wv = threadIdx.x >> 6, lane = threadIdx.x & 63;
  for (int t = wv; t < 36; t += 4) {
    const int s = t / 12, h = t - s * 12;
    const float val = qkv[(long)row * 2304 + s * 768 + h * 64 + lane];
    const long addr = (((long)(b * 12 + h)) * 1024 + n) * 64 + lane;
    if (s == 2) {
      vf[addr] = val;
    } else {
      const float sq = val * val;
      float tot = sq;
#pragma unroll
      for (int d = 1; d < 64; d <<= 1) tot += __shfl_xor(tot, d);
      const float q2 = sq / tot;
      const bf16 hi = (bf16)q2;
      const bf16 lo = (bf16)(q2 - (float)hi);
      if (s == 0) { q2h[addr] = hi; q2l[addr] = lo; }
      else        { k2h[addr] = hi; k2l[addr] = lo; }
    }
  }
}

// v (B,H,N,D) f32 -> vT (B,H,D,N) split bf16, 64x64 tiles.
__global__ __launch_bounds__(256) void transpose_v(
    const float* __restrict__ vf, bf16* __restrict__ vth, bf16* __restrict__ vtl)
{
  __shared__ float t[64][65];
  const int z = blockIdx.y, n0 = blockIdx.x * 64, tid = threadIdx.x;
  const float* srcp = vf + ((long)z * 1024 + n0) * 64;
  for (int e = tid; e < 4096; e += 256) t[e >> 6][e & 63] = srcp[e];
  __syncthreads();
  for (int e = tid; e < 4096; e += 256) {
    const int d = e >> 6, c = e & 63;
    const float v = t[c][d];
    const bf16 hi = (bf16)v;
    const long a = ((long)z * 64 + d) * 1024 + n0 + c;
    vth[a] = hi;
    vtl[a] = (bf16)(v - (float)hi);
  }
}

// Gram partials: Gq += q2^T q2 (64x64), Gk likewise; Sq/Sk column sums.
// 8 rows per barrier pair (was 1 -> 256 barriers; now 32).
__global__ __launch_bounds__(256) void stats_accum(
    const bf16* __restrict__ q2h, const bf16* __restrict__ q2l,
    const bf16* __restrict__ k2h, const bf16* __restrict__ k2l,
    float* __restrict__ Gq, float* __restrict__ Gk,
    float* __restrict__ Sq, float* __restrict__ Sk)
{
  __shared__ float rowbuf[8][128];     // 8 rows x (64 q | 64 k)
  const int tid = threadIdx.x;
  const int z = blockIdx.y;
  const long base = ((long)z * 1024 + (long)blockIdx.x * 128) * 64;
  const int tx = tid & 15, ty = tid >> 4;
  float gq[4][4] = {}, gk[4][4] = {};
  float sq = 0.f, sk = 0.f;
  for (int r0 = 0; r0 < 128; r0 += 8) {
    __syncthreads();
#pragma unroll
    for (int i = 0; i < 4; ++i) {
      const int idx = tid + i * 256;   // 0..1023 over 8x128
      const int rr = idx >> 7, cc = idx & 127;
      const long a = base + (long)(r0 + rr) * 64 + (cc & 63);
      float v;
      if (cc < 64) v = (float)q2h[a] + (float)q2l[a];
      else         v = (float)k2h[a] + (float)k2l[a];
      rowbuf[rr][cc] = v;
    }
    __syncthreads();
#pragma unroll
    for (int r = 0; r < 8; ++r) {
      float qa[4], qe[4], ka[4], ke[4];
#pragma unroll
      for (int i = 0; i < 4; ++i) {
        qa[i] = rowbuf[r][ty * 4 + i]; qe[i] = rowbuf[r][tx * 4 + i];
        ka[i] = rowbuf[r][64 + ty * 4 + i]; ke[i] = rowbuf[r][64 + tx * 4 + i];
      }
#pragma unroll
      for (int i = 0; i < 4; ++i)
#pragma unroll
        for (int j = 0; j < 4; ++j) {
          gq[i][j] += qa[i] * qe[j];
          gk[i][j] += ka[i] * ke[j];
        }
    }
    if (tid < 128) {
      float s = 0.f;
#pragma unroll
      for (int r = 0; r < 8; ++r) s += rowbuf[r][tid];
      if (tid < 64) sq += s; else sk += s;
    }
  }
#pragma unroll
  for (int i = 0; i < 4; ++i)
#pragma unroll
    for (int j = 0; j < 4; ++j) {
      atomicAdd(&Gq[(long)z * 4096 + (ty * 4 + i) * 64 + tx * 4 + j], gq[i][j]);
      atomicAdd(&Gk[(long)z * 4096 + (ty * 4 + i) * 64 + tx * 4 + j], gk[i][j]);
    }
  if (tid < 64) atomicAdd(&Sq[z * 64 + tid], sq);
  else if (tid < 128) atomicAdd(&Sk[z * 64 + tid - 64], sk);
}

// Per-batch mean / rstd of the attn tensor from Gram partials.
__global__ __launch_bounds__(256) void stats_final(
    const float* __restrict__ Gq, const float* __restrict__ Gk,
    const float* __restrict__ Sq, const float* __restrict__ Sk,
    float* __restrict__ stats)
{
  __shared__ double red[256];
  const int b = blockIdx.x, tid = threadIdx.x;
  double s2 = 0.0, s1 = 0.0;
  for (int h = 0; h < 12; ++h) {
    const float* gq = Gq + ((long)(b * 12 + h)) * 4096;
    const float* gk = Gk + ((long)(b * 12 + h)) * 4096;
    for (int i = tid; i < 4096; i += 256) s2 += (double)gq[i] * (double)gk[i];
    const float* sqp = Sq + (b * 12 + h) * 64;
    const float* skp = Sk + (b * 12 + h) * 64;
    for (int i = tid; i < 64; i += 256) s1 += (double)sqp[i] * (double)skp[i];
  }
  red[tid] = s2; __syncthreads();
  for (int st = 128; st > 0; st >>= 1) { if (tid < st) red[tid] += red[tid + st]; __syncthreads(); }
  const double S2 = red[0]; __syncthreads();
  red[tid] = s1; __syncthreads();
  for (int st = 128; st > 0; st >>= 1) { if (tid < st) red[tid] += red[tid + st]; __syncthreads(); }
  if (tid == 0) {
    const double S1 = red[0];
    const double cnt = 12.0 * 1024.0 * 1024.0;
    const double mean = S1 / cnt;
    const double var = S2 / cnt - mean * mean;
    stats[2 * b] = (float)mean;
    stats[2 * b + 1] = (float)(1.0 / sqrt(var + 1e-5));
  }
}

// ---------------------------------------------------------------------------
extern "C" void kernel_launch(void* const* d_in, const int* in_sizes, int n_in,
                              void* d_out, int out_size, void* d_ws, size_t ws_size,
                              hipStream_t stream)
{
  const float* x      = (const float*)d_in[0];
  const float* ln0_w  = (const float*)d_in[1];
  const float* ln0_b  = (const float*)d_in[2];
  const float* qkv_w  = (const float*)d_in[3];
  const float* qkv_b  = (const float*)d_in[4];
  const float* proj_w = (const float*)d_in[5];
  const float* proj_b = (const float*)d_in[6];
  const float* attn_w = (const float*)d_in[7];
  const float* attn_b = (const float*)d_in[8];
  const float* ln1_w  = (const float*)d_in[9];
  const float* ln1_b  = (const float*)d_in[10];
  const float* fc1_w  = (const float*)d_in[11];
  const float* fc1_b  = (const float*)d_in[12];
  const float* fc2_w  = (const float*)d_in[13];
  const float* fc2_b  = (const float*)d_in[14];

  float* out_src  = (float*)d_out;
  float* out_attn = out_src + 4L * 1024 * 768;       // 3145728

  char* p = (char*)d_ws;
  auto take = [&](long bytes) -> char* {
    char* r = p;
    p += (bytes + 255) & ~255L;
    return r;
  };
  bf16* qkvw_h = (bf16*)take(3538944);
  bf16* qkvw_l = (bf16*)take(3538944);
  bf16* projw_h = (bf16*)take(1179648);
  bf16* projw_l = (bf16*)take(1179648);
  bf16* fc1w_h = (bf16*)take(4718592);
  bf16* fc2w_h = (bf16*)take(4718592);
  char* regB = take(12582912);                 // hh+hl, later src_f32
  bf16* hh = (bf16*)regB;
  bf16* hl = (bf16*)(regB + 6291456);
  float* src = (float*)regB;
  char* regC = take(37748736);                 // qkv f32, later gelu acts + ln1f
  float* qkvf = (float*)regC;
  bf16* gact = (bf16*)regC;                    // [0, 25165824) bf16 4096x3072
  float* ln1f = (float*)(regC + 25165824);     // [25165824, 37748736) f32 4096x768
  bf16* q2h = (bf16*)take(6291456);
  bf16* q2l = (bf16*)take(6291456);
  bf16* k2h = (bf16*)take(6291456);
  bf16* k2l = (bf16*)take(6291456);
  bf16* vth = (bf16*)take(6291456);
  bf16* vtl = (bf16*)take(6291456);
  char* regF = take(12582912);                 // v f32, later oh+ol
  float* vf = (float*)regF;
  bf16* oh = (bf16*)regF;
  bf16* ol = (bf16*)(regF + 6291456);
  bf16* h1v = (bf16*)take(6291456);
  float* Gq = (float*)take(786432);
  float* Gk = (float*)take(786432);
  float* Sq = (float*)take(12288);
  float* Sk = (float*)take(12288);
  float* stats = (float*)take(256);

  const dim3 blk(256);

  (void)hipMemsetAsync((void*)Gq, 0, 786432 * 2 + 12288 * 2 + 256, stream);

  cast_split<<<dim3((1769472 + 255) / 256), blk, 0, stream>>>(qkv_w, qkvw_h, qkvw_l, 1769472);
  cast_split<<<dim3((589824 + 255) / 256), blk, 0, stream>>>(proj_w, projw_h, projw_l, 589824);
  cast_split<<<dim3((2359296 + 255) / 256), blk, 0, stream>>>(fc1_w, fc1w_h, nullptr, 2359296);
  cast_split<<<dim3((2359296 + 255) / 256), blk, 0, stream>>>(fc2_w, fc2w_h, nullptr, 2359296);

  ln_row<<<dim3(4096), blk, 0, stream>>>(x, ln0_w, ln0_b, hh, hl, nullptr);

  gemm_k<128, 128, 2, 4, 4, 3, 2, EpiQKV><<<dim3(18, 32, 1), blk, 0, stream>>>(
      hh, hl, 0, qkvw_h, qkvw_l, 0, 768, 768, 768, EpiQKV{qkv_b, qkvf});

  qkv_post<<<dim3(4096), blk, 0, stream>>>(qkvf, q2h, q2l, k2h, k2l, vf);
  transpose_v<<<dim3(16, 48), blk, 0, stream>>>(vf, vth, vtl);
  stats_accum<<<dim3(8, 48), blk, 0, stream>>>(q2h, q2l, k2h, k2l, Gq, Gk, Sq, Sk);
  stats_final<<<dim3(4), blk, 0, stream>>>(Gq, Gk, Sq, Sk, stats);

  attn_fused<<<dim3(16, 48), blk, 0, stream>>>(
      q2h, q2l, k2h, k2l, vth, vtl, stats, attn_w, attn_b, out_attn, oh, ol);

  gemm_k<128, 64, 2, 4, 2, 3, 2, EpiProj><<<dim3(12, 32, 1), blk, 0, stream>>>(
      oh, ol, 0, projw_h, projw_l, 0, 768, 768, 768, EpiProj{proj_b, x, src});

  ln_row<<<dim3(4096), blk, 0, stream>>>(src, ln1_w, ln1_b, h1v, nullptr, ln1f);

  gemm_k<128, 128, 2, 4, 4, 1, 4, EpiGelu><<<dim3(24, 32, 1), blk, 0, stream>>>(
      h1v, nullptr, 0, fc1w_h, nullptr, 0, 768, 768, 768, EpiGelu{fc1_b, gact});

  gemm_k<128, 64, 2, 4, 2, 1, 4, EpiOut><<<dim3(12, 32, 1), blk, 0, stream>>>(
      gact, nullptr, 0, fc2w_h, nullptr, 0, 3072, 3072, 3072, EpiOut{fc2_b, ln1f, out_src});
}

// Round 5
// 523.329 us; speedup vs baseline: 1.3593x; 1.0080x over previous
//
#include <hip/hip_runtime.h>

typedef __bf16 bf16;
typedef __bf16 bf16x4 __attribute__((ext_vector_type(4)));
typedef __bf16 bf16x8 __attribute__((ext_vector_type(8)));
typedef float f32x4 __attribute__((ext_vector_type(4)));

#define DEVI __device__ __forceinline__

typedef const __attribute__((address_space(1))) void* gas1;
typedef __attribute__((address_space(3))) void* las3;

// ---------------------------------------------------------------------------
// Stage a [rows x 64] bf16 tile (row bytes = 128) into LDS via global_load_lds,
// with st-style XOR swizzle: LDS[o] = data[o ^ ((row(o)&7)<<4)].
// Linear LDS dest + pre-swizzled global source; ds_read applies the same XOR.
// ---------------------------------------------------------------------------
DEVI void stage_tile(const bf16* g, int ld, char* lds, int bytes, int tid)
{
  const int wv = tid >> 6, lane = tid & 63;
  const char* gb = (const char*)g;
  const long rowb = (long)ld * 2;
  for (int off = wv * 1024; off < bytes; off += 4096) {
    const int o  = off + lane * 16;                 // linear LDS dest
    const int s  = o ^ (((o >> 7) & 7) << 4);       // pre-swizzled source pos
    const int r  = s >> 7;                          // 128B per tile row
    const int cb = s & 127;
    __builtin_amdgcn_global_load_lds((gas1)(gb + (long)r * rowb + cb),
                                     (las3)(lds + off), 16, 0, 0);
  }
}

template<int N> DEVI void waitvm()
{
  if constexpr (N == 8)      asm volatile("s_waitcnt vmcnt(8)" ::: "memory");
  else if constexpr (N == 6) asm volatile("s_waitcnt vmcnt(6)" ::: "memory");
  else if constexpr (N == 4) asm volatile("s_waitcnt vmcnt(4)" ::: "memory");
  else                       asm volatile("s_waitcnt vmcnt(0)" ::: "memory");
}

// ---------------------------------------------------------------------------
// Epilogue functors
// ---------------------------------------------------------------------------
struct EpiQKV {
  const float* bias; float* C;
  DEVI void operator()(int z, int row, int col, float v) const {
    C[(long)row * 2304 + col] = v + bias[col];
  }
};

struct EpiProj {
  const float* bias; const float* x; float* src;
  DEVI void operator()(int z, int row, int col, float v) const {
    const long i = (long)row * 768 + col;
    src[i] = v + bias[col] + x[i];
  }
};

struct EpiGelu {
  const float* bias; bf16* g;
  DEVI void operator()(int z, int row, int col, float v) const {
    const float t = v + bias[col];
    const float r = 0.5f * t * (1.0f + erff(t * 0.70710678118654752f));
    g[(long)row * 3072 + col] = (bf16)r;
  }
};

struct EpiOut {
  const float* bias; const float* lnf; float* outp;
  DEVI void operator()(int z, int row, int col, float v) const {
    const long i = (long)row * 768 + col;
    outp[i] = v + bias[col] + lnf[i];   // final residual uses POST-LN1 src
  }
};

// ---------------------------------------------------------------------------
// Generic split-bf16 GEMM, 2-phase double-buffered (T3/T4 minimum form):
//   prologue STAGE(buf0); loop { STAGE(buf^1,t+1); vmcnt(LPS); barrier;
//   MFMA(buf); lgkmcnt(0); barrier; }
// Counted vmcnt keeps next-tile loads in flight across the compute phase.
// NPASS==3: (Ah,Bh)+(Ah,Bl)+(Al,Bh).  NPASS==1: (Ah,Bh) only.
// 256 threads = 4 waves arranged (4/WC) x WC; per-wave FM x FN 16x16 frags.
// ---------------------------------------------------------------------------
template<int BM, int BN, int WC, int FM, int FN, int NPASS, int WPE, class Epi>
__global__ __launch_bounds__(256, WPE) void gemm_k(
    const bf16* __restrict__ Ah, const bf16* __restrict__ Al, long abatch,
    const bf16* __restrict__ Bh, const bf16* __restrict__ Bl, long bbatch,
    int lda, int ldb, int K, Epi epi)
{
  constexpr int BK = 64;
  constexpr int AB = BM * BK * 2, BB = BN * BK * 2;
  constexpr int HB = (NPASS > 1) ? 2 : 1;
  constexpr int BUFB = HB * (AB + BB);
  constexpr int LPS = BUFB / 4096;          // global_load_lds per wave per stage
  __shared__ char smem[2 * BUFB];

  const int tid = threadIdx.x, lane = tid & 63, wv = tid >> 6;
  const int wr = wv / WC, wc = wv % WC;
  const int mt = blockIdx.y, nt = blockIdx.x, z = blockIdx.z;
  const long abase = (long)z * abatch + (long)mt * BM * lda;
  const long bbase = (long)z * bbatch + (long)nt * BN * ldb;
  const int l15 = lane & 15;
  const int sw = (lane & 7) << 4;           // per-lane read swizzle

  auto stage_all = [&](int buf, int kt) {
    char* base = smem + buf * BUFB;
    stage_tile(Ah + abase + kt, lda, base, AB, tid);
    if constexpr (NPASS > 1) stage_tile(Al + abase + kt, lda, base + AB, AB, tid);
    stage_tile(Bh + bbase + kt, ldb, base + HB * AB, BB, tid);
    if constexpr (NPASS > 1) stage_tile(Bl + bbase + kt, ldb, base + HB * AB + BB, BB, tid);
  };

  f32x4 acc[FM][FN];
#pragma unroll
  for (int m = 0; m < FM; ++m)
#pragma unroll
    for (int n = 0; n < FN; ++n) acc[m][n] = f32x4{0.f, 0.f, 0.f, 0.f};

  const int arow = wr * FM * 16, bcol = wc * FN * 16;
  const int T = K / BK;

  stage_all(0, 0);
  int cur = 0;
  for (int t = 0; t < T; ++t) {
    if (t + 1 < T) { stage_all(cur ^ 1, (t + 1) * BK); waitvm<LPS>(); }
    else           { waitvm<0>(); }
    __builtin_amdgcn_s_barrier();
    asm volatile("" ::: "memory");

    const char* Abase = smem + cur * BUFB;
    const char* Bbase = Abase + HB * AB;
#pragma unroll
    for (int p = 0; p < NPASS; ++p) {
      const char* As = (p == 2) ? Abase + AB : Abase;
      const char* Bs = (p == 1) ? Bbase + BB : Bbase;
#pragma unroll
      for (int ks = 0; ks < 2; ++ks) {
        const int ko = (ks * 64 + (lane >> 4) * 16) ^ sw;
        bf16x8 av[FM], bv[FN];
#pragma unroll
        for (int m = 0; m < FM; ++m)
          av[m] = *(const bf16x8*)(As + (arow + m * 16 + l15) * 128 + ko);
#pragma unroll
        for (int n = 0; n < FN; ++n)
          bv[n] = *(const bf16x8*)(Bs + (bcol + n * 16 + l15) * 128 + ko);
#pragma unroll
        for (int m = 0; m < FM; ++m)
#pragma unroll
          for (int n = 0; n < FN; ++n)
            acc[m][n] = __builtin_amdgcn_mfma_f32_16x16x32_bf16(av[m], bv[n], acc[m][n], 0, 0, 0);
      }
    }
    asm volatile("s_waitcnt lgkmcnt(0)" ::: "memory");   // all LDS reads done
    __builtin_amdgcn_s_barrier();                         // before buf reuse
    asm volatile("" ::: "memory");
    cur ^= 1;
  }

#pragma unroll
  for (int m = 0; m < FM; ++m)
#pragma unroll
    for (int n = 0; n < FN; ++n)
#pragma unroll
      for (int r = 0; r < 4; ++r) {
        const int grow = mt * BM + arow + m * 16 + (lane >> 4) * 4 + r;
        const int gcol = nt * BN + bcol + n * 16 + l15;
        epi(z, grow, gcol, acc[m][n][r]);
      }
}

// ---------------------------------------------------------------------------
// Fused attention tail: per workgroup = (row-strip of 64, z).
// z remapped: h = z>>2, b = z&3 (batches sharing wn[h]/bn[h] adjacent -> L3).
// Per col-tile: K/V DMA + wn/bn reg-prefetch (T14, drained together) ->
// QK^T (3-pass, swizzled) -> swizzled Pf -> LN from regs (f32x4 store) ->
// PV accumulate. LDS = 80KB -> 2 blocks/CU.
// ---------------------------------------------------------------------------
__global__ __launch_bounds__(256, 2) void attn_fused(
    const bf16* __restrict__ q2h, const bf16* __restrict__ q2l,
    const bf16* __restrict__ k2h, const bf16* __restrict__ k2l,
    const bf16* __restrict__ vth, const bf16* __restrict__ vtl,
    const float* __restrict__ stats, const float* __restrict__ wn,
    const float* __restrict__ bn, float* __restrict__ attn_out,
    bf16* __restrict__ oh, bf16* __restrict__ ol)
{
  __shared__ char smem[81920];
  char* Qh = smem;                    //  8KB  64x64 bf16 (swizzled)
  char* Ql = smem + 8192;
  char* Kh = smem + 16384;
  char* Kl = smem + 24576;
  char* Vh = smem + 32768;
  char* Vl = smem + 40960;
  float* Pf = (float*)(smem + 49152); // 16KB  64x64 f32 raw scores (swizzled)
  char* Ph = smem + 65536;
  char* Pl = smem + 73728;

  const int tid = threadIdx.x, lane = tid & 63, wv = tid >> 6;
  const int wr = wv >> 1, wc = wv & 1;
  const int mt = blockIdx.x, z = blockIdx.y;
  const int h = z >> 2, b = z & 3;
  const int zq = b * 12 + h;
  const float mu = stats[2 * b], rs = stats[2 * b + 1];
  const int l15 = lane & 15;
  const int sw = (lane & 7) << 4;
  const int lr = tid >> 4, c0 = (tid & 15) * 4;

  const long zoff = (long)zq * 65536;
  stage_tile(q2h + zoff + (long)mt * 64 * 64, 64, Qh, 8192, tid);
  stage_tile(q2l + zoff + (long)mt * 64 * 64, 64, Ql, 8192, tid);

  f32x4 oacc[2][2];
#pragma unroll
  for (int m = 0; m < 2; ++m)
#pragma unroll
    for (int n = 0; n < 2; ++n) oacc[m][n] = f32x4{0.f, 0.f, 0.f, 0.f};

  for (int nt = 0; nt < 16; ++nt) {
    __syncthreads();   // previous PV done before overwriting K/V/P
    stage_tile(k2h + zoff + (long)nt * 64 * 64, 64, Kh, 8192, tid);
    stage_tile(k2l + zoff + (long)nt * 64 * 64, 64, Kl, 8192, tid);
    stage_tile(vth + zoff + nt * 64, 1024, Vh, 8192, tid);
    stage_tile(vtl + zoff + nt * 64, 1024, Vl, 8192, tid);

    // T14: wn/bn prefetch into regs; drains with the DMA at the next barrier.
    f32x4 wreg[4], breg[4];
#pragma unroll
    for (int rr = 0; rr < 4; ++rr) {
      const long grow = (long)mt * 64 + rr * 16 + lr;
      const long gcol = (long)nt * 64 + c0;
      wreg[rr] = *(const f32x4*)&wn[((long)h * 1024 + grow) * 1024 + gcol];
      breg[rr] = *(const f32x4*)&bn[((long)h * 1024 + grow) * 1024 + gcol];
    }
    __syncthreads();

    // ---- QK^T: scores[i (64), j (64)] = sum_d q2[i,d] k2[j,d], 3-pass ----
    f32x4 acc[2][2];
#pragma unroll
    for (int m = 0; m < 2; ++m)
#pragma unroll
      for (int n = 0; n < 2; ++n) acc[m][n] = f32x4{0.f, 0.f, 0.f, 0.f};
#pragma unroll
    for (int p = 0; p < 3; ++p) {
      const char* As = (p == 2) ? Ql : Qh;
      const char* Bs = (p == 1) ? Kl : Kh;
#pragma unroll
      for (int ks = 0; ks < 2; ++ks) {
        const int ko = (ks * 64 + (lane >> 4) * 16) ^ sw;
        bf16x8 av[2], bv[2];
#pragma unroll
        for (int m = 0; m < 2; ++m)
          av[m] = *(const bf16x8*)(As + (wr * 32 + m * 16 + l15) * 128 + ko);
#pragma unroll
        for (int n = 0; n < 2; ++n)
          bv[n] = *(const bf16x8*)(Bs + (wc * 32 + n * 16 + l15) * 128 + ko);
#pragma unroll
        for (int m = 0; m < 2; ++m)
#pragma unroll
          for (int n = 0; n < 2; ++n)
            acc[m][n] = __builtin_amdgcn_mfma_f32_16x16x32_bf16(av[m], bv[n], acc[m][n], 0, 0, 0);
      }
    }
    // raw scores -> swizzled Pf: slot(i,j) = j ^ (((i^(i>>2))&7)<<2)
#pragma unroll
    for (int m = 0; m < 2; ++m)
#pragma unroll
      for (int n = 0; n < 2; ++n)
#pragma unroll
        for (int r = 0; r < 4; ++r) {
          const int i = wr * 32 + m * 16 + (lane >> 4) * 4 + r;
          const int j = wc * 32 + n * 16 + l15;
          const int sp = ((i ^ (i >> 2)) & 7) << 2;
          Pf[i * 64 + (j ^ sp)] = acc[m][n][r];
        }
    __syncthreads();

    // ---- LN pass: coalesced; wn/bn from regs ----
    {
#pragma unroll
      for (int rr = 0; rr < 4; ++rr) {
        const int row = rr * 16 + lr;
        const int sp = ((row ^ (row >> 2)) & 7) << 2;
        const long grow = (long)mt * 64 + row;
        const long gcol = (long)nt * 64 + c0;
        const f32x4 s = *(const f32x4*)&Pf[row * 64 + (c0 ^ sp)];
        f32x4 r4;
        bf16x4 h4, l4;
#pragma unroll
        for (int e = 0; e < 4; ++e) {
          const float r = (s[e] - mu) * rs * wreg[rr][e] + breg[rr][e];
          r4[e] = r;
          const bf16 hi = (bf16)r;
          h4[e] = hi;
          l4[e] = (bf16)(r - (float)hi);
        }
        *(f32x4*)&attn_out[((long)zq * 1024 + grow) * 1024 + gcol] = r4;
        const int pb = row * 128 + ((c0 * 2) ^ ((row & 7) << 4));
        *(bf16x4*)(Ph + pb) = h4;
        *(bf16x4*)(Pl + pb) = l4;
      }
    }
    __syncthreads();

    // ---- PV: out[i, d] += sum_j p[i,j] vT[d,j], 3-pass ----
#pragma unroll
    for (int p = 0; p < 3; ++p) {
      const char* As = (p == 2) ? Pl : Ph;
      const char* Bs = (p == 1) ? Vl : Vh;
#pragma unroll
      for (int ks = 0; ks < 2; ++ks) {
        const int ko = (ks * 64 + (lane >> 4) * 16) ^ sw;
        bf16x8 av[2], bv[2];
#pragma unroll
        for (int m = 0; m < 2; ++m)
          av[m] = *(const bf16x8*)(As + (wr * 32 + m * 16 + l15) * 128 + ko);
#pragma unroll
        for (int n = 0; n < 2; ++n)
          bv[n] = *(const bf16x8*)(Bs + (wc * 32 + n * 16 + l15) * 128 + ko);
#pragma unroll
        for (int m = 0; m < 2; ++m)
#pragma unroll
          for (int n = 0; n < 2; ++n)
            oacc[m][n] = __builtin_amdgcn_mfma_f32_16x16x32_bf16(av[m], bv[n], oacc[m][n], 0, 0, 0);
      }
    }
  }

  // ---- epilogue: o -> (B,N,C) split bf16 ----
#pragma unroll
  for (int m = 0; m < 2; ++m)
#pragma unroll
    for (int n = 0; n < 2; ++n)
#pragma unroll
      for (int r = 0; r < 4; ++r) {
        const int row = mt * 64 + wr * 32 + m * 16 + (lane >> 4) * 4 + r;
        const int col = wc * 32 + n * 16 + l15;
        const long addr = ((long)(b * 1024 + row)) * 768 + h * 64 + col;
        const float v = oacc[m][n][r];
        const bf16 hi = (bf16)v;
        oh[addr] = hi;
        ol[addr] = (bf16)(v - (float)hi);
      }
}

// ---------------------------------------------------------------------------
// Elementwise helpers
// ---------------------------------------------------------------------------
__global__ void cast_split(const float* __restrict__ s, bf16* __restrict__ dh,
                           bf16* __restrict__ dl, int n)
{
  const int i = blockIdx.x * 256 + threadIdx.x;
  if (i < n) {
    const float x = s[i];
    const bf16 hi = (bf16)x;
    dh[i] = hi;
    if (dl) dl[i] = (bf16)(x - (float)hi);
  }
}

// LayerNorm over rows of 768; writes bf16 hi (+ optional lo, + optional f32).
__global__ __launch_bounds__(256) void ln_row(
    const float* __restrict__ in, const float* __restrict__ w,
    const float* __restrict__ b, bf16* __restrict__ outh,
    bf16* __restrict__ outl, float* __restrict__ outf)
{
  __shared__ float red[256];
  const int row = blockIdx.x, tid = threadIdx.x;
  const float* p = in + (long)row * 768;
  const float v0 = p[tid], v1 = p[tid + 256], v2 = p[tid + 512];
  red[tid] = v0 + v1 + v2;
  __syncthreads();
  for (int st = 128; st > 0; st >>= 1) { if (tid < st) red[tid] += red[tid + st]; __syncthreads(); }
  const float mu = red[0] * (1.0f / 768.0f);
  __syncthreads();
  const float d0 = v0 - mu, d1 = v1 - mu, d2 = v2 - mu;
  red[tid] = d0 * d0 + d1 * d1 + d2 * d2;
  __syncthreads();
  for (int st = 128; st > 0; st >>= 1) { if (tid < st) red[tid] += red[tid + st]; __syncthreads(); }
  const float rs = rsqrtf(red[0] * (1.0f / 768.0f) + 1e-5f);
  const float dv[3] = {d0, d1, d2};
#pragma unroll
  for (int k = 0; k < 3; ++k) {
    const int c = tid + k * 256;
    const float h = dv[k] * rs * w[c] + b[c];
    const bf16 hi = (bf16)h;
    outh[(long)row * 768 + c] = hi;
    if (outl) outl[(long)row * 768 + c] = (bf16)(h - (float)hi);
    if (outf) outf[(long)row * 768 + c] = h;
  }
}

// Per (b,n): normalize q,k head-vectors -> (q/||q||)^2 split bf16 (B,H,N,D);
// v -> f32 (B,H,N,D).
__global__ __launch_bounds__(256) void qkv_post(
    const float* __restrict__ qkv, bf16* __restrict__ q2h, bf16* __restrict__ q2l,
    bf16* __restrict__ k2h, bf16* __restrict__ k2l, float* __restrict__ vf)
{
  const int row = blockIdx.x;           // b*1024+n
  const int b = row >> 10, n = row & 1023;
  const int wv = threadIdx.x >> 6, lane = threadIdx.x & 63;
  for (int t = wv; t < 36; t += 4) {
    const int s = t / 12, h = t - s * 12;
    const float val = qkv[(long)row * 2304 + s * 768 + h * 64 + lane];
    const long addr = (((long)(b * 12 + h)) * 1024 + n) * 64 + lane;
    if (s == 2) {
      vf[addr] = val;
    } else {
      const float sq = val * val;
      float tot = sq;
#pragma unroll
      for (int d = 1; d < 64; d <<= 1) tot += __shfl_xor(tot, d);
      const float q2 = sq / tot;
      const bf16 hi = (bf16)q2;
      const bf16 lo = (bf16)(q2 - (float)hi);
      if (s == 0) { q2h[addr] = hi; q2l[addr] = lo; }
      else        { k2h[addr] = hi; k2l[addr] = lo; }
    }
  }
}

// v (B,H,N,D) f32 -> vT (B,H,D,N) split bf16, 64x64 tiles.
__global__ __launch_bounds__(256) void transpose_v(
    const float* __restrict__ vf, bf16* __restrict__ vth, bf16* __restrict__ vtl)
{
  __shared__ float t[64][65];
  const int z = blockIdx.y, n0 = blockIdx.x * 64, tid = threadIdx.x;
  const float* srcp = vf + ((long)z * 1024 + n0) * 64;
  for (int e = tid; e < 4096; e += 256) t[e >> 6][e & 63] = srcp[e];
  __syncthreads();
  for (int e = tid; e < 4096; e += 256) {
    const int d = e >> 6, c = e & 63;
    const float v = t[c][d];
    const bf16 hi = (bf16)v;
    const long a = ((long)z * 64 + d) * 1024 + n0 + c;
    vth[a] = hi;
    vtl[a] = (bf16)(v - (float)hi);
  }
}

// Gram partials: Gq += q2^T q2 (64x64), Gk likewise; Sq/Sk column sums.
__global__ __launch_bounds__(256) void stats_accum(
    const bf16* __restrict__ q2h, const bf16* __restrict__ q2l,
    const bf16* __restrict__ k2h, const bf16* __restrict__ k2l,
    float* __restrict__ Gq, float* __restrict__ Gk,
    float* __restrict__ Sq, float* __restrict__ Sk)
{
  __shared__ float rowbuf[8][128];     // 8 rows x (64 q | 64 k)
  const int tid = threadIdx.x;
  const int z = blockIdx.y;
  const long base = ((long)z * 1024 + (long)blockIdx.x * 128) * 64;
  const int tx = tid & 15, ty = tid >> 4;
  float gq[4][4] = {}, gk[4][4] = {};
  float sq = 0.f, sk = 0.f;
  for (int r0 = 0; r0 < 128; r0 += 8) {
    __syncthreads();
#pragma unroll
    for (int i = 0; i < 4; ++i) {
      const int idx = tid + i * 256;   // 0..1023 over 8x128
      const int rr = idx >> 7, cc = idx & 127;
      const long a = base + (long)(r0 + rr) * 64 + (cc & 63);
      float v;
      if (cc < 64) v = (float)q2h[a] + (float)q2l[a];
      else         v = (float)k2h[a] + (float)k2l[a];
      rowbuf[rr][cc] = v;
    }
    __syncthreads();
#pragma unroll
    for (int r = 0; r < 8; ++r) {
      float qa[4], qe[4], ka[4], ke[4];
#pragma unroll
      for (int i = 0; i < 4; ++i) {
        qa[i] = rowbuf[r][ty * 4 + i]; qe[i] = rowbuf[r][tx * 4 + i];
        ka[i] = rowbuf[r][64 + ty * 4 + i]; ke[i] = rowbuf[r][64 + tx * 4 + i];
      }
#pragma unroll
      for (int i = 0; i < 4; ++i)
#pragma unroll
        for (int j = 0; j < 4; ++j) {
          gq[i][j] += qa[i] * qe[j];
          gk[i][j] += ka[i] * ke[j];
        }
    }
    if (tid < 128) {
      float s = 0.f;
#pragma unroll
      for (int r = 0; r < 8; ++r) s += rowbuf[r][tid];
      if (tid < 64) sq += s; else sk += s;
    }
  }
#pragma unroll
  for (int i = 0; i < 4; ++i)
#pragma unroll
    for (int j = 0; j < 4; ++j) {
      atomicAdd(&Gq[(long)z * 4096 + (ty * 4 + i) * 64 + tx * 4 + j], gq[i][j]);
      atomicAdd(&Gk[(long)z * 4096 + (ty * 4 + i) * 64 + tx * 4 + j], gk[i][j]);
    }
  if (tid < 64) atomicAdd(&Sq[z * 64 + tid], sq);
  else if (tid < 128) atomicAdd(&Sk[z * 64 + tid - 64], sk);
}

// Per-batch mean / rstd of the attn tensor from Gram partials.
__global__ __launch_bounds__(256) void stats_final(
    const float* __restrict__ Gq, const float* __restrict__ Gk,
    const float* __restrict__ Sq, const float* __restrict__ Sk,
    float* __restrict__ stats)
{
  __shared__ double red[256];
  const int b = blockIdx.x, tid = threadIdx.x;
  double s2 = 0.0, s1 = 0.0;
  for (int h = 0; h < 12; ++h) {
    const float* gq = Gq + ((long)(b * 12 + h)) * 4096;
    const float* gk = Gk + ((long)(b * 12 + h)) * 4096;
    for (int i = tid; i < 4096; i += 256) s2 += (double)gq[i] * (double)gk[i];
    const float* sqp = Sq + (b * 12 + h) * 64;
    const float* skp = Sk + (b * 12 + h) * 64;
    for (int i = tid; i < 64; i += 256) s1 += (double)sqp[i] * (double)skp[i];
  }
  red[tid] = s2; __syncthreads();
  for (int st = 128; st > 0; st >>= 1) { if (tid < st) red[tid] += red[tid + st]; __syncthreads(); }
  const double S2 = red[0]; __syncthreads();
  red[tid] = s1; __syncthreads();
  for (int st = 128; st > 0; st >>= 1) { if (tid < st) red[tid] += red[tid + st]; __syncthreads(); }
  if (tid == 0) {
    const double S1 = red[0];
    const double cnt = 12.0 * 1024.0 * 1024.0;
    const double mean = S1 / cnt;
    const double var = S2 / cnt - mean * mean;
    stats[2 * b] = (float)mean;
    stats[2 * b + 1] = (float)(1.0 / sqrt(var + 1e-5));
  }
}

// ---------------------------------------------------------------------------
extern "C" void kernel_launch(void* const* d_in, const int* in_sizes, int n_in,
                              void* d_out, int out_size, void* d_ws, size_t ws_size,
                              hipStream_t stream)
{
  const float* x      = (const float*)d_in[0];
  const float* ln0_w  = (const float*)d_in[1];
  const float* ln0_b  = (const float*)d_in[2];
  const float* qkv_w  = (const float*)d_in[3];
  const float* qkv_b  = (const float*)d_in[4];
  const float* proj_w = (const float*)d_in[5];
  const float* proj_b = (const float*)d_in[6];
  const float* attn_w = (const float*)d_in[7];
  const float* attn_b = (const float*)d_in[8];
  const float* ln1_w  = (const float*)d_in[9];
  const float* ln1_b  = (const float*)d_in[10];
  const float* fc1_w  = (const float*)d_in[11];
  const float* fc1_b  = (const float*)d_in[12];
  const float* fc2_w  = (const float*)d_in[13];
  const float* fc2_b  = (const float*)d_in[14];

  float* out_src  = (float*)d_out;
  float* out_attn = out_src + 4L * 1024 * 768;       // 3145728

  char* p = (char*)d_ws;
  auto take = [&](long bytes) -> char* {
    char* r = p;
    p += (bytes + 255) & ~255L;
    return r;
  };
  bf16* qkvw_h = (bf16*)take(3538944);
  bf16* qkvw_l = (bf16*)take(3538944);
  bf16* projw_h = (bf16*)take(1179648);
  bf16* projw_l = (bf16*)take(1179648);
  bf16* fc1w_h = (bf16*)take(4718592);
  bf16* fc2w_h = (bf16*)take(4718592);
  char* regB = take(12582912);                 // hh+hl, later src_f32
  bf16* hh = (bf16*)regB;
  bf16* hl = (bf16*)(regB + 6291456);
  float* src = (float*)regB;
  char* regC = take(37748736);                 // qkv f32, later gelu acts + ln1f
  float* qkvf = (float*)regC;
  bf16* gact = (bf16*)regC;                    // [0, 25165824) bf16 4096x3072
  float* ln1f = (float*)(regC + 25165824);     // [25165824, 37748736) f32 4096x768
  bf16* q2h = (bf16*)take(6291456);
  bf16* q2l = (bf16*)take(6291456);
  bf16* k2h = (bf16*)take(6291456);
  bf16* k2l = (bf16*)take(6291456);
  bf16* vth = (bf16*)take(6291456);
  bf16* vtl = (bf16*)take(6291456);
  char* regF = take(12582912);                 // v f32, later oh+ol
  float* vf = (float*)regF;
  bf16* oh = (bf16*)regF;
  bf16* ol = (bf16*)(regF + 6291456);
  bf16* h1v = (bf16*)take(6291456);
  float* Gq = (float*)take(786432);
  float* Gk = (float*)take(786432);
  float* Sq = (float*)take(12288);
  float* Sk = (float*)take(12288);
  float* stats = (float*)take(256);

  const dim3 blk(256);

  (void)hipMemsetAsync((void*)Gq, 0, 786432 * 2 + 12288 * 2 + 256, stream);

  cast_split<<<dim3((1769472 + 255) / 256), blk, 0, stream>>>(qkv_w, qkvw_h, qkvw_l, 1769472);
  cast_split<<<dim3((589824 + 255) / 256), blk, 0, stream>>>(proj_w, projw_h, projw_l, 589824);
  cast_split<<<dim3((2359296 + 255) / 256), blk, 0, stream>>>(fc1_w, fc1w_h, nullptr, 2359296);
  cast_split<<<dim3((2359296 + 255) / 256), blk, 0, stream>>>(fc2_w, fc2w_h, nullptr, 2359296);

  ln_row<<<dim3(4096), blk, 0, stream>>>(x, ln0_w, ln0_b, hh, hl, nullptr);

  gemm_k<64, 64, 2, 2, 2, 3, 2, EpiQKV><<<dim3(36, 64, 1), blk, 0, stream>>>(
      hh, hl, 0, qkvw_h, qkvw_l, 0, 768, 768, 768, EpiQKV{qkv_b, qkvf});

  qkv_post<<<dim3(4096), blk, 0, stream>>>(qkvf, q2h, q2l, k2h, k2l, vf);
  transpose_v<<<dim3(16, 48), blk, 0, stream>>>(vf, vth, vtl);
  stats_accum<<<dim3(8, 48), blk, 0, stream>>>(q2h, q2l, k2h, k2l, Gq, Gk, Sq, Sk);
  stats_final<<<dim3(4), blk, 0, stream>>>(Gq, Gk, Sq, Sk, stats);

  attn_fused<<<dim3(16, 48), blk, 0, stream>>>(
      q2h, q2l, k2h, k2l, vth, vtl, stats, attn_w, attn_b, out_attn, oh, ol);

  gemm_k<64, 64, 2, 2, 2, 3, 2, EpiProj><<<dim3(12, 64, 1), blk, 0, stream>>>(
      oh, ol, 0, projw_h, projw_l, 0, 768, 768, 768, EpiProj{proj_b, x, src});

  ln_row<<<dim3(4096), blk, 0, stream>>>(src, ln1_w, ln1_b, h1v, nullptr, ln1f);

  gemm_k<128, 128, 2, 4, 4, 1, 2, EpiGelu><<<dim3(24, 32, 1), blk, 0, stream>>>(
      h1v, nullptr, 0, fc1w_h, nullptr, 0, 768, 768, 768, EpiGelu{fc1_b, gact});

  gemm_k<128, 64, 2, 4, 2, 1, 2, EpiOut><<<dim3(12, 32, 1), blk, 0, stream>>>(
      gact, nullptr, 0, fc2w_h, nullptr, 0, 3072, 3072, 3072, EpiOut{fc2_b, ln1f, out_src});
}

// Round 6
// 449.138 us; speedup vs baseline: 1.5838x; 1.1652x over previous
//
#include <hip/hip_runtime.h>

typedef __bf16 bf16;
typedef __bf16 bf16x4 __attribute__((ext_vector_type(4)));
typedef __bf16 bf16x8 __attribute__((ext_vector_type(8)));
typedef float f32x4 __attribute__((ext_vector_type(4)));

#define DEVI __device__ __forceinline__

typedef const __attribute__((address_space(1))) void* gas1;
typedef __attribute__((address_space(3))) void* las3;

// ---------------------------------------------------------------------------
// Stage a [rows x 64] bf16 tile (row bytes = 128) into LDS via global_load_lds,
// with st-style XOR swizzle: LDS[o] = data[o ^ ((row(o)&7)<<4)].
// Linear LDS dest + pre-swizzled global source; ds_read applies the same XOR.
// ---------------------------------------------------------------------------
DEVI void stage_tile(const bf16* g, int ld, char* lds, int bytes, int tid)
{
  const int wv = tid >> 6, lane = tid & 63;
  const char* gb = (const char*)g;
  const long rowb = (long)ld * 2;
  for (int off = wv * 1024; off < bytes; off += 4096) {
    const int o  = off + lane * 16;                 // linear LDS dest
    const int s  = o ^ (((o >> 7) & 7) << 4);       // pre-swizzled source pos
    const int r  = s >> 7;                          // 128B per tile row
    const int cb = s & 127;
    __builtin_amdgcn_global_load_lds((gas1)(gb + (long)r * rowb + cb),
                                     (las3)(lds + off), 16, 0, 0);
  }
}

template<int N> DEVI void waitvm()
{
  if constexpr (N == 8)      asm volatile("s_waitcnt vmcnt(8)" ::: "memory");
  else if constexpr (N == 6) asm volatile("s_waitcnt vmcnt(6)" ::: "memory");
  else if constexpr (N == 4) asm volatile("s_waitcnt vmcnt(4)" ::: "memory");
  else                       asm volatile("s_waitcnt vmcnt(0)" ::: "memory");
}

// ---------------------------------------------------------------------------
// Epilogue functors
// ---------------------------------------------------------------------------
struct EpiQKV {          // writes bf16 qkv (single precision path)
  const float* bias; bf16* C;
  DEVI void operator()(int z, int row, int col, float v) const {
    C[(long)row * 2304 + col] = (bf16)(v + bias[col]);
  }
};

struct EpiProj {
  const float* bias; const float* x; float* src;
  DEVI void operator()(int z, int row, int col, float v) const {
    const long i = (long)row * 768 + col;
    src[i] = v + bias[col] + x[i];
  }
};

struct EpiGelu {
  const float* bias; bf16* g;
  DEVI void operator()(int z, int row, int col, float v) const {
    const float t = v + bias[col];
    const float r = 0.5f * t * (1.0f + erff(t * 0.70710678118654752f));
    g[(long)row * 3072 + col] = (bf16)r;
  }
};

struct EpiOut {
  const float* bias; const float* lnf; float* outp;
  DEVI void operator()(int z, int row, int col, float v) const {
    const long i = (long)row * 768 + col;
    outp[i] = v + bias[col] + lnf[i];   // final residual uses POST-LN1 src
  }
};

// ---------------------------------------------------------------------------
// bf16 GEMM, 2-phase double-buffered (T3/T4 minimum form):
//   prologue STAGE(buf0); loop { STAGE(buf^1,t+1); vmcnt(LPS); barrier;
//   MFMA(buf); lgkmcnt(0); barrier; }
// NPASS==3 keeps the split path available for revert; production uses 1.
// 256 threads = 4 waves arranged (4/WC) x WC; per-wave FM x FN 16x16 frags.
// ---------------------------------------------------------------------------
template<int BM, int BN, int WC, int FM, int FN, int NPASS, int WPE, class Epi>
__global__ __launch_bounds__(256, WPE) void gemm_k(
    const bf16* __restrict__ Ah, const bf16* __restrict__ Al, long abatch,
    const bf16* __restrict__ Bh, const bf16* __restrict__ Bl, long bbatch,
    int lda, int ldb, int K, Epi epi)
{
  constexpr int BK = 64;
  constexpr int AB = BM * BK * 2, BB = BN * BK * 2;
  constexpr int HB = (NPASS > 1) ? 2 : 1;
  constexpr int BUFB = HB * (AB + BB);
  constexpr int LPS = BUFB / 4096;          // global_load_lds per wave per stage
  __shared__ char smem[2 * BUFB];

  const int tid = threadIdx.x, lane = tid & 63, wv = tid >> 6;
  const int wr = wv / WC, wc = wv % WC;
  const int mt = blockIdx.y, nt = blockIdx.x, z = blockIdx.z;
  const long abase = (long)z * abatch + (long)mt * BM * lda;
  const long bbase = (long)z * bbatch + (long)nt * BN * ldb;
  const int l15 = lane & 15;
  const int sw = (lane & 7) << 4;           // per-lane read swizzle

  auto stage_all = [&](int buf, int kt) {
    char* base = smem + buf * BUFB;
    stage_tile(Ah + abase + kt, lda, base, AB, tid);
    if constexpr (NPASS > 1) stage_tile(Al + abase + kt, lda, base + AB, AB, tid);
    stage_tile(Bh + bbase + kt, ldb, base + HB * AB, BB, tid);
    if constexpr (NPASS > 1) stage_tile(Bl + bbase + kt, ldb, base + HB * AB + BB, BB, tid);
  };

  f32x4 acc[FM][FN];
#pragma unroll
  for (int m = 0; m < FM; ++m)
#pragma unroll
    for (int n = 0; n < FN; ++n) acc[m][n] = f32x4{0.f, 0.f, 0.f, 0.f};

  const int arow = wr * FM * 16, bcol = wc * FN * 16;
  const int T = K / BK;

  stage_all(0, 0);
  int cur = 0;
  for (int t = 0; t < T; ++t) {
    if (t + 1 < T) { stage_all(cur ^ 1, (t + 1) * BK); waitvm<LPS>(); }
    else           { waitvm<0>(); }
    __builtin_amdgcn_s_barrier();
    asm volatile("" ::: "memory");

    const char* Abase = smem + cur * BUFB;
    const char* Bbase = Abase + HB * AB;
#pragma unroll
    for (int p = 0; p < NPASS; ++p) {
      const char* As = (p == 2) ? Abase + AB : Abase;
      const char* Bs = (p == 1) ? Bbase + BB : Bbase;
#pragma unroll
      for (int ks = 0; ks < 2; ++ks) {
        const int ko = (ks * 64 + (lane >> 4) * 16) ^ sw;
        bf16x8 av[FM], bv[FN];
#pragma unroll
        for (int m = 0; m < FM; ++m)
          av[m] = *(const bf16x8*)(As + (arow + m * 16 + l15) * 128 + ko);
#pragma unroll
        for (int n = 0; n < FN; ++n)
          bv[n] = *(const bf16x8*)(Bs + (bcol + n * 16 + l15) * 128 + ko);
#pragma unroll
        for (int m = 0; m < FM; ++m)
#pragma unroll
          for (int n = 0; n < FN; ++n)
            acc[m][n] = __builtin_amdgcn_mfma_f32_16x16x32_bf16(av[m], bv[n], acc[m][n], 0, 0, 0);
      }
    }
    asm volatile("s_waitcnt lgkmcnt(0)" ::: "memory");   // all LDS reads done
    __builtin_amdgcn_s_barrier();                         // before buf reuse
    asm volatile("" ::: "memory");
    cur ^= 1;
  }

#pragma unroll
  for (int m = 0; m < FM; ++m)
#pragma unroll
    for (int n = 0; n < FN; ++n)
#pragma unroll
      for (int r = 0; r < 4; ++r) {
        const int grow = mt * BM + arow + m * 16 + (lane >> 4) * 4 + r;
        const int gcol = nt * BN + bcol + n * 16 + l15;
        epi(z, grow, gcol, acc[m][n][r]);
      }
}

// ---------------------------------------------------------------------------
// Fused attention tail, single-precision bf16, K/V double-buffered.
// z remapped: h = z>>2, b = z&3 (batches sharing wn[h]/bn[h] adjacent -> L3).
// Per iter nt: DMA K/V(nt+1) -> other buf; wn/bn reg loads; QK^T (8 MFMA);
// Pf write; barrier; LN -> attn_out + Ph; barrier; PV (8 MFMA); vmcnt(0);
// barrier. LDS = 64KB -> 2 blocks/CU.
// ---------------------------------------------------------------------------
__global__ __launch_bounds__(256, 2) void attn_fused(
    const bf16* __restrict__ q2h, const bf16* __restrict__ k2h,
    const bf16* __restrict__ vth, const float* __restrict__ stats,
    const float* __restrict__ wn, const float* __restrict__ bn,
    float* __restrict__ attn_out, bf16* __restrict__ oh)
{
  __shared__ char smem[65536];
  char* Qs  = smem;                    //  8KB  64x64 bf16 (swizzled)
  char* Ks0 = smem + 8192;             //  8KB  K buf 0
  char* Ks1 = smem + 16384;            //  8KB  K buf 1
  char* Vs0 = smem + 24576;            //  8KB  V buf 0
  char* Vs1 = smem + 32768;            //  8KB  V buf 1
  float* Pf = (float*)(smem + 40960);  // 16KB  64x64 f32 raw scores (swizzled)
  char* Ph  = smem + 57344;            //  8KB  64x64 bf16 P (swizzled)

  const int tid = threadIdx.x, lane = tid & 63, wv = tid >> 6;
  const int wr = wv >> 1, wc = wv & 1;
  const int mt = blockIdx.x, z = blockIdx.y;
  const int h = z >> 2, b = z & 3;
  const int zq = b * 12 + h;
  const float mu = stats[2 * b], rs = stats[2 * b + 1];
  const int l15 = lane & 15;
  const int sw = (lane & 7) << 4;
  const int lr = tid >> 4, c0 = (tid & 15) * 4;

  const long zoff = (long)zq * 65536;
  stage_tile(q2h + zoff + (long)mt * 4096, 64, Qs, 8192, tid);
  stage_tile(k2h + zoff, 64, Ks0, 8192, tid);
  stage_tile(vth + zoff, 1024, Vs0, 8192, tid);
  waitvm<0>();
  __builtin_amdgcn_s_barrier();
  asm volatile("" ::: "memory");

  f32x4 oacc[2][2];
#pragma unroll
  for (int m = 0; m < 2; ++m)
#pragma unroll
    for (int n = 0; n < 2; ++n) oacc[m][n] = f32x4{0.f, 0.f, 0.f, 0.f};

  for (int nt = 0; nt < 16; ++nt) {
    const int cur = nt & 1;
    char* Kc = cur ? Ks1 : Ks0;
    char* Vc = cur ? Vs1 : Vs0;
    char* Kn = cur ? Ks0 : Ks1;
    char* Vn = cur ? Vs0 : Vs1;

    // DMA next K/V tile into the free buffer (drains at this iter's end).
    if (nt + 1 < 16) {
      stage_tile(k2h + zoff + (long)(nt + 1) * 4096, 64, Kn, 8192, tid);
      stage_tile(vth + zoff + (nt + 1) * 64, 1024, Vn, 8192, tid);
    }
    // wn/bn prefetch into regs (compiler waits before LN use).
    f32x4 wreg[4], breg[4];
#pragma unroll
    for (int rr = 0; rr < 4; ++rr) {
      const long grow = (long)mt * 64 + rr * 16 + lr;
      const long gcol = (long)nt * 64 + c0;
      wreg[rr] = *(const f32x4*)&wn[((long)h * 1024 + grow) * 1024 + gcol];
      breg[rr] = *(const f32x4*)&bn[((long)h * 1024 + grow) * 1024 + gcol];
    }

    // ---- QK^T: scores[i,j] = sum_d q2[i,d] k2[j,d], single pass ----
    f32x4 acc[2][2];
#pragma unroll
    for (int m = 0; m < 2; ++m)
#pragma unroll
      for (int n = 0; n < 2; ++n) acc[m][n] = f32x4{0.f, 0.f, 0.f, 0.f};
#pragma unroll
    for (int ks = 0; ks < 2; ++ks) {
      const int ko = (ks * 64 + (lane >> 4) * 16) ^ sw;
      bf16x8 av[2], bv[2];
#pragma unroll
      for (int m = 0; m < 2; ++m)
        av[m] = *(const bf16x8*)(Qs + (wr * 32 + m * 16 + l15) * 128 + ko);
#pragma unroll
      for (int n = 0; n < 2; ++n)
        bv[n] = *(const bf16x8*)(Kc + (wc * 32 + n * 16 + l15) * 128 + ko);
#pragma unroll
      for (int m = 0; m < 2; ++m)
#pragma unroll
        for (int n = 0; n < 2; ++n)
          acc[m][n] = __builtin_amdgcn_mfma_f32_16x16x32_bf16(av[m], bv[n], acc[m][n], 0, 0, 0);
    }
    // raw scores -> swizzled Pf: slot(i,j) = j ^ (((i^(i>>2))&7)<<2)
#pragma unroll
    for (int m = 0; m < 2; ++m)
#pragma unroll
      for (int n = 0; n < 2; ++n)
#pragma unroll
        for (int r = 0; r < 4; ++r) {
          const int i = wr * 32 + m * 16 + (lane >> 4) * 4 + r;
          const int j = wc * 32 + n * 16 + l15;
          const int sp = ((i ^ (i >> 2)) & 7) << 2;
          Pf[i * 64 + (j ^ sp)] = acc[m][n][r];
        }
    __syncthreads();    // sync1: Pf visible to all waves

    // ---- LN pass: coalesced; wn/bn from regs; write attn + Ph ----
#pragma unroll
    for (int rr = 0; rr < 4; ++rr) {
      const int row = rr * 16 + lr;
      const int sp = ((row ^ (row >> 2)) & 7) << 2;
      const long grow = (long)mt * 64 + row;
      const long gcol = (long)nt * 64 + c0;
      const f32x4 s = *(const f32x4*)&Pf[row * 64 + (c0 ^ sp)];
      f32x4 r4;
      bf16x4 h4;
#pragma unroll
      for (int e = 0; e < 4; ++e) {
        const float r = (s[e] - mu) * rs * wreg[rr][e] + breg[rr][e];
        r4[e] = r;
        h4[e] = (bf16)r;
      }
      *(f32x4*)&attn_out[((long)zq * 1024 + grow) * 1024 + gcol] = r4;
      *(bf16x4*)(Ph + row * 128 + ((c0 * 2) ^ ((row & 7) << 4))) = h4;
    }
    __syncthreads();    // sync2: Ph visible

    // ---- PV: out[i,d] += sum_j p[i,j] vT[d,j], single pass ----
#pragma unroll
    for (int ks = 0; ks < 2; ++ks) {
      const int ko = (ks * 64 + (lane >> 4) * 16) ^ sw;
      bf16x8 av[2], bv[2];
#pragma unroll
      for (int m = 0; m < 2; ++m)
        av[m] = *(const bf16x8*)(Ph + (wr * 32 + m * 16 + l15) * 128 + ko);
#pragma unroll
      for (int n = 0; n < 2; ++n)
        bv[n] = *(const bf16x8*)(Vc + (wc * 32 + n * 16 + l15) * 128 + ko);
#pragma unroll
      for (int m = 0; m < 2; ++m)
#pragma unroll
        for (int n = 0; n < 2; ++n)
          oacc[m][n] = __builtin_amdgcn_mfma_f32_16x16x32_bf16(av[m], bv[n], oacc[m][n], 0, 0, 0);
    }
    waitvm<0>();        // next-tile DMA landed (had full compute phase)
    __syncthreads();    // sync3: PV reads done; next iter may overwrite
  }

  // ---- epilogue: o -> (B,N,C) bf16 ----
#pragma unroll
  for (int m = 0; m < 2; ++m)
#pragma unroll
    for (int n = 0; n < 2; ++n)
#pragma unroll
      for (int r = 0; r < 4; ++r) {
        const int row = mt * 64 + wr * 32 + m * 16 + (lane >> 4) * 4 + r;
        const int col = wc * 32 + n * 16 + l15;
        oh[((long)(b * 1024 + row)) * 768 + h * 64 + col] = (bf16)oacc[m][n][r];
      }
}

// ---------------------------------------------------------------------------
// Elementwise helpers
// ---------------------------------------------------------------------------
__global__ void cast_bf16(const float* __restrict__ s, bf16* __restrict__ d, int n)
{
  const int i = blockIdx.x * 256 + threadIdx.x;
  if (i < n) d[i] = (bf16)s[i];
}

// LayerNorm over rows of 768; writes bf16 (+ optional f32).
__global__ __launch_bounds__(256) void ln_row(
    const float* __restrict__ in, const float* __restrict__ w,
    const float* __restrict__ b, bf16* __restrict__ outh,
    float* __restrict__ outf)
{
  __shared__ float red[256];
  const int row = blockIdx.x, tid = threadIdx.x;
  const float* p = in + (long)row * 768;
  const float v0 = p[tid], v1 = p[tid + 256], v2 = p[tid + 512];
  red[tid] = v0 + v1 + v2;
  __syncthreads();
  for (int st = 128; st > 0; st >>= 1) { if (tid < st) red[tid] += red[tid + st]; __syncthreads(); }
  const float mu = red[0] * (1.0f / 768.0f);
  __syncthreads();
  const float d0 = v0 - mu, d1 = v1 - mu, d2 = v2 - mu;
  red[tid] = d0 * d0 + d1 * d1 + d2 * d2;
  __syncthreads();
  for (int st = 128; st > 0; st >>= 1) { if (tid < st) red[tid] += red[tid + st]; __syncthreads(); }
  const float rs = rsqrtf(red[0] * (1.0f / 768.0f) + 1e-5f);
  const float dv[3] = {d0, d1, d2};
#pragma unroll
  for (int k = 0; k < 3; ++k) {
    const int c = tid + k * 256;
    const float h = dv[k] * rs * w[c] + b[c];
    outh[(long)row * 768 + c] = (bf16)h;
    if (outf) outf[(long)row * 768 + c] = h;
  }
}

// Per (b,n): normalize q,k head-vectors -> (q/||q||)^2 bf16 (B,H,N,D);
// v -> bf16 (B,H,N,D).
__global__ __launch_bounds__(256) void qkv_post(
    const bf16* __restrict__ qkv, bf16* __restrict__ q2h,
    bf16* __restrict__ k2h, bf16* __restrict__ vb)
{
  const int row = blockIdx.x;           // b*1024+n
  const int b = row >> 10, n = row & 1023;
  const int wv = threadIdx.x >> 6, lane = threadIdx.x & 63;
  for (int t = wv; t < 36; t += 4) {
    const int s = t / 12, h = t - s * 12;
    const float val = (float)qkv[(long)row * 2304 + s * 768 + h * 64 + lane];
    const long addr = (((long)(b * 12 + h)) * 1024 + n) * 64 + lane;
    if (s == 2) {
      vb[addr] = (bf16)val;
    } else {
      const float sq = val * val;
      float tot = sq;
#pragma unroll
      for (int d = 1; d < 64; d <<= 1) tot += __shfl_xor(tot, d);
      const float q2 = sq / tot;
      if (s == 0) q2h[addr] = (bf16)q2;
      else        k2h[addr] = (bf16)q2;
    }
  }
}

// v (B,H,N,D) bf16 -> vT (B,H,D,N) bf16, 64x64 tiles.
__global__ __launch_bounds__(256) void transpose_v(
    const bf16* __restrict__ vb, bf16* __restrict__ vth)
{
  __shared__ float t[64][65];
  const int z = blockIdx.y, n0 = blockIdx.x * 64, tid = threadIdx.x;
  const bf16* srcp = vb + ((long)z * 1024 + n0) * 64;
  for (int e = tid; e < 4096; e += 256) t[e >> 6][e & 63] = (float)srcp[e];
  __syncthreads();
  for (int e = tid; e < 4096; e += 256) {
    const int d = e >> 6, c = e & 63;
    vth[((long)z * 64 + d) * 1024 + n0 + c] = (bf16)t[c][d];
  }
}

// Gram partials: Gq += q2^T q2 (64x64), Gk likewise; Sq/Sk column sums.
__global__ __launch_bounds__(256) void stats_accum(
    const bf16* __restrict__ q2h, const bf16* __restrict__ k2h,
    float* __restrict__ Gq, float* __restrict__ Gk,
    float* __restrict__ Sq, float* __restrict__ Sk)
{
  __shared__ float rowbuf[8][128];     // 8 rows x (64 q | 64 k)
  const int tid = threadIdx.x;
  const int z = blockIdx.y;
  const long base = ((long)z * 1024 + (long)blockIdx.x * 128) * 64;
  const int tx = tid & 15, ty = tid >> 4;
  float gq[4][4] = {}, gk[4][4] = {};
  float sq = 0.f, sk = 0.f;
  for (int r0 = 0; r0 < 128; r0 += 8) {
    __syncthreads();
#pragma unroll
    for (int i = 0; i < 4; ++i) {
      const int idx = tid + i * 256;   // 0..1023 over 8x128
      const int rr = idx >> 7, cc = idx & 127;
      const long a = base + (long)(r0 + rr) * 64 + (cc & 63);
      rowbuf[rr][cc] = (cc < 64) ? (float)q2h[a] : (float)k2h[a];
    }
    __syncthreads();
#pragma unroll
    for (int r = 0; r < 8; ++r) {
      float qa[4], qe[4], ka[4], ke[4];
#pragma unroll
      for (int i = 0; i < 4; ++i) {
        qa[i] = rowbuf[r][ty * 4 + i]; qe[i] = rowbuf[r][tx * 4 + i];
        ka[i] = rowbuf[r][64 + ty * 4 + i]; ke[i] = rowbuf[r][64 + tx * 4 + i];
      }
#pragma unroll
      for (int i = 0; i < 4; ++i)
#pragma unroll
        for (int j = 0; j < 4; ++j) {
          gq[i][j] += qa[i] * qe[j];
          gk[i][j] += ka[i] * ke[j];
        }
    }
    if (tid < 128) {
      float s = 0.f;
#pragma unroll
      for (int r = 0; r < 8; ++r) s += rowbuf[r][tid];
      if (tid < 64) sq += s; else sk += s;
    }
  }
#pragma unroll
  for (int i = 0; i < 4; ++i)
#pragma unroll
    for (int j = 0; j < 4; ++j) {
      atomicAdd(&Gq[(long)z * 4096 + (ty * 4 + i) * 64 + tx * 4 + j], gq[i][j]);
      atomicAdd(&Gk[(long)z * 4096 + (ty * 4 + i) * 64 + tx * 4 + j], gk[i][j]);
    }
  if (tid < 64) atomicAdd(&Sq[z * 64 + tid], sq);
  else if (tid < 128) atomicAdd(&Sk[z * 64 + tid - 64], sk);
}

// Per-batch mean / rstd of the attn tensor from Gram partials.
__global__ __launch_bounds__(256) void stats_final(
    const float* __restrict__ Gq, const float* __restrict__ Gk,
    const float* __restrict__ Sq, const float* __restrict__ Sk,
    float* __restrict__ stats)
{
  __shared__ double red[256];
  const int b = blockIdx.x, tid = threadIdx.x;
  double s2 = 0.0, s1 = 0.0;
  for (int h = 0; h < 12; ++h) {
    const float* gq = Gq + ((long)(b * 12 + h)) * 4096;
    const float* gk = Gk + ((long)(b * 12 + h)) * 4096;
    for (int i = tid; i < 4096; i += 256) s2 += (double)gq[i] * (double)gk[i];
    const float* sqp = Sq + (b * 12 + h) * 64;
    const float* skp = Sk + (b * 12 + h) * 64;
    for (int i = tid; i < 64; i += 256) s1 += (double)sqp[i] * (double)skp[i];
  }
  red[tid] = s2; __syncthreads();
  for (int st = 128; st > 0; st >>= 1) { if (tid < st) red[tid] += red[tid + st]; __syncthreads(); }
  const double S2 = red[0]; __syncthreads();
  red[tid] = s1; __syncthreads();
  for (int st = 128; st > 0; st >>= 1) { if (tid < st) red[tid] += red[tid + st]; __syncthreads(); }
  if (tid == 0) {
    const double S1 = red[0];
    const double cnt = 12.0 * 1024.0 * 1024.0;
    const double mean = S1 / cnt;
    const double var = S2 / cnt - mean * mean;
    stats[2 * b] = (float)mean;
    stats[2 * b + 1] = (float)(1.0 / sqrt(var + 1e-5));
  }
}

// ---------------------------------------------------------------------------
extern "C" void kernel_launch(void* const* d_in, const int* in_sizes, int n_in,
                              void* d_out, int out_size, void* d_ws, size_t ws_size,
                              hipStream_t stream)
{
  const float* x      = (const float*)d_in[0];
  const float* ln0_w  = (const float*)d_in[1];
  const float* ln0_b  = (const float*)d_in[2];
  const float* qkv_w  = (const float*)d_in[3];
  const float* qkv_b  = (const float*)d_in[4];
  const float* proj_w = (const float*)d_in[5];
  const float* proj_b = (const float*)d_in[6];
  const float* attn_w = (const float*)d_in[7];
  const float* attn_b = (const float*)d_in[8];
  const float* ln1_w  = (const float*)d_in[9];
  const float* ln1_b  = (const float*)d_in[10];
  const float* fc1_w  = (const float*)d_in[11];
  const float* fc1_b  = (const float*)d_in[12];
  const float* fc2_w  = (const float*)d_in[13];
  const float* fc2_b  = (const float*)d_in[14];

  float* out_src  = (float*)d_out;
  float* out_attn = out_src + 4L * 1024 * 768;       // 3145728

  char* p = (char*)d_ws;
  auto take = [&](long bytes) -> char* {
    char* r = p;
    p += (bytes + 255) & ~255L;
    return r;
  };
  bf16* qkvw_h = (bf16*)take(3538944);
  bf16* projw_h = (bf16*)take(1179648);
  bf16* fc1w_h = (bf16*)take(4718592);
  bf16* fc2w_h = (bf16*)take(4718592);
  char* regB = take(12582912);                 // hh, later src_f32
  bf16* hh = (bf16*)regB;
  float* src = (float*)regB;
  char* regC = take(37748736);                 // qkv bf16, later gelu acts + ln1f
  bf16* qkvb = (bf16*)regC;                    // [0, 18874368) bf16 4096x2304
  bf16* gact = (bf16*)regC;                    // [0, 25165824) bf16 4096x3072
  float* ln1f = (float*)(regC + 25165824);     // [25165824, 37748736) f32
  bf16* q2h = (bf16*)take(6291456);
  bf16* k2h = (bf16*)take(6291456);
  bf16* vb  = (bf16*)take(6291456);
  bf16* vth = (bf16*)take(6291456);
  bf16* oh  = (bf16*)take(6291456);
  bf16* h1v = (bf16*)take(6291456);
  float* Gq = (float*)take(786432);
  float* Gk = (float*)take(786432);
  float* Sq = (float*)take(12288);
  float* Sk = (float*)take(12288);
  float* stats = (float*)take(256);

  const dim3 blk(256);

  (void)hipMemsetAsync((void*)Gq, 0, 786432 * 2 + 12288 * 2 + 256, stream);

  cast_bf16<<<dim3((1769472 + 255) / 256), blk, 0, stream>>>(qkv_w, qkvw_h, 1769472);
  cast_bf16<<<dim3((589824 + 255) / 256), blk, 0, stream>>>(proj_w, projw_h, 589824);
  cast_bf16<<<dim3((2359296 + 255) / 256), blk, 0, stream>>>(fc1_w, fc1w_h, 2359296);
  cast_bf16<<<dim3((2359296 + 255) / 256), blk, 0, stream>>>(fc2_w, fc2w_h, 2359296);

  ln_row<<<dim3(4096), blk, 0, stream>>>(x, ln0_w, ln0_b, hh, nullptr);

  gemm_k<128, 128, 2, 4, 4, 1, 2, EpiQKV><<<dim3(18, 32, 1), blk, 0, stream>>>(
      hh, nullptr, 0, qkvw_h, nullptr, 0, 768, 768, 768, EpiQKV{qkv_b, qkvb});

  qkv_post<<<dim3(4096), blk, 0, stream>>>(qkvb, q2h, k2h, vb);
  transpose_v<<<dim3(16, 48), blk, 0, stream>>>(vb, vth);
  stats_accum<<<dim3(8, 48), blk, 0, stream>>>(q2h, k2h, Gq, Gk, Sq, Sk);
  stats_final<<<dim3(4), blk, 0, stream>>>(Gq, Gk, Sq, Sk, stats);

  attn_fused<<<dim3(16, 48), blk, 0, stream>>>(
      q2h, k2h, vth, stats, attn_w, attn_b, out_attn, oh);

  gemm_k<128, 128, 2, 4, 4, 1, 2, EpiProj><<<dim3(6, 32, 1), blk, 0, stream>>>(
      oh, nullptr, 0, projw_h, nullptr, 0, 768, 768, 768, EpiProj{proj_b, x, src});

  ln_row<<<dim3(4096), blk, 0, stream>>>(src, ln1_w, ln1_b, h1v, ln1f);

  gemm_k<128, 128, 2, 4, 4, 1, 2, EpiGelu><<<dim3(24, 32, 1), blk, 0, stream>>>(
      h1v, nullptr, 0, fc1w_h, nullptr, 0, 768, 768, 768, EpiGelu{fc1_b, gact});

  gemm_k<128, 128, 2, 4, 4, 1, 2, EpiOut><<<dim3(6, 32, 1), blk, 0, stream>>>(
      gact, nullptr, 0, fc2w_h, nullptr, 0, 3072, 3072, 3072, EpiOut{fc2_b, ln1f, out_src});
}

// Round 8
// 387.999 us; speedup vs baseline: 1.8334x; 1.1576x over previous
//
#include <hip/hip_runtime.h>

typedef __bf16 bf16;
typedef __bf16 bf16x4 __attribute__((ext_vector_type(4)));
typedef __bf16 bf16x8 __attribute__((ext_vector_type(8)));
typedef float f32x4 __attribute__((ext_vector_type(4)));

#define DEVI __device__ __forceinline__

typedef const __attribute__((address_space(1))) void* gas1;
typedef __attribute__((address_space(3))) void* las3;

// ---------------------------------------------------------------------------
// Stage a [rows x 64] bf16 tile (row bytes = 128) into LDS via global_load_lds,
// with st-style XOR swizzle: LDS[addr(row,c)] where addr applies c^((row&7)<<4).
// Linear LDS dest + pre-swizzled global source; every ds_read applies same XOR.
// ---------------------------------------------------------------------------
DEVI void stage_tile(const bf16* g, int ld, char* lds, int bytes, int tid)
{
  const int wv = tid >> 6, lane = tid & 63;
  const char* gb = (const char*)g;
  const long rowb = (long)ld * 2;
  for (int off = wv * 1024; off < bytes; off += 4096) {
    const int o  = off + lane * 16;                 // linear LDS dest
    const int s  = o ^ (((o >> 7) & 7) << 4);       // pre-swizzled source pos
    const int r  = s >> 7;                          // 128B per tile row
    const int cb = s & 127;
    __builtin_amdgcn_global_load_lds((gas1)(gb + (long)r * rowb + cb),
                                     (las3)(lds + off), 16, 0, 0);
  }
}

template<int N> DEVI void waitvm()
{
  if constexpr (N == 8)      asm volatile("s_waitcnt vmcnt(8)" ::: "memory");
  else if constexpr (N == 6) asm volatile("s_waitcnt vmcnt(6)" ::: "memory");
  else if constexpr (N == 4) asm volatile("s_waitcnt vmcnt(4)" ::: "memory");
  else if constexpr (N == 2) asm volatile("s_waitcnt vmcnt(2)" ::: "memory");
  else                       asm volatile("s_waitcnt vmcnt(0)" ::: "memory");
}

// ---------------------------------------------------------------------------
// Epilogue functors
// ---------------------------------------------------------------------------
struct EpiQKV {
  const float* bias; bf16* C;
  DEVI void operator()(int z, int row, int col, float v) const {
    C[(long)row * 2304 + col] = (bf16)(v + bias[col]);
  }
};

struct EpiProj {
  const float* bias; const float* x; float* src;
  DEVI void operator()(int z, int row, int col, float v) const {
    const long i = (long)row * 768 + col;
    src[i] = v + bias[col] + x[i];
  }
};

struct EpiGelu {
  const float* bias; bf16* g;
  DEVI void operator()(int z, int row, int col, float v) const {
    const float t = v + bias[col];
    const float r = 0.5f * t * (1.0f + erff(t * 0.70710678118654752f));
    g[(long)row * 3072 + col] = (bf16)r;
  }
};

struct EpiOut {
  const float* bias; const float* lnf; float* outp;
  DEVI void operator()(int z, int row, int col, float v) const {
    const long i = (long)row * 768 + col;
    outp[i] = v + bias[col] + lnf[i];   // final residual uses POST-LN1 src
  }
};

// ---------------------------------------------------------------------------
// bf16 GEMM, 2-phase double-buffered, counted vmcnt (T3/T4 minimum form).
// 64x64 tiles, 4 waves (2x2), FM=FN=2. WPE blocks/CU via launch bounds.
// ---------------------------------------------------------------------------
template<int BM, int BN, int WC, int FM, int FN, int WPE, class Epi>
__global__ __launch_bounds__(256, WPE) void gemm_k(
    const bf16* __restrict__ A, long abatch,
    const bf16* __restrict__ B, long bbatch,
    int lda, int ldb, int K, Epi epi)
{
  constexpr int BK = 64;
  constexpr int AB = BM * BK * 2, BB = BN * BK * 2;
  constexpr int BUFB = AB + BB;
  constexpr int LPS = BUFB / 4096;          // global_load_lds per wave per stage
  __shared__ char smem[2 * BUFB];

  const int tid = threadIdx.x, lane = tid & 63, wv = tid >> 6;
  const int wr = wv / WC, wc = wv % WC;
  const int mt = blockIdx.y, nt = blockIdx.x, z = blockIdx.z;
  const long abase = (long)z * abatch + (long)mt * BM * lda;
  const long bbase = (long)z * bbatch + (long)nt * BN * ldb;
  const int l15 = lane & 15;
  const int sw = (lane & 7) << 4;           // per-lane read swizzle

  auto stage_all = [&](int buf, int kt) {
    char* base = smem + buf * BUFB;
    stage_tile(A + abase + kt, lda, base, AB, tid);
    stage_tile(B + bbase + kt, ldb, base + AB, BB, tid);
  };

  f32x4 acc[FM][FN];
#pragma unroll
  for (int m = 0; m < FM; ++m)
#pragma unroll
    for (int n = 0; n < FN; ++n) acc[m][n] = f32x4{0.f, 0.f, 0.f, 0.f};

  const int arow = wr * FM * 16, bcol = wc * FN * 16;
  const int T = K / BK;

  stage_all(0, 0);
  int cur = 0;
  for (int t = 0; t < T; ++t) {
    if (t + 1 < T) { stage_all(cur ^ 1, (t + 1) * BK); waitvm<LPS>(); }
    else           { waitvm<0>(); }
    __builtin_amdgcn_s_barrier();
    asm volatile("" ::: "memory");

    const char* As = smem + cur * BUFB;
    const char* Bs = As + AB;
#pragma unroll
    for (int ks = 0; ks < 2; ++ks) {
      const int ko = (ks * 64 + (lane >> 4) * 16) ^ sw;
      bf16x8 av[FM], bv[FN];
#pragma unroll
      for (int m = 0; m < FM; ++m)
        av[m] = *(const bf16x8*)(As + (arow + m * 16 + l15) * 128 + ko);
#pragma unroll
      for (int n = 0; n < FN; ++n)
        bv[n] = *(const bf16x8*)(Bs + (bcol + n * 16 + l15) * 128 + ko);
#pragma unroll
      for (int m = 0; m < FM; ++m)
#pragma unroll
        for (int n = 0; n < FN; ++n)
          acc[m][n] = __builtin_amdgcn_mfma_f32_16x16x32_bf16(av[m], bv[n], acc[m][n], 0, 0, 0);
    }
    asm volatile("s_waitcnt lgkmcnt(0)" ::: "memory");   // LDS reads done
    __builtin_amdgcn_s_barrier();                         // before buf reuse
    asm volatile("" ::: "memory");
    cur ^= 1;
  }

#pragma unroll
  for (int m = 0; m < FM; ++m)
#pragma unroll
    for (int n = 0; n < FN; ++n)
#pragma unroll
      for (int r = 0; r < 4; ++r) {
        const int grow = mt * BM + arow + m * 16 + (lane >> 4) * 4 + r;
        const int gcol = nt * BN + bcol + n * 16 + l15;
        epi(z, grow, gcol, acc[m][n][r]);
      }
}

// ---------------------------------------------------------------------------
// Fused attention tail — wave-owns-rows decomposition.
// Each of 4 waves owns 16 score rows; P scratch (2KB/wave) is wave-private.
// RACE FIX vs R7: the QK^T->LN and LN->PV hand-offs are cross-LANE RAW
// through LDS — the per-lane memory model gives no ordering, so each phase
// boundary needs an explicit sync. Use __syncthreads() (proven R6 pattern).
// Scores stored in-place as bf16 s_ln=(s-mu)*rs; LN computes r=s_ln*w+b,
// writes attn_out f32 and bf16(r) back to the same slot for PV.
// LDS 48KB -> 3 blocks/CU; grid 768 = 3*256 exact.
// ---------------------------------------------------------------------------
__global__ __launch_bounds__(256, 3) void attn_fused(
    const bf16* __restrict__ q2h, const bf16* __restrict__ k2h,
    const bf16* __restrict__ vth, const float* __restrict__ stats,
    const float* __restrict__ wn, const float* __restrict__ bn,
    float* __restrict__ attn_out, bf16* __restrict__ oh)
{
  __shared__ char smem[49152];
  char* Qs  = smem;                    //  8KB  64x64 bf16 (swizzled)
  char* Ks0 = smem + 8192;
  char* Ks1 = smem + 16384;
  char* Vs0 = smem + 24576;
  char* Vs1 = smem + 32768;
  char* Pall = smem + 40960;           //  8KB: 4 waves x [16][64] bf16 (swz)

  const int tid = threadIdx.x, lane = tid & 63, wv = tid >> 6;
  const int mt = blockIdx.x, z = blockIdx.y;
  const int h = z >> 2, b = z & 3;
  const int zq = b * 12 + h;
  const float mu = stats[2 * b], rs = stats[2 * b + 1];
  const int l15 = lane & 15, lhi = lane >> 4;
  const int sw = (lane & 7) << 4;
  char* Ps = Pall + wv * 2048;         // wave-private [16 rows][128B]

  const long zoff = (long)zq * 65536;
  stage_tile(q2h + zoff + (long)mt * 4096, 64, Qs, 8192, tid);
  stage_tile(k2h + zoff, 64, Ks0, 8192, tid);
  stage_tile(vth + zoff, 1024, Vs0, 8192, tid);
  __syncthreads();

  f32x4 oacc[4];
#pragma unroll
  for (int n = 0; n < 4; ++n) oacc[n] = f32x4{0.f, 0.f, 0.f, 0.f};

  for (int nt = 0; nt < 16; ++nt) {
    const int cur = nt & 1;
    char* Kc = cur ? Ks1 : Ks0;
    char* Vc = cur ? Vs1 : Vs0;
    char* Kn = cur ? Ks0 : Ks1;
    char* Vn = cur ? Vs0 : Vs1;

    if (nt + 1 < 16) {
      stage_tile(k2h + zoff + (long)(nt + 1) * 4096, 64, Kn, 8192, tid);
      stage_tile(vth + zoff + (nt + 1) * 64, 1024, Vn, 8192, tid);
    }
    // wn/bn for this tile: wave rows wv*16..+16, cols nt*64..+64, coalesced.
    f32x4 wreg[4], breg[4];
#pragma unroll
    for (int rr = 0; rr < 4; ++rr) {
      const long grow = (long)mt * 64 + wv * 16 + rr * 4 + lhi;
      const long gcol = (long)nt * 64 + l15 * 4;
      wreg[rr] = *(const f32x4*)&wn[((long)h * 1024 + grow) * 1024 + gcol];
      breg[rr] = *(const f32x4*)&bn[((long)h * 1024 + grow) * 1024 + gcol];
    }

    // ---- QK^T: wave computes its 16 rows x all 64 cols ----
    f32x4 acc[4];
#pragma unroll
    for (int n = 0; n < 4; ++n) acc[n] = f32x4{0.f, 0.f, 0.f, 0.f};
#pragma unroll
    for (int ks = 0; ks < 2; ++ks) {
      const int ko = (ks * 64 + lhi * 16) ^ sw;
      const bf16x8 av = *(const bf16x8*)(Qs + (wv * 16 + l15) * 128 + ko);
#pragma unroll
      for (int n = 0; n < 4; ++n) {
        const bf16x8 bv = *(const bf16x8*)(Kc + (n * 16 + l15) * 128 + ko);
        acc[n] = __builtin_amdgcn_mfma_f32_16x16x32_bf16(av, bv, acc[n], 0, 0, 0);
      }
    }
    // s_ln = (s-mu)*rs -> bf16, into wave-private Ps (swizzled).
#pragma unroll
    for (int n = 0; n < 4; ++n)
#pragma unroll
      for (int r = 0; r < 4; ++r) {
        const int row = lhi * 4 + r;                 // local row 0..15
        const int cb = (n * 32 + l15 * 2) ^ ((row & 7) << 4);
        *(bf16*)(Ps + row * 128 + cb) = (bf16)((acc[n][r] - mu) * rs);
      }
    __syncthreads();   // cross-lane RAW: QK^T writes -> LN reads

    // ---- LN: r = s_ln*w + b -> attn_out f32 + Ps in-place ----
#pragma unroll
    for (int rr = 0; rr < 4; ++rr) {
      const int row = rr * 4 + lhi;                  // local row 0..15
      const int cb = (l15 * 8) ^ ((row & 7) << 4);
      const bf16x4 s4 = *(const bf16x4*)(Ps + row * 128 + cb);
      const long grow = (long)mt * 64 + wv * 16 + row;
      const long gcol = (long)nt * 64 + l15 * 4;
      f32x4 r4;
      bf16x4 h4;
#pragma unroll
      for (int e = 0; e < 4; ++e) {
        const float r = (float)s4[e] * wreg[rr][e] + breg[rr][e];
        r4[e] = r;
        h4[e] = (bf16)r;
      }
      *(f32x4*)&attn_out[((long)zq * 1024 + grow) * 1024 + gcol] = r4;
      *(bf16x4*)(Ps + row * 128 + cb) = h4;
    }
    __syncthreads();   // cross-lane RAW: LN write-back -> PV reads

    // ---- PV: o[row, d] += sum_j P[row,j] vT[d,j] ----
#pragma unroll
    for (int ks = 0; ks < 2; ++ks) {
      const int ko = (ks * 64 + lhi * 16) ^ sw;
      const bf16x8 av = *(const bf16x8*)(Ps + l15 * 128 + ko);
#pragma unroll
      for (int n = 0; n < 4; ++n) {
        const bf16x8 bv = *(const bf16x8*)(Vc + (n * 16 + l15) * 128 + ko);
        oacc[n] = __builtin_amdgcn_mfma_f32_16x16x32_bf16(av, bv, oacc[n], 0, 0, 0);
      }
    }
    __syncthreads();   // drains DMA (vmcnt) + protects K/V dbuf + Ps WAR
  }

  // ---- epilogue: o -> (B,N,C) bf16 ----
#pragma unroll
  for (int n = 0; n < 4; ++n)
#pragma unroll
    for (int r = 0; r < 4; ++r) {
      const int row = mt * 64 + wv * 16 + lhi * 4 + r;
      const int col = n * 16 + l15;
      oh[((long)(b * 1024 + row)) * 768 + h * 64 + col] = (bf16)oacc[n][r];
    }
}

// ---------------------------------------------------------------------------
// Elementwise helpers
// ---------------------------------------------------------------------------
__global__ void cast_bf16(const float* __restrict__ s, bf16* __restrict__ d, int n)
{
  const int i = blockIdx.x * 256 + threadIdx.x;
  if (i < n) d[i] = (bf16)s[i];
}

// LayerNorm over rows of 768; writes bf16 (+ optional f32).
__global__ __launch_bounds__(256) void ln_row(
    const float* __restrict__ in, const float* __restrict__ w,
    const float* __restrict__ b, bf16* __restrict__ outh,
    float* __restrict__ outf)
{
  __shared__ float red[256];
  const int row = blockIdx.x, tid = threadIdx.x;
  const float* p = in + (long)row * 768;
  const float v0 = p[tid], v1 = p[tid + 256], v2 = p[tid + 512];
  red[tid] = v0 + v1 + v2;
  __syncthreads();
  for (int st = 128; st > 0; st >>= 1) { if (tid < st) red[tid] += red[tid + st]; __syncthreads(); }
  const float mu = red[0] * (1.0f / 768.0f);
  __syncthreads();
  const float d0 = v0 - mu, d1 = v1 - mu, d2 = v2 - mu;
  red[tid] = d0 * d0 + d1 * d1 + d2 * d2;
  __syncthreads();
  for (int st = 128; st > 0; st >>= 1) { if (tid < st) red[tid] += red[tid + st]; __syncthreads(); }
  const float rs = rsqrtf(red[0] * (1.0f / 768.0f) + 1e-5f);
  const float dv[3] = {d0, d1, d2};
#pragma unroll
  for (int k = 0; k < 3; ++k) {
    const int c = tid + k * 256;
    const float h = dv[k] * rs * w[c] + b[c];
    outh[(long)row * 768 + c] = (bf16)h;
    if (outf) outf[(long)row * 768 + c] = h;
  }
}

// Per (b,n): normalize q,k head-vectors -> (q/||q||)^2 bf16; v passthrough.
// 8-lane subgroup per head vector; bf16x8 vector loads/stores (G13).
__global__ __launch_bounds__(256) void qkv_post(
    const bf16* __restrict__ qkv, bf16* __restrict__ q2h,
    bf16* __restrict__ k2h, bf16* __restrict__ vb)
{
  const int row = blockIdx.x;           // b*1024+n
  const int b = row >> 10, n = row & 1023;
  const int sg = threadIdx.x >> 3, l8 = threadIdx.x & 7;
  for (int t = sg; t < 36; t += 32) {
    const int s = t / 12, h = t - s * 12;
    const bf16x8 v8 = *(const bf16x8*)&qkv[(long)row * 2304 + s * 768 + h * 64 + l8 * 8];
    const long addr = (((long)(b * 12 + h)) * 1024 + n) * 64 + l8 * 8;
    if (s == 2) {
      *(bf16x8*)&vb[addr] = v8;
    } else {
      float f[8];
      float sq = 0.f;
#pragma unroll
      for (int e = 0; e < 8; ++e) { f[e] = (float)v8[e]; sq += f[e] * f[e]; }
      float tot = sq;
      tot += __shfl_xor(tot, 1);
      tot += __shfl_xor(tot, 2);
      tot += __shfl_xor(tot, 4);
      const float inv = 1.0f / tot;
      bf16x8 o;
#pragma unroll
      for (int e = 0; e < 8; ++e) o[e] = (bf16)(f[e] * f[e] * inv);
      if (s == 0) *(bf16x8*)&q2h[addr] = o;
      else        *(bf16x8*)&k2h[addr] = o;
    }
  }
}

// v (B,H,N,D) bf16 -> vT (B,H,D,N) bf16, 64x64 tiles, vectorized both sides.
__global__ __launch_bounds__(256) void transpose_v(
    const bf16* __restrict__ vb, bf16* __restrict__ vth)
{
  __shared__ float t[64][65];
  const int z = blockIdx.y, n0 = blockIdx.x * 64, tid = threadIdx.x;
  const bf16* srcp = vb + ((long)z * 1024 + n0) * 64;
  for (int e = tid * 8; e < 4096; e += 2048) {
    const bf16x8 v8 = *(const bf16x8*)&srcp[e];
    const int r = e >> 6, c = e & 63;
#pragma unroll
    for (int j = 0; j < 8; ++j) t[r][c + j] = (float)v8[j];
  }
  __syncthreads();
  for (int e = tid; e < 512; e += 256) {
    const int d = e >> 3, c0 = (e & 7) * 8;
    bf16x8 o;
#pragma unroll
    for (int j = 0; j < 8; ++j) o[j] = (bf16)t[c0 + j][d];
    *(bf16x8*)&vth[((long)z * 64 + d) * 1024 + n0 + c0] = o;
  }
}

// Gram partials: Gq += q2^T q2 (64x64), Gk likewise; Sq/Sk column sums.
__global__ __launch_bounds__(256) void stats_accum(
    const bf16* __restrict__ q2h, const bf16* __restrict__ k2h,
    float* __restrict__ Gq, float* __restrict__ Gk,
    float* __restrict__ Sq, float* __restrict__ Sk)
{
  __shared__ float rowbuf[8][128];     // 8 rows x (64 q | 64 k)
  const int tid = threadIdx.x;
  const int z = blockIdx.y;
  const long base = ((long)z * 1024 + (long)blockIdx.x * 128) * 64;
  const int tx = tid & 15, ty = tid >> 4;
  float gq[4][4] = {}, gk[4][4] = {};
  float sq = 0.f, sk = 0.f;
  for (int r0 = 0; r0 < 128; r0 += 8) {
    __syncthreads();
    {
      const int idx = tid * 4;         // 0..1023 over 8x128, bf16x4 loads
      const int rr = idx >> 7, cc = idx & 127;
      const long a = base + (long)(r0 + rr) * 64 + (cc & 63);
      const bf16x4 v4 = (cc < 64) ? *(const bf16x4*)&q2h[a]
                                  : *(const bf16x4*)&k2h[a];
#pragma unroll
      for (int j = 0; j < 4; ++j) rowbuf[rr][cc + j] = (float)v4[j];
    }
    __syncthreads();
#pragma unroll
    for (int r = 0; r < 8; ++r) {
      float qa[4], qe[4], ka[4], ke[4];
#pragma unroll
      for (int i = 0; i < 4; ++i) {
        qa[i] = rowbuf[r][ty * 4 + i]; qe[i] = rowbuf[r][tx * 4 + i];
        ka[i] = rowbuf[r][64 + ty * 4 + i]; ke[i] = rowbuf[r][64 + tx * 4 + i];
      }
#pragma unroll
      for (int i = 0; i < 4; ++i)
#pragma unroll
        for (int j = 0; j < 4; ++j) {
          gq[i][j] += qa[i] * qe[j];
          gk[i][j] += ka[i] * ke[j];
        }
    }
    if (tid < 128) {
      float s = 0.f;
#pragma unroll
      for (int r = 0; r < 8; ++r) s += rowbuf[r][tid];
      if (tid < 64) sq += s; else sk += s;
    }
  }
#pragma unroll
  for (int i = 0; i < 4; ++i)
#pragma unroll
    for (int j = 0; j < 4; ++j) {
      atomicAdd(&Gq[(long)z * 4096 + (ty * 4 + i) * 64 + tx * 4 + j], gq[i][j]);
      atomicAdd(&Gk[(long)z * 4096 + (ty * 4 + i) * 64 + tx * 4 + j], gk[i][j]);
    }
  if (tid < 64) atomicAdd(&Sq[z * 64 + tid], sq);
  else if (tid < 128) atomicAdd(&Sk[z * 64 + tid - 64], sk);
}

// Per-batch mean / rstd of the attn tensor from Gram partials.
__global__ __launch_bounds__(256) void stats_final(
    const float* __restrict__ Gq, const float* __restrict__ Gk,
    const float* __restrict__ Sq, const float* __restrict__ Sk,
    float* __restrict__ stats)
{
  __shared__ double red[256];
  const int b = blockIdx.x, tid = threadIdx.x;
  double s2 = 0.0, s1 = 0.0;
  for (int h = 0; h < 12; ++h) {
    const float* gq = Gq + ((long)(b * 12 + h)) * 4096;
    const float* gk = Gk + ((long)(b * 12 + h)) * 4096;
    for (int i = tid; i < 4096; i += 256) s2 += (double)gq[i] * (double)gk[i];
    const float* sqp = Sq + (b * 12 + h) * 64;
    const float* skp = Sk + (b * 12 + h) * 64;
    for (int i = tid; i < 64; i += 256) s1 += (double)sqp[i] * (double)skp[i];
  }
  red[tid] = s2; __syncthreads();
  for (int st = 128; st > 0; st >>= 1) { if (tid < st) red[tid] += red[tid + st]; __syncthreads(); }
  const double S2 = red[0]; __syncthreads();
  red[tid] = s1; __syncthreads();
  for (int st = 128; st > 0; st >>= 1) { if (tid < st) red[tid] += red[tid + st]; __syncthreads(); }
  if (tid == 0) {
    const double S1 = red[0];
    const double cnt = 12.0 * 1024.0 * 1024.0;
    const double mean = S1 / cnt;
    const double var = S2 / cnt - mean * mean;
    stats[2 * b] = (float)mean;
    stats[2 * b + 1] = (float)(1.0 / sqrt(var + 1e-5));
  }
}

// ---------------------------------------------------------------------------
extern "C" void kernel_launch(void* const* d_in, const int* in_sizes, int n_in,
                              void* d_out, int out_size, void* d_ws, size_t ws_size,
                              hipStream_t stream)
{
  const float* x      = (const float*)d_in[0];
  const float* ln0_w  = (const float*)d_in[1];
  const float* ln0_b  = (const float*)d_in[2];
  const float* qkv_w  = (const float*)d_in[3];
  const float* qkv_b  = (const float*)d_in[4];
  const float* proj_w = (const float*)d_in[5];
  const float* proj_b = (const float*)d_in[6];
  const float* attn_w = (const float*)d_in[7];
  const float* attn_b = (const float*)d_in[8];
  const float* ln1_w  = (const float*)d_in[9];
  const float* ln1_b  = (const float*)d_in[10];
  const float* fc1_w  = (const float*)d_in[11];
  const float* fc1_b  = (const float*)d_in[12];
  const float* fc2_w  = (const float*)d_in[13];
  const float* fc2_b  = (const float*)d_in[14];

  float* out_src  = (float*)d_out;
  float* out_attn = out_src + 4L * 1024 * 768;       // 3145728

  char* p = (char*)d_ws;
  auto take = [&](long bytes) -> char* {
    char* r = p;
    p += (bytes + 255) & ~255L;
    return r;
  };
  bf16* qkvw_h = (bf16*)take(3538944);
  bf16* projw_h = (bf16*)take(1179648);
  bf16* fc1w_h = (bf16*)take(4718592);
  bf16* fc2w_h = (bf16*)take(4718592);
  char* regB = take(12582912);                 // hh, later src_f32
  bf16* hh = (bf16*)regB;
  float* src = (float*)regB;
  char* regC = take(37748736);                 // qkv bf16, later gelu acts + ln1f
  bf16* qkvb = (bf16*)regC;                    // [0, 18874368) bf16 4096x2304
  bf16* gact = (bf16*)regC;                    // [0, 25165824) bf16 4096x3072
  float* ln1f = (float*)(regC + 25165824);     // [25165824, 37748736) f32
  bf16* q2h = (bf16*)take(6291456);
  bf16* k2h = (bf16*)take(6291456);
  bf16* vb  = (bf16*)take(6291456);
  bf16* vth = (bf16*)take(6291456);
  bf16* oh  = (bf16*)take(6291456);
  bf16* h1v = (bf16*)take(6291456);
  float* Gq = (float*)take(786432);
  float* Gk = (float*)take(786432);
  float* Sq = (float*)take(12288);
  float* Sk = (float*)take(12288);
  float* stats = (float*)take(256);

  const dim3 blk(256);

  (void)hipMemsetAsync((void*)Gq, 0, 786432 * 2 + 12288 * 2 + 256, stream);

  cast_bf16<<<dim3((1769472 + 255) / 256), blk, 0, stream>>>(qkv_w, qkvw_h, 1769472);
  cast_bf16<<<dim3((589824 + 255) / 256), blk, 0, stream>>>(proj_w, projw_h, 589824);
  cast_bf16<<<dim3((2359296 + 255) / 256), blk, 0, stream>>>(fc1_w, fc1w_h, 2359296);
  cast_bf16<<<dim3((2359296 + 255) / 256), blk, 0, stream>>>(fc2_w, fc2w_h, 2359296);

  ln_row<<<dim3(4096), blk, 0, stream>>>(x, ln0_w, ln0_b, hh, nullptr);

  gemm_k<64, 64, 2, 2, 2, 4, EpiQKV><<<dim3(36, 64, 1), blk, 0, stream>>>(
      hh, 0, qkvw_h, 0, 768, 768, 768, EpiQKV{qkv_b, qkvb});

  qkv_post<<<dim3(4096), blk, 0, stream>>>(qkvb, q2h, k2h, vb);
  transpose_v<<<dim3(16, 48), blk, 0, stream>>>(vb, vth);
  stats_accum<<<dim3(8, 48), blk, 0, stream>>>(q2h, k2h, Gq, Gk, Sq, Sk);
  stats_final<<<dim3(4), blk, 0, stream>>>(Gq, Gk, Sq, Sk, stats);

  attn_fused<<<dim3(16, 48), blk, 0, stream>>>(
      q2h, k2h, vth, stats, attn_w, attn_b, out_attn, oh);

  gemm_k<64, 64, 2, 2, 2, 4, EpiProj><<<dim3(12, 64, 1), blk, 0, stream>>>(
      oh, 0, projw_h, 0, 768, 768, 768, EpiProj{proj_b, x, src});

  ln_row<<<dim3(4096), blk, 0, stream>>>(src, ln1_w, ln1_b, h1v, ln1f);

  gemm_k<64, 64, 2, 2, 2, 4, EpiGelu><<<dim3(48, 64, 1), blk, 0, stream>>>(
      h1v, 0, fc1w_h, 0, 768, 768, 768, EpiGelu{fc1_b, gact});

  gemm_k<64, 64, 2, 2, 2, 4, EpiOut><<<dim3(12, 64, 1), blk, 0, stream>>>(
      gact, 0, fc2w_h, 0, 3072, 3072, 3072, EpiOut{fc2_b, ln1f, out_src});
}

// Round 9
// 386.446 us; speedup vs baseline: 1.8408x; 1.0040x over previous
//
#include <hip/hip_runtime.h>

typedef __bf16 bf16;
typedef __bf16 bf16x4 __attribute__((ext_vector_type(4)));
typedef __bf16 bf16x8 __attribute__((ext_vector_type(8)));
typedef float f32x4 __attribute__((ext_vector_type(4)));

#define DEVI __device__ __forceinline__

typedef const __attribute__((address_space(1))) void* gas1;
typedef __attribute__((address_space(3))) void* las3;

// ---------------------------------------------------------------------------
// Stage a [rows x 64] bf16 tile (row bytes = 128) into LDS via global_load_lds,
// with st-style XOR swizzle: LDS[addr(row,c)] where addr applies c^((row&7)<<4).
// Linear LDS dest + pre-swizzled global source; every ds_read applies same XOR.
// ---------------------------------------------------------------------------
DEVI void stage_tile(const bf16* g, int ld, char* lds, int bytes, int tid)
{
  const int wv = tid >> 6, lane = tid & 63;
  const char* gb = (const char*)g;
  const long rowb = (long)ld * 2;
  for (int off = wv * 1024; off < bytes; off += 4096) {
    const int o  = off + lane * 16;                 // linear LDS dest
    const int s  = o ^ (((o >> 7) & 7) << 4);       // pre-swizzled source pos
    const int r  = s >> 7;                          // 128B per tile row
    const int cb = s & 127;
    __builtin_amdgcn_global_load_lds((gas1)(gb + (long)r * rowb + cb),
                                     (las3)(lds + off), 16, 0, 0);
  }
}

template<int N> DEVI void waitvm()
{
  if constexpr (N == 8)      asm volatile("s_waitcnt vmcnt(8)" ::: "memory");
  else if constexpr (N == 6) asm volatile("s_waitcnt vmcnt(6)" ::: "memory");
  else if constexpr (N == 4) asm volatile("s_waitcnt vmcnt(4)" ::: "memory");
  else if constexpr (N == 2) asm volatile("s_waitcnt vmcnt(2)" ::: "memory");
  else                       asm volatile("s_waitcnt vmcnt(0)" ::: "memory");
}

// Wave-local LDS fence: orders ds_write -> ds_read across lanes of ONE wave.
// lgkmcnt(0) drains the DS queue; sched_barrier(0) pins the compiler (rule #18).
DEVI void wave_lds_fence()
{
  asm volatile("s_waitcnt lgkmcnt(0)" ::: "memory");
  __builtin_amdgcn_sched_barrier(0);
}

// ---------------------------------------------------------------------------
// Epilogue functors
// ---------------------------------------------------------------------------
struct EpiQKV {
  const float* bias; bf16* C;
  DEVI void operator()(int z, int row, int col, float v) const {
    C[(long)row * 2304 + col] = (bf16)(v + bias[col]);
  }
};

struct EpiProj {
  const float* bias; const float* x; float* src;
  DEVI void operator()(int z, int row, int col, float v) const {
    const long i = (long)row * 768 + col;
    src[i] = v + bias[col] + x[i];
  }
};

struct EpiGelu {
  const float* bias; bf16* g;
  DEVI void operator()(int z, int row, int col, float v) const {
    const float t = v + bias[col];
    const float r = 0.5f * t * (1.0f + erff(t * 0.70710678118654752f));
    g[(long)row * 3072 + col] = (bf16)r;
  }
};

struct EpiOut {
  const float* bias; const float* lnf; float* outp;
  DEVI void operator()(int z, int row, int col, float v) const {
    const long i = (long)row * 768 + col;
    outp[i] = v + bias[col] + lnf[i];   // final residual uses POST-LN1 src
  }
};

// ---------------------------------------------------------------------------
// bf16 GEMM, 2-phase double-buffered, counted vmcnt (T3/T4 minimum form).
// 128x64 tiles, 4 waves (2x2), FM=4 FN=2: 16 MFMA : 12 ds_read per wave-step.
// LDS 48KB -> 3 blocks/CU.
// ---------------------------------------------------------------------------
template<int BM, int BN, int WC, int FM, int FN, int WPE, class Epi>
__global__ __launch_bounds__(256, WPE) void gemm_k(
    const bf16* __restrict__ A, long abatch,
    const bf16* __restrict__ B, long bbatch,
    int lda, int ldb, int K, Epi epi)
{
  constexpr int BK = 64;
  constexpr int AB = BM * BK * 2, BB = BN * BK * 2;
  constexpr int BUFB = AB + BB;
  constexpr int LPS = BUFB / 4096;          // global_load_lds per wave per stage
  __shared__ char smem[2 * BUFB];

  const int tid = threadIdx.x, lane = tid & 63, wv = tid >> 6;
  const int wr = wv / WC, wc = wv % WC;
  const int mt = blockIdx.y, nt = blockIdx.x, z = blockIdx.z;
  const long abase = (long)z * abatch + (long)mt * BM * lda;
  const long bbase = (long)z * bbatch + (long)nt * BN * ldb;
  const int l15 = lane & 15;
  const int sw = (lane & 7) << 4;           // per-lane read swizzle

  auto stage_all = [&](int buf, int kt) {
    char* base = smem + buf * BUFB;
    stage_tile(A + abase + kt, lda, base, AB, tid);
    stage_tile(B + bbase + kt, ldb, base + AB, BB, tid);
  };

  f32x4 acc[FM][FN];
#pragma unroll
  for (int m = 0; m < FM; ++m)
#pragma unroll
    for (int n = 0; n < FN; ++n) acc[m][n] = f32x4{0.f, 0.f, 0.f, 0.f};

  const int arow = wr * FM * 16, bcol = wc * FN * 16;
  const int T = K / BK;

  stage_all(0, 0);
  int cur = 0;
  for (int t = 0; t < T; ++t) {
    if (t + 1 < T) { stage_all(cur ^ 1, (t + 1) * BK); waitvm<LPS>(); }
    else           { waitvm<0>(); }
    __builtin_amdgcn_s_barrier();
    asm volatile("" ::: "memory");

    const char* As = smem + cur * BUFB;
    const char* Bs = As + AB;
#pragma unroll
    for (int ks = 0; ks < 2; ++ks) {
      const int ko = (ks * 64 + (lane >> 4) * 16) ^ sw;
      bf16x8 av[FM], bv[FN];
#pragma unroll
      for (int m = 0; m < FM; ++m)
        av[m] = *(const bf16x8*)(As + (arow + m * 16 + l15) * 128 + ko);
#pragma unroll
      for (int n = 0; n < FN; ++n)
        bv[n] = *(const bf16x8*)(Bs + (bcol + n * 16 + l15) * 128 + ko);
#pragma unroll
      for (int m = 0; m < FM; ++m)
#pragma unroll
        for (int n = 0; n < FN; ++n)
          acc[m][n] = __builtin_amdgcn_mfma_f32_16x16x32_bf16(av[m], bv[n], acc[m][n], 0, 0, 0);
    }
    asm volatile("s_waitcnt lgkmcnt(0)" ::: "memory");   // LDS reads done
    __builtin_amdgcn_s_barrier();                         // before buf reuse
    asm volatile("" ::: "memory");
    cur ^= 1;
  }

#pragma unroll
  for (int m = 0; m < FM; ++m)
#pragma unroll
    for (int n = 0; n < FN; ++n)
#pragma unroll
      for (int r = 0; r < 4; ++r) {
        const int grow = mt * BM + arow + m * 16 + (lane >> 4) * 4 + r;
        const int gcol = nt * BN + bcol + n * 16 + l15;
        epi(z, grow, gcol, acc[m][n][r]);
      }
}

// ---------------------------------------------------------------------------
// Fused attention tail — wave-owns-rows; wave-private P scratch.
// Cross-lane RAW hand-offs (QK^T->LN, LN->PV) are within ONE wave, so a
// wave-local lgkmcnt(0)+sched_barrier(0) fence suffices (no block barrier).
// ONE __syncthreads per iter protects the cross-wave K/V double buffer.
// setprio(1) wraps MFMA clusters (T5: waves are desynced now).
// LDS 48KB -> 3 blocks/CU; grid 768 = 3*256 exact.
// ---------------------------------------------------------------------------
__global__ __launch_bounds__(256, 3) void attn_fused(
    const bf16* __restrict__ q2h, const bf16* __restrict__ k2h,
    const bf16* __restrict__ vth, const float* __restrict__ stats,
    const float* __restrict__ wn, const float* __restrict__ bn,
    float* __restrict__ attn_out, bf16* __restrict__ oh)
{
  __shared__ char smem[49152];
  char* Qs  = smem;                    //  8KB  64x64 bf16 (swizzled)
  char* Ks0 = smem + 8192;
  char* Ks1 = smem + 16384;
  char* Vs0 = smem + 24576;
  char* Vs1 = smem + 32768;
  char* Pall = smem + 40960;           //  8KB: 4 waves x [16][64] bf16 (swz)

  const int tid = threadIdx.x, lane = tid & 63, wv = tid >> 6;
  const int mt = blockIdx.x, z = blockIdx.y;
  const int h = z >> 2, b = z & 3;
  const int zq = b * 12 + h;
  const float mu = stats[2 * b], rs = stats[2 * b + 1];
  const int l15 = lane & 15, lhi = lane >> 4;
  const int sw = (lane & 7) << 4;
  char* Ps = Pall + wv * 2048;         // wave-private [16 rows][128B]

  const long zoff = (long)zq * 65536;
  stage_tile(q2h + zoff + (long)mt * 4096, 64, Qs, 8192, tid);
  stage_tile(k2h + zoff, 64, Ks0, 8192, tid);
  stage_tile(vth + zoff, 1024, Vs0, 8192, tid);
  __syncthreads();

  f32x4 oacc[4];
#pragma unroll
  for (int n = 0; n < 4; ++n) oacc[n] = f32x4{0.f, 0.f, 0.f, 0.f};

  for (int nt = 0; nt < 16; ++nt) {
    const int cur = nt & 1;
    char* Kc = cur ? Ks1 : Ks0;
    char* Vc = cur ? Vs1 : Vs0;
    char* Kn = cur ? Ks0 : Ks1;
    char* Vn = cur ? Vs0 : Vs1;

    if (nt + 1 < 16) {
      stage_tile(k2h + zoff + (long)(nt + 1) * 4096, 64, Kn, 8192, tid);
      stage_tile(vth + zoff + (nt + 1) * 64, 1024, Vn, 8192, tid);
    }
    // wn/bn for this tile: wave rows wv*16..+16, cols nt*64..+64, coalesced.
    f32x4 wreg[4], breg[4];
#pragma unroll
    for (int rr = 0; rr < 4; ++rr) {
      const long grow = (long)mt * 64 + wv * 16 + rr * 4 + lhi;
      const long gcol = (long)nt * 64 + l15 * 4;
      wreg[rr] = *(const f32x4*)&wn[((long)h * 1024 + grow) * 1024 + gcol];
      breg[rr] = *(const f32x4*)&bn[((long)h * 1024 + grow) * 1024 + gcol];
    }

    // ---- QK^T: wave computes its 16 rows x all 64 cols ----
    f32x4 acc[4];
#pragma unroll
    for (int n = 0; n < 4; ++n) acc[n] = f32x4{0.f, 0.f, 0.f, 0.f};
    __builtin_amdgcn_s_setprio(1);
#pragma unroll
    for (int ks = 0; ks < 2; ++ks) {
      const int ko = (ks * 64 + lhi * 16) ^ sw;
      const bf16x8 av = *(const bf16x8*)(Qs + (wv * 16 + l15) * 128 + ko);
#pragma unroll
      for (int n = 0; n < 4; ++n) {
        const bf16x8 bv = *(const bf16x8*)(Kc + (n * 16 + l15) * 128 + ko);
        acc[n] = __builtin_amdgcn_mfma_f32_16x16x32_bf16(av, bv, acc[n], 0, 0, 0);
      }
    }
    __builtin_amdgcn_s_setprio(0);
    // s_ln = (s-mu)*rs -> bf16, into wave-private Ps (swizzled).
#pragma unroll
    for (int n = 0; n < 4; ++n)
#pragma unroll
      for (int r = 0; r < 4; ++r) {
        const int row = lhi * 4 + r;                 // local row 0..15
        const int cb = (n * 32 + l15 * 2) ^ ((row & 7) << 4);
        *(bf16*)(Ps + row * 128 + cb) = (bf16)((acc[n][r] - mu) * rs);
      }
    wave_lds_fence();  // cross-lane RAW within wave: QK^T writes -> LN reads

    // ---- LN: r = s_ln*w + b -> attn_out f32 + Ps in-place ----
#pragma unroll
    for (int rr = 0; rr < 4; ++rr) {
      const int row = rr * 4 + lhi;                  // local row 0..15
      const int cb = (l15 * 8) ^ ((row & 7) << 4);
      const bf16x4 s4 = *(const bf16x4*)(Ps + row * 128 + cb);
      const long grow = (long)mt * 64 + wv * 16 + row;
      const long gcol = (long)nt * 64 + l15 * 4;
      f32x4 r4;
      bf16x4 h4;
#pragma unroll
      for (int e = 0; e < 4; ++e) {
        const float r = (float)s4[e] * wreg[rr][e] + breg[rr][e];
        r4[e] = r;
        h4[e] = (bf16)r;
      }
      *(f32x4*)&attn_out[((long)zq * 1024 + grow) * 1024 + gcol] = r4;
      *(bf16x4*)(Ps + row * 128 + cb) = h4;
    }
    wave_lds_fence();  // cross-lane RAW within wave: LN write-back -> PV reads

    // ---- PV: o[row, d] += sum_j P[row,j] vT[d,j] ----
    __builtin_amdgcn_s_setprio(1);
#pragma unroll
    for (int ks = 0; ks < 2; ++ks) {
      const int ko = (ks * 64 + lhi * 16) ^ sw;
      const bf16x8 av = *(const bf16x8*)(Ps + l15 * 128 + ko);
#pragma unroll
      for (int n = 0; n < 4; ++n) {
        const bf16x8 bv = *(const bf16x8*)(Vc + (n * 16 + l15) * 128 + ko);
        oacc[n] = __builtin_amdgcn_mfma_f32_16x16x32_bf16(av, bv, oacc[n], 0, 0, 0);
      }
    }
    __builtin_amdgcn_s_setprio(0);
    __syncthreads();   // cross-wave: drains DMA + protects K/V dbuf + Ps WAR
  }

  // ---- epilogue: o -> (B,N,C) bf16 ----
#pragma unroll
  for (int n = 0; n < 4; ++n)
#pragma unroll
    for (int r = 0; r < 4; ++r) {
      const int row = mt * 64 + wv * 16 + lhi * 4 + r;
      const int col = n * 16 + l15;
      oh[((long)(b * 1024 + row)) * 768 + h * 64 + col] = (bf16)oacc[n][r];
    }
}

// ---------------------------------------------------------------------------
// Elementwise helpers
// ---------------------------------------------------------------------------
__global__ void cast_bf16(const float* __restrict__ s, bf16* __restrict__ d, int n4)
{
  const int i = blockIdx.x * 256 + threadIdx.x;   // n4 = n/4
  if (i < n4) {
    const f32x4 v = *(const f32x4*)&s[i * 4];
    bf16x4 o;
#pragma unroll
    for (int j = 0; j < 4; ++j) o[j] = (bf16)v[j];
    *(bf16x4*)&d[i * 4] = o;
  }
}

// LayerNorm over rows of 768; writes bf16 (+ optional f32).
__global__ __launch_bounds__(256) void ln_row(
    const float* __restrict__ in, const float* __restrict__ w,
    const float* __restrict__ b, bf16* __restrict__ outh,
    float* __restrict__ outf)
{
  __shared__ float red[256];
  const int row = blockIdx.x, tid = threadIdx.x;
  const float* p = in + (long)row * 768;
  const float v0 = p[tid], v1 = p[tid + 256], v2 = p[tid + 512];
  red[tid] = v0 + v1 + v2;
  __syncthreads();
  for (int st = 128; st > 0; st >>= 1) { if (tid < st) red[tid] += red[tid + st]; __syncthreads(); }
  const float mu = red[0] * (1.0f / 768.0f);
  __syncthreads();
  const float d0 = v0 - mu, d1 = v1 - mu, d2 = v2 - mu;
  red[tid] = d0 * d0 + d1 * d1 + d2 * d2;
  __syncthreads();
  for (int st = 128; st > 0; st >>= 1) { if (tid < st) red[tid] += red[tid + st]; __syncthreads(); }
  const float rs = rsqrtf(red[0] * (1.0f / 768.0f) + 1e-5f);
  const float dv[3] = {d0, d1, d2};
#pragma unroll
  for (int k = 0; k < 3; ++k) {
    const int c = tid + k * 256;
    const float h = dv[k] * rs * w[c] + b[c];
    outh[(long)row * 768 + c] = (bf16)h;
    if (outf) outf[(long)row * 768 + c] = h;
  }
}

// Per (b,n): normalize q,k head-vectors -> (q/||q||)^2 bf16; v passthrough.
// 8-lane subgroup per head vector; bf16x8 vector loads/stores (G13).
__global__ __launch_bounds__(256) void qkv_post(
    const bf16* __restrict__ qkv, bf16* __restrict__ q2h,
    bf16* __restrict__ k2h, bf16* __restrict__ vb)
{
  const int row = blockIdx.x;           // b*1024+n
  const int b = row >> 10, n = row & 1023;
  const int sg = threadIdx.x >> 3, l8 = threadIdx.x & 7;
  for (int t = sg; t < 36; t += 32) {
    const int s = t / 12, h = t - s * 12;
    const bf16x8 v8 = *(const bf16x8*)&qkv[(long)row * 2304 + s * 768 + h * 64 + l8 * 8];
    const long addr = (((long)(b * 12 + h)) * 1024 + n) * 64 + l8 * 8;
    if (s == 2) {
      *(bf16x8*)&vb[addr] = v8;
    } else {
      float f[8];
      float sq = 0.f;
#pragma unroll
      for (int e = 0; e < 8; ++e) { f[e] = (float)v8[e]; sq += f[e] * f[e]; }
      float tot = sq;
      tot += __shfl_xor(tot, 1);
      tot += __shfl_xor(tot, 2);
      tot += __shfl_xor(tot, 4);
      const float inv = 1.0f / tot;
      bf16x8 o;
#pragma unroll
      for (int e = 0; e < 8; ++e) o[e] = (bf16)(f[e] * f[e] * inv);
      if (s == 0) *(bf16x8*)&q2h[addr] = o;
      else        *(bf16x8*)&k2h[addr] = o;
    }
  }
}

// v (B,H,N,D) bf16 -> vT (B,H,D,N) bf16, 64x64 tiles, vectorized both sides.
__global__ __launch_bounds__(256) void transpose_v(
    const bf16* __restrict__ vb, bf16* __restrict__ vth)
{
  __shared__ float t[64][65];
  const int z = blockIdx.y, n0 = blockIdx.x * 64, tid = threadIdx.x;
  const bf16* srcp = vb + ((long)z * 1024 + n0) * 64;
  for (int e = tid * 8; e < 4096; e += 2048) {
    const bf16x8 v8 = *(const bf16x8*)&srcp[e];
    const int r = e >> 6, c = e & 63;
#pragma unroll
    for (int j = 0; j < 8; ++j) t[r][c + j] = (float)v8[j];
  }
  __syncthreads();
  for (int e = tid; e < 512; e += 256) {
    const int d = e >> 3, c0 = (e & 7) * 8;
    bf16x8 o;
#pragma unroll
    for (int j = 0; j < 8; ++j) o[j] = (bf16)t[c0 + j][d];
    *(bf16x8*)&vth[((long)z * 64 + d) * 1024 + n0 + c0] = o;
  }
}

// Gram partials: Gq += q2^T q2 (64x64), Gk likewise; Sq/Sk column sums.
__global__ __launch_bounds__(256) void stats_accum(
    const bf16* __restrict__ q2h, const bf16* __restrict__ k2h,
    float* __restrict__ Gq, float* __restrict__ Gk,
    float* __restrict__ Sq, float* __restrict__ Sk)
{
  __shared__ float rowbuf[8][128];     // 8 rows x (64 q | 64 k)
  const int tid = threadIdx.x;
  const int z = blockIdx.y;
  const long base = ((long)z * 1024 + (long)blockIdx.x * 128) * 64;
  const int tx = tid & 15, ty = tid >> 4;
  float gq[4][4] = {}, gk[4][4] = {};
  float sq = 0.f, sk = 0.f;
  for (int r0 = 0; r0 < 128; r0 += 8) {
    __syncthreads();
    {
      const int idx = tid * 4;         // 0..1023 over 8x128, bf16x4 loads
      const int rr = idx >> 7, cc = idx & 127;
      const long a = base + (long)(r0 + rr) * 64 + (cc & 63);
      const bf16x4 v4 = (cc < 64) ? *(const bf16x4*)&q2h[a]
                                  : *(const bf16x4*)&k2h[a];
#pragma unroll
      for (int j = 0; j < 4; ++j) rowbuf[rr][cc + j] = (float)v4[j];
    }
    __syncthreads();
#pragma unroll
    for (int r = 0; r < 8; ++r) {
      float qa[4], qe[4], ka[4], ke[4];
#pragma unroll
      for (int i = 0; i < 4; ++i) {
        qa[i] = rowbuf[r][ty * 4 + i]; qe[i] = rowbuf[r][tx * 4 + i];
        ka[i] = rowbuf[r][64 + ty * 4 + i]; ke[i] = rowbuf[r][64 + tx * 4 + i];
      }
#pragma unroll
      for (int i = 0; i < 4; ++i)
#pragma unroll
        for (int j = 0; j < 4; ++j) {
          gq[i][j] += qa[i] * qe[j];
          gk[i][j] += ka[i] * ke[j];
        }
    }
    if (tid < 128) {
      float s = 0.f;
#pragma unroll
      for (int r = 0; r < 8; ++r) s += rowbuf[r][tid];
      if (tid < 64) sq += s; else sk += s;
    }
  }
#pragma unroll
  for (int i = 0; i < 4; ++i)
#pragma unroll
    for (int j = 0; j < 4; ++j) {
      atomicAdd(&Gq[(long)z * 4096 + (ty * 4 + i) * 64 + tx * 4 + j], gq[i][j]);
      atomicAdd(&Gk[(long)z * 4096 + (ty * 4 + i) * 64 + tx * 4 + j], gk[i][j]);
    }
  if (tid < 64) atomicAdd(&Sq[z * 64 + tid], sq);
  else if (tid < 128) atomicAdd(&Sk[z * 64 + tid - 64], sk);
}

// Per-batch mean / rstd of the attn tensor from Gram partials.
__global__ __launch_bounds__(256) void stats_final(
    const float* __restrict__ Gq, const float* __restrict__ Gk,
    const float* __restrict__ Sq, const float* __restrict__ Sk,
    float* __restrict__ stats)
{
  __shared__ double red[256];
  const int b = blockIdx.x, tid = threadIdx.x;
  double s2 = 0.0, s1 = 0.0;
  for (int h = 0; h < 12; ++h) {
    const float* gq = Gq + ((long)(b * 12 + h)) * 4096;
    const float* gk = Gk + ((long)(b * 12 + h)) * 4096;
    for (int i = tid; i < 4096; i += 256) s2 += (double)gq[i] * (double)gk[i];
    const float* sqp = Sq + (b * 12 + h) * 64;
    const float* skp = Sk + (b * 12 + h) * 64;
    for (int i = tid; i < 64; i += 256) s1 += (double)sqp[i] * (double)skp[i];
  }
  red[tid] = s2; __syncthreads();
  for (int st = 128; st > 0; st >>= 1) { if (tid < st) red[tid] += red[tid + st]; __syncthreads(); }
  const double S2 = red[0]; __syncthreads();
  red[tid] = s1; __syncthreads();
  for (int st = 128; st > 0; st >>= 1) { if (tid < st) red[tid] += red[tid + st]; __syncthreads(); }
  if (tid == 0) {
    const double S1 = red[0];
    const double cnt = 12.0 * 1024.0 * 1024.0;
    const double mean = S1 / cnt;
    const double var = S2 / cnt - mean * mean;
    stats[2 * b] = (float)mean;
    stats[2 * b + 1] = (float)(1.0 / sqrt(var + 1e-5));
  }
}

// ---------------------------------------------------------------------------
extern "C" void kernel_launch(void* const* d_in, const int* in_sizes, int n_in,
                              void* d_out, int out_size, void* d_ws, size_t ws_size,
                              hipStream_t stream)
{
  const float* x      = (const float*)d_in[0];
  const float* ln0_w  = (const float*)d_in[1];
  const float* ln0_b  = (const float*)d_in[2];
  const float* qkv_w  = (const float*)d_in[3];
  const float* qkv_b  = (const float*)d_in[4];
  const float* proj_w = (const float*)d_in[5];
  const float* proj_b = (const float*)d_in[6];
  const float* attn_w = (const float*)d_in[7];
  const float* attn_b = (const float*)d_in[8];
  const float* ln1_w  = (const float*)d_in[9];
  const float* ln1_b  = (const float*)d_in[10];
  const float* fc1_w  = (const float*)d_in[11];
  const float* fc1_b  = (const float*)d_in[12];
  const float* fc2_w  = (const float*)d_in[13];
  const float* fc2_b  = (const float*)d_in[14];

  float* out_src  = (float*)d_out;
  float* out_attn = out_src + 4L * 1024 * 768;       // 3145728

  char* p = (char*)d_ws;
  auto take = [&](long bytes) -> char* {
    char* r = p;
    p += (bytes + 255) & ~255L;
    return r;
  };
  bf16* qkvw_h = (bf16*)take(3538944);
  bf16* projw_h = (bf16*)take(1179648);
  bf16* fc1w_h = (bf16*)take(4718592);
  bf16* fc2w_h = (bf16*)take(4718592);
  char* regB = take(12582912);                 // hh, later src_f32
  bf16* hh = (bf16*)regB;
  float* src = (float*)regB;
  char* regC = take(37748736);                 // qkv bf16, later gelu acts + ln1f
  bf16* qkvb = (bf16*)regC;                    // [0, 18874368) bf16 4096x2304
  bf16* gact = (bf16*)regC;                    // [0, 25165824) bf16 4096x3072
  float* ln1f = (float*)(regC + 25165824);     // [25165824, 37748736) f32
  bf16* q2h = (bf16*)take(6291456);
  bf16* k2h = (bf16*)take(6291456);
  bf16* vb  = (bf16*)take(6291456);
  bf16* vth = (bf16*)take(6291456);
  bf16* oh  = (bf16*)take(6291456);
  bf16* h1v = (bf16*)take(6291456);
  float* Gq = (float*)take(786432);
  float* Gk = (float*)take(786432);
  float* Sq = (float*)take(12288);
  float* Sk = (float*)take(12288);
  float* stats = (float*)take(256);

  const dim3 blk(256);

  (void)hipMemsetAsync((void*)Gq, 0, 786432 * 2 + 12288 * 2 + 256, stream);

  cast_bf16<<<dim3(1769472 / 4 / 256), blk, 0, stream>>>(qkv_w, qkvw_h, 442368);
  cast_bf16<<<dim3(589824 / 4 / 256), blk, 0, stream>>>(proj_w, projw_h, 147456);
  cast_bf16<<<dim3(2359296 / 4 / 256), blk, 0, stream>>>(fc1_w, fc1w_h, 589824);
  cast_bf16<<<dim3(2359296 / 4 / 256), blk, 0, stream>>>(fc2_w, fc2w_h, 589824);

  ln_row<<<dim3(4096), blk, 0, stream>>>(x, ln0_w, ln0_b, hh, nullptr);

  gemm_k<128, 64, 2, 4, 2, 3, EpiQKV><<<dim3(36, 32, 1), blk, 0, stream>>>(
      hh, 0, qkvw_h, 0, 768, 768, 768, EpiQKV{qkv_b, qkvb});

  qkv_post<<<dim3(4096), blk, 0, stream>>>(qkvb, q2h, k2h, vb);
  transpose_v<<<dim3(16, 48), blk, 0, stream>>>(vb, vth);
  stats_accum<<<dim3(8, 48), blk, 0, stream>>>(q2h, k2h, Gq, Gk, Sq, Sk);
  stats_final<<<dim3(4), blk, 0, stream>>>(Gq, Gk, Sq, Sk, stats);

  attn_fused<<<dim3(16, 48), blk, 0, stream>>>(
      q2h, k2h, vth, stats, attn_w, attn_b, out_attn, oh);

  gemm_k<128, 64, 2, 4, 2, 3, EpiProj><<<dim3(12, 32, 1), blk, 0, stream>>>(
      oh, 0, projw_h, 0, 768, 768, 768, EpiProj{proj_b, x, src});

  ln_row<<<dim3(4096), blk, 0, stream>>>(src, ln1_w, ln1_b, h1v, ln1f);

  gemm_k<128, 64, 2, 4, 2, 3, EpiGelu><<<dim3(48, 32, 1), blk, 0, stream>>>(
      h1v, 0, fc1w_h, 0, 768, 768, 768, EpiGelu{fc1_b, gact});

  gemm_k<128, 64, 2, 4, 2, 3, EpiOut><<<dim3(12, 32, 1), blk, 0, stream>>>(
      gact, 0, fc2w_h, 0, 3072, 3072, 3072, EpiOut{fc2_b, ln1f, out_src});
}

// Round 10
// 384.287 us; speedup vs baseline: 1.8511x; 1.0056x over previous
//
#include <hip/hip_runtime.h>

typedef __bf16 bf16;
typedef __bf16 bf16x4 __attribute__((ext_vector_type(4)));
typedef __bf16 bf16x8 __attribute__((ext_vector_type(8)));
typedef float f32x4 __attribute__((ext_vector_type(4)));

#define DEVI __device__ __forceinline__

typedef const __attribute__((address_space(1))) void* gas1;
typedef __attribute__((address_space(3))) void* las3;

// ---------------------------------------------------------------------------
// XCD-chunked bijective block remap (T1, m204 form). HW round-robins
// consecutive block ids across the 8 XCDs; this map hands each XCD a
// CONTIGUOUS chunk of work ids so panel reuse stays in that XCD's L2.
// Wrong-XCD assumption costs locality only, never correctness.
// ---------------------------------------------------------------------------
DEVI int xcd_chunk(int bid, int nwg)
{
  const int q = nwg >> 3, r = nwg & 7;
  const int xcd = bid & 7, rank = bid >> 3;
  return (xcd < r) ? xcd * (q + 1) + rank
                   : r * (q + 1) + (xcd - r) * q + rank;
}

// ---------------------------------------------------------------------------
// Stage a [rows x 64] bf16 tile (row bytes = 128) into LDS via global_load_lds,
// with st-style XOR swizzle: LDS[addr(row,c)] where addr applies c^((row&7)<<4).
// Linear LDS dest + pre-swizzled global source; every ds_read applies same XOR.
// ---------------------------------------------------------------------------
DEVI void stage_tile(const bf16* g, int ld, char* lds, int bytes, int tid)
{
  const int wv = tid >> 6, lane = tid & 63;
  const char* gb = (const char*)g;
  const long rowb = (long)ld * 2;
  for (int off = wv * 1024; off < bytes; off += 4096) {
    const int o  = off + lane * 16;                 // linear LDS dest
    const int s  = o ^ (((o >> 7) & 7) << 4);       // pre-swizzled source pos
    const int r  = s >> 7;                          // 128B per tile row
    const int cb = s & 127;
    __builtin_amdgcn_global_load_lds((gas1)(gb + (long)r * rowb + cb),
                                     (las3)(lds + off), 16, 0, 0);
  }
}

template<int N> DEVI void waitvm()
{
  if constexpr (N == 8)      asm volatile("s_waitcnt vmcnt(8)" ::: "memory");
  else if constexpr (N == 6) asm volatile("s_waitcnt vmcnt(6)" ::: "memory");
  else if constexpr (N == 4) asm volatile("s_waitcnt vmcnt(4)" ::: "memory");
  else if constexpr (N == 2) asm volatile("s_waitcnt vmcnt(2)" ::: "memory");
  else                       asm volatile("s_waitcnt vmcnt(0)" ::: "memory");
}

// Wave-local LDS fence: orders ds_write -> ds_read across lanes of ONE wave.
DEVI void wave_lds_fence()
{
  asm volatile("s_waitcnt lgkmcnt(0)" ::: "memory");
  __builtin_amdgcn_sched_barrier(0);
}

// ---------------------------------------------------------------------------
// Epilogue functors
// ---------------------------------------------------------------------------
struct EpiQKV {
  const float* bias; bf16* C;
  DEVI void operator()(int z, int row, int col, float v) const {
    C[(long)row * 2304 + col] = (bf16)(v + bias[col]);
  }
};

struct EpiProj {
  const float* bias; const float* x; float* src;
  DEVI void operator()(int z, int row, int col, float v) const {
    const long i = (long)row * 768 + col;
    src[i] = v + bias[col] + x[i];
  }
};

struct EpiGelu {
  const float* bias; bf16* g;
  DEVI void operator()(int z, int row, int col, float v) const {
    const float t = v + bias[col];
    const float r = 0.5f * t * (1.0f + erff(t * 0.70710678118654752f));
    g[(long)row * 3072 + col] = (bf16)r;
  }
};

struct EpiOut {
  const float* bias; const float* lnf; float* outp;
  DEVI void operator()(int z, int row, int col, float v) const {
    const long i = (long)row * 768 + col;
    outp[i] = v + bias[col] + lnf[i];   // final residual uses POST-LN1 src
  }
};

// ---------------------------------------------------------------------------
// bf16 GEMM, 2-phase double-buffered, counted vmcnt; XCD-chunked (mt,nt)
// decode so each XCD walks nt fastest within a contiguous chunk -> A-panel
// L2-resident per XCD, B row-working-set <= ~3.5MB ~ L2.
// 128x64 tiles, 4 waves (2x2), FM=4 FN=2. LDS 48KB -> 3 blocks/CU.
// ---------------------------------------------------------------------------
template<int BM, int BN, int WC, int FM, int FN, int WPE, class Epi>
__global__ __launch_bounds__(256, WPE) void gemm_k(
    const bf16* __restrict__ A, long abatch,
    const bf16* __restrict__ B, long bbatch,
    int lda, int ldb, int K, Epi epi)
{
  constexpr int BK = 64;
  constexpr int AB = BM * BK * 2, BB = BN * BK * 2;
  constexpr int BUFB = AB + BB;
  constexpr int LPS = BUFB / 4096;          // global_load_lds per wave per stage
  __shared__ char smem[2 * BUFB];

  const int tid = threadIdx.x, lane = tid & 63, wv = tid >> 6;
  const int wr = wv / WC, wc = wv % WC;
  const int NT = gridDim.x;
  const int nwg = NT * gridDim.y;
  const int wid = xcd_chunk(blockIdx.y * NT + blockIdx.x, nwg);
  const int mt = wid / NT, nt = wid % NT;
  const int z = blockIdx.z;
  const long abase = (long)z * abatch + (long)mt * BM * lda;
  const long bbase = (long)z * bbatch + (long)nt * BN * ldb;
  const int l15 = lane & 15;
  const int sw = (lane & 7) << 4;           // per-lane read swizzle

  auto stage_all = [&](int buf, int kt) {
    char* base = smem + buf * BUFB;
    stage_tile(A + abase + kt, lda, base, AB, tid);
    stage_tile(B + bbase + kt, ldb, base + AB, BB, tid);
  };

  f32x4 acc[FM][FN];
#pragma unroll
  for (int m = 0; m < FM; ++m)
#pragma unroll
    for (int n = 0; n < FN; ++n) acc[m][n] = f32x4{0.f, 0.f, 0.f, 0.f};

  const int arow = wr * FM * 16, bcol = wc * FN * 16;
  const int T = K / BK;

  stage_all(0, 0);
  int cur = 0;
  for (int t = 0; t < T; ++t) {
    if (t + 1 < T) { stage_all(cur ^ 1, (t + 1) * BK); waitvm<LPS>(); }
    else           { waitvm<0>(); }
    __builtin_amdgcn_s_barrier();
    asm volatile("" ::: "memory");

    const char* As = smem + cur * BUFB;
    const char* Bs = As + AB;
#pragma unroll
    for (int ks = 0; ks < 2; ++ks) {
      const int ko = (ks * 64 + (lane >> 4) * 16) ^ sw;
      bf16x8 av[FM], bv[FN];
#pragma unroll
      for (int m = 0; m < FM; ++m)
        av[m] = *(const bf16x8*)(As + (arow + m * 16 + l15) * 128 + ko);
#pragma unroll
      for (int n = 0; n < FN; ++n)
        bv[n] = *(const bf16x8*)(Bs + (bcol + n * 16 + l15) * 128 + ko);
#pragma unroll
      for (int m = 0; m < FM; ++m)
#pragma unroll
        for (int n = 0; n < FN; ++n)
          acc[m][n] = __builtin_amdgcn_mfma_f32_16x16x32_bf16(av[m], bv[n], acc[m][n], 0, 0, 0);
    }
    asm volatile("s_waitcnt lgkmcnt(0)" ::: "memory");   // LDS reads done
    __builtin_amdgcn_s_barrier();                         // before buf reuse
    asm volatile("" ::: "memory");
    cur ^= 1;
  }

#pragma unroll
  for (int m = 0; m < FM; ++m)
#pragma unroll
    for (int n = 0; n < FN; ++n)
#pragma unroll
      for (int r = 0; r < 4; ++r) {
        const int grow = mt * BM + arow + m * 16 + (lane >> 4) * 4 + r;
        const int gcol = nt * BN + bcol + n * 16 + l15;
        epi(z, grow, gcol, acc[m][n][r]);
      }
}

// ---------------------------------------------------------------------------
// Fused attention tail — wave-owns-rows; wave-private P scratch.
// 1D grid 768; XCD-chunked decode with b FASTEST: the 4 batches sharing one
// wn/bn strip run back-to-back on the same XCD -> strip is L2-hit 3 of 4x
// (was L3). LDS 48KB -> 3 blocks/CU.
// ---------------------------------------------------------------------------
__global__ __launch_bounds__(256, 3) void attn_fused(
    const bf16* __restrict__ q2h, const bf16* __restrict__ k2h,
    const bf16* __restrict__ vth, const float* __restrict__ stats,
    const float* __restrict__ wn, const float* __restrict__ bn,
    float* __restrict__ attn_out, bf16* __restrict__ oh)
{
  __shared__ char smem[49152];
  char* Qs  = smem;                    //  8KB  64x64 bf16 (swizzled)
  char* Ks0 = smem + 8192;
  char* Ks1 = smem + 16384;
  char* Vs0 = smem + 24576;
  char* Vs1 = smem + 32768;
  char* Pall = smem + 40960;           //  8KB: 4 waves x [16][64] bf16 (swz)

  const int tid = threadIdx.x, lane = tid & 63, wv = tid >> 6;
  const int wid = xcd_chunk(blockIdx.x, 768);
  const int b = wid & 3;               // fastest: wn/bn strip sharing
  const int mt = (wid >> 2) & 15;
  const int h = wid >> 6;
  const int zq = b * 12 + h;
  const float mu = stats[2 * b], rs = stats[2 * b + 1];
  const int l15 = lane & 15, lhi = lane >> 4;
  const int sw = (lane & 7) << 4;
  char* Ps = Pall + wv * 2048;         // wave-private [16 rows][128B]

  const long zoff = (long)zq * 65536;
  stage_tile(q2h + zoff + (long)mt * 4096, 64, Qs, 8192, tid);
  stage_tile(k2h + zoff, 64, Ks0, 8192, tid);
  stage_tile(vth + zoff, 1024, Vs0, 8192, tid);
  __syncthreads();

  f32x4 oacc[4];
#pragma unroll
  for (int n = 0; n < 4; ++n) oacc[n] = f32x4{0.f, 0.f, 0.f, 0.f};

  for (int nt = 0; nt < 16; ++nt) {
    const int cur = nt & 1;
    char* Kc = cur ? Ks1 : Ks0;
    char* Vc = cur ? Vs1 : Vs0;
    char* Kn = cur ? Ks0 : Ks1;
    char* Vn = cur ? Vs0 : Vs1;

    if (nt + 1 < 16) {
      stage_tile(k2h + zoff + (long)(nt + 1) * 4096, 64, Kn, 8192, tid);
      stage_tile(vth + zoff + (nt + 1) * 64, 1024, Vn, 8192, tid);
    }
    // wn/bn for this tile: wave rows wv*16..+16, cols nt*64..+64, coalesced.
    f32x4 wreg[4], breg[4];
#pragma unroll
    for (int rr = 0; rr < 4; ++rr) {
      const long grow = (long)mt * 64 + wv * 16 + rr * 4 + lhi;
      const long gcol = (long)nt * 64 + l15 * 4;
      wreg[rr] = *(const f32x4*)&wn[((long)h * 1024 + grow) * 1024 + gcol];
      breg[rr] = *(const f32x4*)&bn[((long)h * 1024 + grow) * 1024 + gcol];
    }

    // ---- QK^T: wave computes its 16 rows x all 64 cols ----
    f32x4 acc[4];
#pragma unroll
    for (int n = 0; n < 4; ++n) acc[n] = f32x4{0.f, 0.f, 0.f, 0.f};
    __builtin_amdgcn_s_setprio(1);
#pragma unroll
    for (int ks = 0; ks < 2; ++ks) {
      const int ko = (ks * 64 + lhi * 16) ^ sw;
      const bf16x8 av = *(const bf16x8*)(Qs + (wv * 16 + l15) * 128 + ko);
#pragma unroll
      for (int n = 0; n < 4; ++n) {
        const bf16x8 bv = *(const bf16x8*)(Kc + (n * 16 + l15) * 128 + ko);
        acc[n] = __builtin_amdgcn_mfma_f32_16x16x32_bf16(av, bv, acc[n], 0, 0, 0);
      }
    }
    __builtin_amdgcn_s_setprio(0);
    // s_ln = (s-mu)*rs -> bf16, into wave-private Ps (swizzled).
#pragma unroll
    for (int n = 0; n < 4; ++n)
#pragma unroll
      for (int r = 0; r < 4; ++r) {
        const int row = lhi * 4 + r;                 // local row 0..15
        const int cb = (n * 32 + l15 * 2) ^ ((row & 7) << 4);
        *(bf16*)(Ps + row * 128 + cb) = (bf16)((acc[n][r] - mu) * rs);
      }
    wave_lds_fence();  // cross-lane RAW within wave: QK^T writes -> LN reads

    // ---- LN: r = s_ln*w + b -> attn_out f32 + Ps in-place ----
#pragma unroll
    for (int rr = 0; rr < 4; ++rr) {
      const int row = rr * 4 + lhi;                  // local row 0..15
      const int cb = (l15 * 8) ^ ((row & 7) << 4);
      const bf16x4 s4 = *(const bf16x4*)(Ps + row * 128 + cb);
      const long grow = (long)mt * 64 + wv * 16 + row;
      const long gcol = (long)nt * 64 + l15 * 4;
      f32x4 r4;
      bf16x4 h4;
#pragma unroll
      for (int e = 0; e < 4; ++e) {
        const float r = (float)s4[e] * wreg[rr][e] + breg[rr][e];
        r4[e] = r;
        h4[e] = (bf16)r;
      }
      *(f32x4*)&attn_out[((long)zq * 1024 + grow) * 1024 + gcol] = r4;
      *(bf16x4*)(Ps + row * 128 + cb) = h4;
    }
    wave_lds_fence();  // cross-lane RAW within wave: LN write-back -> PV reads

    // ---- PV: o[row, d] += sum_j P[row,j] vT[d,j] ----
    __builtin_amdgcn_s_setprio(1);
#pragma unroll
    for (int ks = 0; ks < 2; ++ks) {
      const int ko = (ks * 64 + lhi * 16) ^ sw;
      const bf16x8 av = *(const bf16x8*)(Ps + l15 * 128 + ko);
#pragma unroll
      for (int n = 0; n < 4; ++n) {
        const bf16x8 bv = *(const bf16x8*)(Vc + (n * 16 + l15) * 128 + ko);
        oacc[n] = __builtin_amdgcn_mfma_f32_16x16x32_bf16(av, bv, oacc[n], 0, 0, 0);
      }
    }
    __builtin_amdgcn_s_setprio(0);
    __syncthreads();   // cross-wave: drains DMA + protects K/V dbuf + Ps WAR
  }

  // ---- epilogue: o -> (B,N,C) bf16 ----
#pragma unroll
  for (int n = 0; n < 4; ++n)
#pragma unroll
    for (int r = 0; r < 4; ++r) {
      const int row = mt * 64 + wv * 16 + lhi * 4 + r;
      const int col = n * 16 + l15;
      oh[((long)(b * 1024 + row)) * 768 + h * 64 + col] = (bf16)oacc[n][r];
    }
}

// ---------------------------------------------------------------------------
// Elementwise helpers
// ---------------------------------------------------------------------------
__global__ void cast_bf16(const float* __restrict__ s, bf16* __restrict__ d, int n4)
{
  const int i = blockIdx.x * 256 + threadIdx.x;   // n4 = n/4
  if (i < n4) {
    const f32x4 v = *(const f32x4*)&s[i * 4];
    bf16x4 o;
#pragma unroll
    for (int j = 0; j < 4; ++j) o[j] = (bf16)v[j];
    *(bf16x4*)&d[i * 4] = o;
  }
}

// LayerNorm over rows of 768; writes bf16 (+ optional f32).
__global__ __launch_bounds__(256) void ln_row(
    const float* __restrict__ in, const float* __restrict__ w,
    const float* __restrict__ b, bf16* __restrict__ outh,
    float* __restrict__ outf)
{
  __shared__ float red[256];
  const int row = blockIdx.x, tid = threadIdx.x;
  const float* p = in + (long)row * 768;
  const float v0 = p[tid], v1 = p[tid + 256], v2 = p[tid + 512];
  red[tid] = v0 + v1 + v2;
  __syncthreads();
  for (int st = 128; st > 0; st >>= 1) { if (tid < st) red[tid] += red[tid + st]; __syncthreads(); }
  const float mu = red[0] * (1.0f / 768.0f);
  __syncthreads();
  const float d0 = v0 - mu, d1 = v1 - mu, d2 = v2 - mu;
  red[tid] = d0 * d0 + d1 * d1 + d2 * d2;
  __syncthreads();
  for (int st = 128; st > 0; st >>= 1) { if (tid < st) red[tid] += red[tid + st]; __syncthreads(); }
  const float rs = rsqrtf(red[0] * (1.0f / 768.0f) + 1e-5f);
  const float dv[3] = {d0, d1, d2};
#pragma unroll
  for (int k = 0; k < 3; ++k) {
    const int c = tid + k * 256;
    const float h = dv[k] * rs * w[c] + b[c];
    outh[(long)row * 768 + c] = (bf16)h;
    if (outf) outf[(long)row * 768 + c] = h;
  }
}

// Per (b,n): normalize q,k head-vectors -> (q/||q||)^2 bf16; v passthrough.
__global__ __launch_bounds__(256) void qkv_post(
    const bf16* __restrict__ qkv, bf16* __restrict__ q2h,
    bf16* __restrict__ k2h, bf16* __restrict__ vb)
{
  const int row = blockIdx.x;           // b*1024+n
  const int b = row >> 10, n = row & 1023;
  const int sg = threadIdx.x >> 3, l8 = threadIdx.x & 7;
  for (int t = sg; t < 36; t += 32) {
    const int s = t / 12, h = t - s * 12;
    const bf16x8 v8 = *(const bf16x8*)&qkv[(long)row * 2304 + s * 768 + h * 64 + l8 * 8];
    const long addr = (((long)(b * 12 + h)) * 1024 + n) * 64 + l8 * 8;
    if (s == 2) {
      *(bf16x8*)&vb[addr] = v8;
    } else {
      float f[8];
      float sq = 0.f;
#pragma unroll
      for (int e = 0; e < 8; ++e) { f[e] = (float)v8[e]; sq += f[e] * f[e]; }
      float tot = sq;
      tot += __shfl_xor(tot, 1);
      tot += __shfl_xor(tot, 2);
      tot += __shfl_xor(tot, 4);
      const float inv = 1.0f / tot;
      bf16x8 o;
#pragma unroll
      for (int e = 0; e < 8; ++e) o[e] = (bf16)(f[e] * f[e] * inv);
      if (s == 0) *(bf16x8*)&q2h[addr] = o;
      else        *(bf16x8*)&k2h[addr] = o;
    }
  }
}

// v (B,H,N,D) bf16 -> vT (B,H,D,N) bf16, 64x64 tiles, vectorized both sides.
__global__ __launch_bounds__(256) void transpose_v(
    const bf16* __restrict__ vb, bf16* __restrict__ vth)
{
  __shared__ float t[64][65];
  const int z = blockIdx.y, n0 = blockIdx.x * 64, tid = threadIdx.x;
  const bf16* srcp = vb + ((long)z * 1024 + n0) * 64;
  for (int e = tid * 8; e < 4096; e += 2048) {
    const bf16x8 v8 = *(const bf16x8*)&srcp[e];
    const int r = e >> 6, c = e & 63;
#pragma unroll
    for (int j = 0; j < 8; ++j) t[r][c + j] = (float)v8[j];
  }
  __syncthreads();
  for (int e = tid; e < 512; e += 256) {
    const int d = e >> 3, c0 = (e & 7) * 8;
    bf16x8 o;
#pragma unroll
    for (int j = 0; j < 8; ++j) o[j] = (bf16)t[c0 + j][d];
    *(bf16x8*)&vth[((long)z * 64 + d) * 1024 + n0 + c0] = o;
  }
}

// Gram partials: Gq += q2^T q2 (64x64), Gk likewise; Sq/Sk column sums.
__global__ __launch_bounds__(256) void stats_accum(
    const bf16* __restrict__ q2h, const bf16* __restrict__ k2h,
    float* __restrict__ Gq, float* __restrict__ Gk,
    float* __restrict__ Sq, float* __restrict__ Sk)
{
  __shared__ float rowbuf[8][128];     // 8 rows x (64 q | 64 k)
  const int tid = threadIdx.x;
  const int z = blockIdx.y;
  const long base = ((long)z * 1024 + (long)blockIdx.x * 128) * 64;
  const int tx = tid & 15, ty = tid >> 4;
  float gq[4][4] = {}, gk[4][4] = {};
  float sq = 0.f, sk = 0.f;
  for (int r0 = 0; r0 < 128; r0 += 8) {
    __syncthreads();
    {
      const int idx = tid * 4;         // 0..1023 over 8x128, bf16x4 loads
      const int rr = idx >> 7, cc = idx & 127;
      const long a = base + (long)(r0 + rr) * 64 + (cc & 63);
      const bf16x4 v4 = (cc < 64) ? *(const bf16x4*)&q2h[a]
                                  : *(const bf16x4*)&k2h[a];
#pragma unroll
      for (int j = 0; j < 4; ++j) rowbuf[rr][cc + j] = (float)v4[j];
    }
    __syncthreads();
#pragma unroll
    for (int r = 0; r < 8; ++r) {
      float qa[4], qe[4], ka[4], ke[4];
#pragma unroll
      for (int i = 0; i < 4; ++i) {
        qa[i] = rowbuf[r][ty * 4 + i]; qe[i] = rowbuf[r][tx * 4 + i];
        ka[i] = rowbuf[r][64 + ty * 4 + i]; ke[i] = rowbuf[r][64 + tx * 4 + i];
      }
#pragma unroll
      for (int i = 0; i < 4; ++i)
#pragma unroll
        for (int j = 0; j < 4; ++j) {
          gq[i][j] += qa[i] * qe[j];
          gk[i][j] += ka[i] * ke[j];
        }
    }
    if (tid < 128) {
      float s = 0.f;
#pragma unroll
      for (int r = 0; r < 8; ++r) s += rowbuf[r][tid];
      if (tid < 64) sq += s; else sk += s;
    }
  }
#pragma unroll
  for (int i = 0; i < 4; ++i)
#pragma unroll
    for (int j = 0; j < 4; ++j) {
      atomicAdd(&Gq[(long)z * 4096 + (ty * 4 + i) * 64 + tx * 4 + j], gq[i][j]);
      atomicAdd(&Gk[(long)z * 4096 + (ty * 4 + i) * 64 + tx * 4 + j], gk[i][j]);
    }
  if (tid < 64) atomicAdd(&Sq[z * 64 + tid], sq);
  else if (tid < 128) atomicAdd(&Sk[z * 64 + tid - 64], sk);
}

// Per-batch mean / rstd of the attn tensor from Gram partials.
__global__ __launch_bounds__(256) void stats_final(
    const float* __restrict__ Gq, const float* __restrict__ Gk,
    const float* __restrict__ Sq, const float* __restrict__ Sk,
    float* __restrict__ stats)
{
  __shared__ double red[256];
  const int b = blockIdx.x, tid = threadIdx.x;
  double s2 = 0.0, s1 = 0.0;
  for (int h = 0; h < 12; ++h) {
    const float* gq = Gq + ((long)(b * 12 + h)) * 4096;
    const float* gk = Gk + ((long)(b * 12 + h)) * 4096;
    for (int i = tid; i < 4096; i += 256) s2 += (double)gq[i] * (double)gk[i];
    const float* sqp = Sq + (b * 12 + h) * 64;
    const float* skp = Sk + (b * 12 + h) * 64;
    for (int i = tid; i < 64; i += 256) s1 += (double)sqp[i] * (double)skp[i];
  }
  red[tid] = s2; __syncthreads();
  for (int st = 128; st > 0; st >>= 1) { if (tid < st) red[tid] += red[tid + st]; __syncthreads(); }
  const double S2 = red[0]; __syncthreads();
  red[tid] = s1; __syncthreads();
  for (int st = 128; st > 0; st >>= 1) { if (tid < st) red[tid] += red[tid + st]; __syncthreads(); }
  if (tid == 0) {
    const double S1 = red[0];
    const double cnt = 12.0 * 1024.0 * 1024.0;
    const double mean = S1 / cnt;
    const double var = S2 / cnt - mean * mean;
    stats[2 * b] = (float)mean;
    stats[2 * b + 1] = (float)(1.0 / sqrt(var + 1e-5));
  }
}

// ---------------------------------------------------------------------------
extern "C" void kernel_launch(void* const* d_in, const int* in_sizes, int n_in,
                              void* d_out, int out_size, void* d_ws, size_t ws_size,
                              hipStream_t stream)
{
  const float* x      = (const float*)d_in[0];
  const float* ln0_w  = (const float*)d_in[1];
  const float* ln0_b  = (const float*)d_in[2];
  const float* qkv_w  = (const float*)d_in[3];
  const float* qkv_b  = (const float*)d_in[4];
  const float* proj_w = (const float*)d_in[5];
  const float* proj_b = (const float*)d_in[6];
  const float* attn_w = (const float*)d_in[7];
  const float* attn_b = (const float*)d_in[8];
  const float* ln1_w  = (const float*)d_in[9];
  const float* ln1_b  = (const float*)d_in[10];
  const float* fc1_w  = (const float*)d_in[11];
  const float* fc1_b  = (const float*)d_in[12];
  const float* fc2_w  = (const float*)d_in[13];
  const float* fc2_b  = (const float*)d_in[14];

  float* out_src  = (float*)d_out;
  float* out_attn = out_src + 4L * 1024 * 768;       // 3145728

  char* p = (char*)d_ws;
  auto take = [&](long bytes) -> char* {
    char* r = p;
    p += (bytes + 255) & ~255L;
    return r;
  };
  bf16* qkvw_h = (bf16*)take(3538944);
  bf16* projw_h = (bf16*)take(1179648);
  bf16* fc1w_h = (bf16*)take(4718592);
  bf16* fc2w_h = (bf16*)take(4718592);
  char* regB = take(12582912);                 // hh, later src_f32
  bf16* hh = (bf16*)regB;
  float* src = (float*)regB;
  char* regC = take(37748736);                 // qkv bf16, later gelu acts + ln1f
  bf16* qkvb = (bf16*)regC;                    // [0, 18874368) bf16 4096x2304
  bf16* gact = (bf16*)regC;                    // [0, 25165824) bf16 4096x3072
  float* ln1f = (float*)(regC + 25165824);     // [25165824, 37748736) f32
  bf16* q2h = (bf16*)take(6291456);
  bf16* k2h = (bf16*)take(6291456);
  bf16* vb  = (bf16*)take(6291456);
  bf16* vth = (bf16*)take(6291456);
  bf16* oh  = (bf16*)take(6291456);
  bf16* h1v = (bf16*)take(6291456);
  float* Gq = (float*)take(786432);
  float* Gk = (float*)take(786432);
  float* Sq = (float*)take(12288);
  float* Sk = (float*)take(12288);
  float* stats = (float*)take(256);

  const dim3 blk(256);

  (void)hipMemsetAsync((void*)Gq, 0, 786432 * 2 + 12288 * 2 + 256, stream);

  cast_bf16<<<dim3(1769472 / 4 / 256), blk, 0, stream>>>(qkv_w, qkvw_h, 442368);
  cast_bf16<<<dim3(589824 / 4 / 256), blk, 0, stream>>>(proj_w, projw_h, 147456);
  cast_bf16<<<dim3(2359296 / 4 / 256), blk, 0, stream>>>(fc1_w, fc1w_h, 589824);
  cast_bf16<<<dim3(2359296 / 4 / 256), blk, 0, stream>>>(fc2_w, fc2w_h, 589824);

  ln_row<<<dim3(4096), blk, 0, stream>>>(x, ln0_w, ln0_b, hh, nullptr);

  gemm_k<128, 64, 2, 4, 2, 3, EpiQKV><<<dim3(36, 32, 1), blk, 0, stream>>>(
      hh, 0, qkvw_h, 0, 768, 768, 768, EpiQKV{qkv_b, qkvb});

  qkv_post<<<dim3(4096), blk, 0, stream>>>(qkvb, q2h, k2h, vb);
  transpose_v<<<dim3(16, 48), blk, 0, stream>>>(vb, vth);
  stats_accum<<<dim3(8, 48), blk, 0, stream>>>(q2h, k2h, Gq, Gk, Sq, Sk);
  stats_final<<<dim3(4), blk, 0, stream>>>(Gq, Gk, Sq, Sk, stats);

  attn_fused<<<dim3(768), blk, 0, stream>>>(
      q2h, k2h, vth, stats, attn_w, attn_b, out_attn, oh);

  gemm_k<128, 64, 2, 4, 2, 3, EpiProj><<<dim3(12, 32, 1), blk, 0, stream>>>(
      oh, 0, projw_h, 0, 768, 768, 768, EpiProj{proj_b, x, src});

  ln_row<<<dim3(4096), blk, 0, stream>>>(src, ln1_w, ln1_b, h1v, ln1f);

  gemm_k<128, 64, 2, 4, 2, 3, EpiGelu><<<dim3(48, 32, 1), blk, 0, stream>>>(
      h1v, 0, fc1w_h, 0, 768, 768, 768, EpiGelu{fc1_b, gact});

  gemm_k<128, 64, 2, 4, 2, 3, EpiOut><<<dim3(12, 32, 1), blk, 0, stream>>>(
      gact, 0, fc2w_h, 0, 3072, 3072, 3072, EpiOut{fc2_b, ln1f, out_src});
}